// Round 2
// baseline (1028.864 us; speedup 1.0000x reference)
//
#include <hip/hip_runtime.h>
#include <hip/hip_bf16.h>
#include <cstdio>
#include <cstdint>

#define B_    2
#define S_    2048
#define H_    32
#define KVH_  8
#define D_    128
#define HID_  4096
#define WIN_  512
#define NROW_ (B_*S_)          // 4096 rows for projection GEMMs
#define SCALE_ 0.08838834764831845f          // 128^-0.5
#define SL2E_  0.12751744932973953f          // SCALE_ * log2(e)

typedef __attribute__((ext_vector_type(8))) __bf16 bf16x8;
typedef __attribute__((ext_vector_type(4))) __bf16 bf16x4;
typedef __attribute__((ext_vector_type(4))) float  f32x4;

#define GAS __attribute__((address_space(1)))
#define LAS __attribute__((address_space(3)))

// ---------------------------------------------------------------- cvt f32->bf16
__global__ __launch_bounds__(256) void cvt_bf16(const float* __restrict__ in,
                                                __hip_bfloat16* __restrict__ out, int n) {
    int i = (blockIdx.x * 256 + threadIdx.x) * 4;
    if (i >= n) return;
    float4 v = *(const float4*)(in + i);
    __hip_bfloat162 a, b;
    a.x = __float2bfloat16(v.x); a.y = __float2bfloat16(v.y);
    b.x = __float2bfloat16(v.z); b.y = __float2bfloat16(v.w);
    *(__hip_bfloat162*)(out + i)     = a;
    *(__hip_bfloat162*)(out + i + 2) = b;
}

// ------------------------------------------------- transpose + cvt: (R,C) f32 -> (C,R) bf16
__global__ __launch_bounds__(256) void transpose_cvt(const float* __restrict__ in,
                                                     __hip_bfloat16* __restrict__ out,
                                                     int R, int C) {
    __shared__ float t[32][33];
    int tx = threadIdx.x, ty = threadIdx.y;             // (32,8)
    int r0 = blockIdx.y * 32, c0 = blockIdx.x * 32;
    #pragma unroll
    for (int i = 0; i < 4; ++i)
        t[ty + 8*i][tx] = in[(size_t)(r0 + ty + 8*i) * C + c0 + tx];
    __syncthreads();
    #pragma unroll
    for (int i = 0; i < 4; ++i)
        out[(size_t)(c0 + ty + 8*i) * R + r0 + tx] = __float2bfloat16(t[tx][ty + 8*i]);
}

// ------------------------------------------------- V: (B*S, KVH*D) f32 -> (B,KVH,D,S) bf16
__global__ __launch_bounds__(256) void v_transpose(const float* __restrict__ vf,
                                                   __hip_bfloat16* __restrict__ vt) {
    __shared__ float t[32][33];
    int tx = threadIdx.x, ty = threadIdx.y;             // (32,8)
    int plane = blockIdx.z, b = plane >> 3, g = plane & 7;
    int s0 = blockIdx.x * 32, d0 = blockIdx.y * 32;
    #pragma unroll
    for (int i = 0; i < 4; ++i) {
        int s = s0 + ty + 8*i;
        t[ty + 8*i][tx] = vf[((size_t)b*S_ + s) * (KVH_*D_) + g*D_ + d0 + tx];
    }
    __syncthreads();
    #pragma unroll
    for (int i = 0; i < 4; ++i) {
        int d = d0 + ty + 8*i;
        vt[(((size_t)b*KVH_ + g) * D_ + d) * S_ + s0 + tx] = __float2bfloat16(t[tx][ty + 8*i]);
    }
}

// ------------------------------------------------- GEMM: A(MxK) * Bt(NxK)^T -> C(MxN) f32
// m97 structure: 128x128 tile, BK=32, 4 waves (2x2), global_load_lds width-16 staging.
__global__ __launch_bounds__(256) void gemm_bt(const __hip_bfloat16* __restrict__ A,
                                               const __hip_bfloat16* __restrict__ Bt,
                                               float* __restrict__ C,
                                               int M, int N, int K) {
    __shared__ __align__(16) __hip_bfloat16 Asl[128*32];
    __shared__ __align__(16) __hip_bfloat16 Bsl[128*32];
    const int lane = threadIdx.x & 63, w = threadIdx.x >> 6;
    const int lc = lane & 15, lg = lane >> 4;
    const int row0 = blockIdx.y * 128, col0 = blockIdx.x * 128;
    const int wm = w >> 1, wn = w & 1;
    const int sr = lane >> 2, sc = (lane & 3) * 8;      // staging row/col within 16-row chunk

    f32x4 acc[4][4] = {};

    for (int kt = 0; kt < K; kt += 32) {
        #pragma unroll
        for (int i = 0; i < 2; ++i) {
            int c = w * 2 + i;                          // chunk 0..7 (16 rows x 32 cols = 1KB)
            const __hip_bfloat16* gA = A  + (size_t)(row0 + c*16 + sr) * K + kt + sc;
            __builtin_amdgcn_global_load_lds((const GAS void*)gA, (LAS void*)&Asl[c*512], 16, 0, 0);
            const __hip_bfloat16* gB = Bt + (size_t)(col0 + c*16 + sr) * K + kt + sc;
            __builtin_amdgcn_global_load_lds((const GAS void*)gB, (LAS void*)&Bsl[c*512], 16, 0, 0);
        }
        __syncthreads();
        bf16x8 af[4], bf[4];
        #pragma unroll
        for (int m = 0; m < 4; ++m)
            af[m] = *(const bf16x8*)&Asl[(wm*64 + m*16 + lc)*32 + lg*8];
        #pragma unroll
        for (int n = 0; n < 4; ++n)
            bf[n] = *(const bf16x8*)&Bsl[(wn*64 + n*16 + lc)*32 + lg*8];
        #pragma unroll
        for (int m = 0; m < 4; ++m)
            #pragma unroll
            for (int n = 0; n < 4; ++n)
                acc[m][n] = __builtin_amdgcn_mfma_f32_16x16x32_bf16(af[m], bf[n], acc[m][n], 0, 0, 0);
        __syncthreads();
    }
    #pragma unroll
    for (int m = 0; m < 4; ++m)
        #pragma unroll
        for (int n = 0; n < 4; ++n) {
            int col = col0 + wn*64 + n*16 + lc;
            #pragma unroll
            for (int r = 0; r < 4; ++r) {
                int row = row0 + wm*64 + m*16 + lg*4 + r;
                C[(size_t)row * N + col] = acc[m][n][r];
            }
        }
}

// ------------------------------------------------- per-head LN + interleaved RoPE
// in:  x (B*S, NH*D) f32 from GEMM.  out: (B, NH, S, D) bf16.
template <int NH>
__global__ __launch_bounds__(256) void ln_rope(const float* __restrict__ x,
                                               const float* __restrict__ wln,
                                               const float* __restrict__ cosT,
                                               const float* __restrict__ sinT,
                                               const int* __restrict__ pids,
                                               __hip_bfloat16* __restrict__ out) {
    const int lane = threadIdx.x & 63, wv = threadIdx.x >> 6;
    const int r = blockIdx.x * 4 + wv;                 // row over B*S*NH
    const int h = r % NH;
    const int bs = r / NH;
    const int b = bs / S_, s = bs % S_;
    const float2 xv = *(const float2*)(x + (size_t)r * D_ + lane*2);
    float sum = xv.x + xv.y;
    #pragma unroll
    for (int o = 32; o; o >>= 1) sum += __shfl_xor(sum, o);
    const float mu = sum * (1.f / D_);
    const float dx = xv.x - mu, dy = xv.y - mu;
    float vs = dx*dx + dy*dy;
    #pragma unroll
    for (int o = 32; o; o >>= 1) vs += __shfl_xor(vs, o);
    const float rs = rsqrtf(vs * (1.f / D_) + 1e-5f);
    const float2 w2 = *(const float2*)(wln + lane*2);
    const float y0 = w2.x * dx * rs, y1 = w2.y * dy * rs;
    const int p = pids[bs];
    const float2 c  = *(const float2*)(cosT + (size_t)p * D_ + lane*2);
    const float2 sn = *(const float2*)(sinT + (size_t)p * D_ + lane*2);
    __hip_bfloat162 ov;
    ov.x = __float2bfloat16(y0 * c.x - y1 * sn.x);     // even: x0*c - x1*s
    ov.y = __float2bfloat16(y1 * c.y + y0 * sn.y);     // odd:  x1*c + x0*s
    *(__hip_bfloat162*)(out + (((size_t)b * NH + h) * S_ + s) * D_ + lane*2) = ov;
}

// ------------------------------------------------- sliding-window GQA flash attention v2
// Swapped QK^T (S^T = K·Q^T): each lane owns ONE q row (col=lane&15); with the
// permuted key->A-row mapping the in-register P^T IS the PV B-fragment. No LDS,
// no cross-lane P movement, softmax reduce = in-lane + 2 shuffles.
// qr (B,H,S,D), kr (B,KVH,S,D), vt (B,KVH,D,S) bf16 -> ao (B,S,H*D) bf16.
__global__ __launch_bounds__(256) void attn_fwd(const __hip_bfloat16* __restrict__ qr,
                                                const __hip_bfloat16* __restrict__ kr,
                                                const __hip_bfloat16* __restrict__ vt,
                                                __hip_bfloat16* __restrict__ ao) {
    const int lane = threadIdx.x & 63, w = threadIdx.x >> 6;
    const int lq = lane & 15, lg = lane >> 4;
    const int blk = blockIdx.x;
    const int qt = blk & (S_/64 - 1);
    const int bh = blk >> 5;                     // S_/64 == 32
    const int h = bh & (H_-1), b = bh >> 5;
    const int g = h >> 2;                        // GQA: kv head = h/4
    const int q0 = qt*64 + w*16;
    const int q  = q0 + lq;

    const __hip_bfloat16* qbase = qr + (((size_t)b*H_ + h)*S_ + q0) * D_;
    const __hip_bfloat16* kbase = kr + ((size_t)b*KVH_ + g) * (size_t)S_ * D_;
    const __hip_bfloat16* vbase = vt + ((size_t)b*KVH_ + g) * (size_t)D_ * S_;

    // Q as B-operand fragment: B[k][col=q], col=lane&15, k=lg*8+j (+32*kk)
    bf16x8 qf[4];
    #pragma unroll
    for (int kk = 0; kk < 4; ++kk)
        qf[kk] = *(const bf16x8*)(qbase + lq*D_ + kk*32 + lg*8);

    f32x4 o[8] = {};                             // out^T frags: d = n*16 + lg*4 + r, col q = lq
    float m = -1e30f, l = 0.f;

    int kst = q0 - (WIN_ - 1); if (kst < 0) kst = 0; kst &= ~63;
    // A-row -> key permutation: key = 8*(row>>2) + 4*f + (row&3)
    const int kldrow = 8*(lq >> 2) + (lq & 3);

    for (int k0 = kst; k0 <= q0 + 15; k0 += 64) {
        // ---- QK^T: S^T fragments; held value (kb,f,r): key = k0+kb*32+8*lg+4f+r
        f32x4 sc[2][2] = {};
        __builtin_amdgcn_s_setprio(1);
        #pragma unroll
        for (int kb = 0; kb < 2; ++kb)
            #pragma unroll
            for (int f = 0; f < 2; ++f) {
                const __hip_bfloat16* kp = kbase + (size_t)(k0 + kb*32 + 4*f + kldrow) * D_ + lg*8;
                #pragma unroll
                for (int kk = 0; kk < 4; ++kk) {
                    bf16x8 ka = *(const bf16x8*)(kp + kk*32);
                    sc[kb][f] = __builtin_amdgcn_mfma_f32_16x16x32_bf16(ka, qf[kk], sc[kb][f], 0, 0, 0);
                }
            }
        __builtin_amdgcn_s_setprio(0);

        // ---- online softmax, log2 domain, lane-local row
        const int dqk = q - (k0 + 8*lg);         // q - key = dqk - (kb*32+4f+r)
        float pv[16];
        float mx = -INFINITY;
        #pragma unroll
        for (int kb = 0; kb < 2; ++kb)
            #pragma unroll
            for (int f = 0; f < 2; ++f)
                #pragma unroll
                for (int r = 0; r < 4; ++r) {
                    const int c = kb*32 + 4*f + r;
                    const int d = dqk - c;
                    float v = (d >= 0 && d < WIN_) ? sc[kb][f][r] * SL2E_ : -INFINITY;
                    pv[kb*8 + f*4 + r] = v;
                    mx = fmaxf(mx, v);
                }
        mx = fmaxf(mx, __shfl_xor(mx, 16));
        mx = fmaxf(mx, __shfl_xor(mx, 32));
        const float mn = fmaxf(m, mx);
        const float alpha = exp2f(m - mn);
        float ls = 0.f;
        union { bf16x8 v; __hip_bfloat16 e[8]; } pu[2];
        #pragma unroll
        for (int kb = 0; kb < 2; ++kb)
            #pragma unroll
            for (int j = 0; j < 8; ++j) {
                const float p = exp2f(pv[kb*8 + j] - mn);
                ls += p;
                pu[kb].e[j] = __float2bfloat16(p);
            }
        ls += __shfl_xor(ls, 16);
        ls += __shfl_xor(ls, 32);
        l = l * alpha + ls;
        m = mn;
        #pragma unroll
        for (int n = 0; n < 8; ++n) {
            o[n][0] *= alpha; o[n][1] *= alpha; o[n][2] *= alpha; o[n][3] *= alpha;
        }

        // ---- PV: out^T[d][q] += V^T[d][k] * P^T[k][q]; P^T regs ARE the B-frag
        __builtin_amdgcn_s_setprio(1);
        #pragma unroll
        for (int kb = 0; kb < 2; ++kb)
            #pragma unroll
            for (int n = 0; n < 8; ++n) {
                bf16x8 vf8 = *(const bf16x8*)(vbase + (size_t)(n*16 + lq)*S_ + k0 + kb*32 + lg*8);
                o[n] = __builtin_amdgcn_mfma_f32_16x16x32_bf16(vf8, pu[kb].v, o[n], 0, 0, 0);
            }
        __builtin_amdgcn_s_setprio(0);
    }

    const float rinv = 1.f / l;
    #pragma unroll
    for (int n = 0; n < 8; ++n) {
        union { bf16x4 v; __hip_bfloat16 e[4]; } ov;
        #pragma unroll
        for (int r = 0; r < 4; ++r) ov.e[r] = __float2bfloat16(o[n][r] * rinv);
        *(bf16x4*)(ao + ((size_t)b*S_ + q)*(H_*D_) + h*D_ + n*16 + lg*4) = ov.v;
    }
}

// ----------------------------------------------------------------- host
extern "C" void kernel_launch(void* const* d_in, const int* in_sizes, int n_in,
                              void* d_out, int out_size, void* d_ws, size_t ws_size,
                              hipStream_t stream) {
    const float* hidden = (const float*)d_in[0];
    const int*   pids   = (const int*)  d_in[1];
    const float* cosT   = (const float*)d_in[2];
    const float* sinT   = (const float*)d_in[3];
    const float* wq     = (const float*)d_in[4];
    const float* wk     = (const float*)d_in[5];
    const float* wv     = (const float*)d_in[6];
    const float* wo     = (const float*)d_in[7];
    const float* qnw    = (const float*)d_in[8];
    const float* knw    = (const float*)d_in[9];
    float* out = (float*)d_out;

    char* base = (char*)d_ws;
    size_t off = 0;
    auto take = [&](size_t bytes) -> void* {
        void* q = base + off;
        off = (off + bytes + 255) & ~(size_t)255;
        return q;
    };
    float* qf            = (float*)take((size_t)NROW_*HID_*4);          // also reused as ao
    __hip_bfloat16* hb   = (__hip_bfloat16*)take((size_t)NROW_*HID_*2);
    __hip_bfloat16* wqT  = (__hip_bfloat16*)take((size_t)HID_*HID_*2);
    __hip_bfloat16* wkT  = (__hip_bfloat16*)take((size_t)HID_*KVH_*D_*2);
    __hip_bfloat16* wvT  = (__hip_bfloat16*)take((size_t)HID_*KVH_*D_*2);
    __hip_bfloat16* woT  = (__hip_bfloat16*)take((size_t)HID_*HID_*2);
    float* kf            = (float*)take((size_t)NROW_*KVH_*D_*4);
    float* vf            = (float*)take((size_t)NROW_*KVH_*D_*4);
    __hip_bfloat16* qr   = (__hip_bfloat16*)take((size_t)B_*H_*S_*D_*2);
    __hip_bfloat16* kr   = (__hip_bfloat16*)take((size_t)B_*KVH_*S_*D_*2);
    __hip_bfloat16* vt   = (__hip_bfloat16*)take((size_t)B_*KVH_*S_*D_*2);
    __hip_bfloat16* ao   = (__hip_bfloat16*)qf;    // alias: qf dead after ln_rope

    if (off > ws_size) {
        fprintf(stderr, "WORKSPACE TOO SMALL: need %zu have %zu\n", off, ws_size);
        return;
    }

    // 1. converts / transposes
    cvt_bf16<<<(NROW_*HID_)/1024, 256, 0, stream>>>(hidden, hb, NROW_*HID_);
    transpose_cvt<<<dim3((H_*D_)/32,   HID_/32), dim3(32,8), 0, stream>>>(wq, wqT, HID_, H_*D_);
    transpose_cvt<<<dim3((KVH_*D_)/32, HID_/32), dim3(32,8), 0, stream>>>(wk, wkT, HID_, KVH_*D_);
    transpose_cvt<<<dim3((KVH_*D_)/32, HID_/32), dim3(32,8), 0, stream>>>(wv, wvT, HID_, KVH_*D_);
    transpose_cvt<<<dim3(HID_/32, (H_*D_)/32),   dim3(32,8), 0, stream>>>(wo, woT, H_*D_, HID_);

    // 2. QKV projections
    gemm_bt<<<dim3((H_*D_)/128,   NROW_/128), 256, 0, stream>>>(hb, wqT, qf, NROW_, H_*D_,   HID_);
    gemm_bt<<<dim3((KVH_*D_)/128, NROW_/128), 256, 0, stream>>>(hb, wkT, kf, NROW_, KVH_*D_, HID_);
    gemm_bt<<<dim3((KVH_*D_)/128, NROW_/128), 256, 0, stream>>>(hb, wvT, vf, NROW_, KVH_*D_, HID_);

    // 3. LN + RoPE (q, k), V transpose
    ln_rope<H_><<<(B_*S_*H_)/4,     256, 0, stream>>>(qf, qnw, cosT, sinT, pids, qr);
    ln_rope<KVH_><<<(B_*S_*KVH_)/4, 256, 0, stream>>>(kf, knw, cosT, sinT, pids, kr);
    v_transpose<<<dim3(S_/32, D_/32, B_*KVH_), dim3(32,8), 0, stream>>>(vf, vt);

    // 4. attention
    attn_fwd<<<B_*H_*(S_/64), 256, 0, stream>>>(qr, kr, vt, ao);

    // 5. output projection -> d_out (f32)
    gemm_bt<<<dim3(HID_/128, NROW_/128), 256, 0, stream>>>(ao, woT, out, NROW_, HID_, H_*D_ /*K=4096*/);
}

// Round 3
// 838.429 us; speedup vs baseline: 1.2271x; 1.2271x over previous
//
#include <hip/hip_runtime.h>
#include <hip/hip_bf16.h>
#include <cstdio>
#include <cstdint>

#define B_    2
#define S_    2048
#define H_    32
#define KVH_  8
#define D_    128
#define HID_  4096
#define WIN_  512
#define NROW_ (B_*S_)          // 4096 rows for projection GEMMs
#define SCALE_ 0.08838834764831845f          // 128^-0.5
#define SL2E_  0.12751744932973953f          // SCALE_ * log2(e)

typedef __attribute__((ext_vector_type(8))) __bf16 bf16x8;
typedef __attribute__((ext_vector_type(4))) __bf16 bf16x4;
typedef __attribute__((ext_vector_type(4))) float  f32x4;

#define GAS __attribute__((address_space(1)))
#define LAS __attribute__((address_space(3)))

// ---------------------------------------------------------------- cvt f32->bf16
__global__ __launch_bounds__(256) void cvt_bf16(const float* __restrict__ in,
                                                __hip_bfloat16* __restrict__ out, int n) {
    int i = (blockIdx.x * 256 + threadIdx.x) * 4;
    if (i >= n) return;
    float4 v = *(const float4*)(in + i);
    __hip_bfloat162 a, b;
    a.x = __float2bfloat16(v.x); a.y = __float2bfloat16(v.y);
    b.x = __float2bfloat16(v.z); b.y = __float2bfloat16(v.w);
    *(__hip_bfloat162*)(out + i)     = a;
    *(__hip_bfloat162*)(out + i + 2) = b;
}

// ------------------------------------------------- transpose + cvt: (R,C) f32 -> (C,R) bf16
__global__ __launch_bounds__(256) void transpose_cvt(const float* __restrict__ in,
                                                     __hip_bfloat16* __restrict__ out,
                                                     int R, int C) {
    __shared__ float t[32][33];
    int tx = threadIdx.x, ty = threadIdx.y;             // (32,8)
    int r0 = blockIdx.y * 32, c0 = blockIdx.x * 32;
    #pragma unroll
    for (int i = 0; i < 4; ++i)
        t[ty + 8*i][tx] = in[(size_t)(r0 + ty + 8*i) * C + c0 + tx];
    __syncthreads();
    #pragma unroll
    for (int i = 0; i < 4; ++i)
        out[(size_t)(c0 + ty + 8*i) * R + r0 + tx] = __float2bfloat16(t[tx][ty + 8*i]);
}

// ------------------------------------------------- V: (B*S, KVH*D) f32 -> (B,KVH,D,S) bf16
__global__ __launch_bounds__(256) void v_transpose(const float* __restrict__ vf,
                                                   __hip_bfloat16* __restrict__ vt) {
    __shared__ float t[32][33];
    int tx = threadIdx.x, ty = threadIdx.y;             // (32,8)
    int plane = blockIdx.z, b = plane >> 3, g = plane & 7;
    int s0 = blockIdx.x * 32, d0 = blockIdx.y * 32;
    #pragma unroll
    for (int i = 0; i < 4; ++i) {
        int s = s0 + ty + 8*i;
        t[ty + 8*i][tx] = vf[((size_t)b*S_ + s) * (KVH_*D_) + g*D_ + d0 + tx];
    }
    __syncthreads();
    #pragma unroll
    for (int i = 0; i < 4; ++i) {
        int d = d0 + ty + 8*i;
        vt[(((size_t)b*KVH_ + g) * D_ + d) * S_ + s0 + tx] = __float2bfloat16(t[tx][ty + 8*i]);
    }
}

// ------------------------------------------------- GEMM: A(MxK) * Bt(NxK)^T -> C(MxN) f32
// m97 structure: 128x128 tile, BK=32, 4 waves (2x2), global_load_lds width-16 staging.
__global__ __launch_bounds__(256) void gemm_bt(const __hip_bfloat16* __restrict__ A,
                                               const __hip_bfloat16* __restrict__ Bt,
                                               float* __restrict__ C,
                                               int M, int N, int K) {
    __shared__ __align__(16) __hip_bfloat16 Asl[128*32];
    __shared__ __align__(16) __hip_bfloat16 Bsl[128*32];
    const int lane = threadIdx.x & 63, w = threadIdx.x >> 6;
    const int lc = lane & 15, lg = lane >> 4;
    const int row0 = blockIdx.y * 128, col0 = blockIdx.x * 128;
    const int wm = w >> 1, wn = w & 1;
    const int sr = lane >> 2, sc = (lane & 3) * 8;      // staging row/col within 16-row chunk

    f32x4 acc[4][4] = {};

    for (int kt = 0; kt < K; kt += 32) {
        #pragma unroll
        for (int i = 0; i < 2; ++i) {
            int c = w * 2 + i;                          // chunk 0..7 (16 rows x 32 cols = 1KB)
            const __hip_bfloat16* gA = A  + (size_t)(row0 + c*16 + sr) * K + kt + sc;
            __builtin_amdgcn_global_load_lds((const GAS void*)gA, (LAS void*)&Asl[c*512], 16, 0, 0);
            const __hip_bfloat16* gB = Bt + (size_t)(col0 + c*16 + sr) * K + kt + sc;
            __builtin_amdgcn_global_load_lds((const GAS void*)gB, (LAS void*)&Bsl[c*512], 16, 0, 0);
        }
        __syncthreads();
        bf16x8 af[4], bf[4];
        #pragma unroll
        for (int m = 0; m < 4; ++m)
            af[m] = *(const bf16x8*)&Asl[(wm*64 + m*16 + lc)*32 + lg*8];
        #pragma unroll
        for (int n = 0; n < 4; ++n)
            bf[n] = *(const bf16x8*)&Bsl[(wn*64 + n*16 + lc)*32 + lg*8];
        #pragma unroll
        for (int m = 0; m < 4; ++m)
            #pragma unroll
            for (int n = 0; n < 4; ++n)
                acc[m][n] = __builtin_amdgcn_mfma_f32_16x16x32_bf16(af[m], bf[n], acc[m][n], 0, 0, 0);
        __syncthreads();
    }
    #pragma unroll
    for (int m = 0; m < 4; ++m)
        #pragma unroll
        for (int n = 0; n < 4; ++n) {
            int col = col0 + wn*64 + n*16 + lc;
            #pragma unroll
            for (int r = 0; r < 4; ++r) {
                int row = row0 + wm*64 + m*16 + lg*4 + r;
                C[(size_t)row * N + col] = acc[m][n][r];
            }
        }
}

// ------------------------------------------------- per-head LN + interleaved RoPE
// in:  x (B*S, NH*D) f32 from GEMM.  out: (B, NH, S, D) bf16.
template <int NH>
__global__ __launch_bounds__(256) void ln_rope(const float* __restrict__ x,
                                               const float* __restrict__ wln,
                                               const float* __restrict__ cosT,
                                               const float* __restrict__ sinT,
                                               const int* __restrict__ pids,
                                               __hip_bfloat16* __restrict__ out) {
    const int lane = threadIdx.x & 63, wv = threadIdx.x >> 6;
    const int r = blockIdx.x * 4 + wv;                 // row over B*S*NH
    const int h = r % NH;
    const int bs = r / NH;
    const int b = bs / S_, s = bs % S_;
    const float2 xv = *(const float2*)(x + (size_t)r * D_ + lane*2);
    float sum = xv.x + xv.y;
    #pragma unroll
    for (int o = 32; o; o >>= 1) sum += __shfl_xor(sum, o);
    const float mu = sum * (1.f / D_);
    const float dx = xv.x - mu, dy = xv.y - mu;
    float vs = dx*dx + dy*dy;
    #pragma unroll
    for (int o = 32; o; o >>= 1) vs += __shfl_xor(vs, o);
    const float rs = rsqrtf(vs * (1.f / D_) + 1e-5f);
    const float2 w2 = *(const float2*)(wln + lane*2);
    const float y0 = w2.x * dx * rs, y1 = w2.y * dy * rs;
    const int p = pids[bs];
    const float2 c  = *(const float2*)(cosT + (size_t)p * D_ + lane*2);
    const float2 sn = *(const float2*)(sinT + (size_t)p * D_ + lane*2);
    __hip_bfloat162 ov;
    ov.x = __float2bfloat16(y0 * c.x - y1 * sn.x);     // even: x0*c - x1*s
    ov.y = __float2bfloat16(y1 * c.y + y0 * sn.y);     // odd:  x1*c + x0*s
    *(__hip_bfloat162*)(out + (((size_t)b * NH + h) * S_ + s) * D_ + lane*2) = ov;
}

// chunk swizzle for K tile (16B chunks, 16/row): spread over 8 bank-groups per 16-lane read
static __device__ __forceinline__ int sigk_(int r) { return (r & 3) | ((r >> 1) & 4); }

// ------------------------------------------------- sliding-window GQA flash attention v3
// v2 math (swapped QK^T, in-register P^T == PV B-frag) + block-level LDS staging of K/V^T
// via global_load_lds, double-buffered with counted vmcnt + raw s_barrier (T3-minimum).
// LDS chunks XOR-swizzled on both stage-source and read side (rule #21).
// qr (B,H,S,D), kr (B,KVH,S,D), vt (B,KVH,D,S) bf16 -> ao (B,S,H*D) bf16.
__global__ __launch_bounds__(256) void attn_fwd(const __hip_bfloat16* __restrict__ qr,
                                                const __hip_bfloat16* __restrict__ kr,
                                                const __hip_bfloat16* __restrict__ vt,
                                                __hip_bfloat16* __restrict__ ao) {
    __shared__ __align__(16) __hip_bfloat16 Ksl[2][64*D_];    // 2 x 16KB
    __shared__ __align__(16) __hip_bfloat16 Vsl[2][D_*64];    // 2 x 16KB
    const int lane = threadIdx.x & 63, w = threadIdx.x >> 6;
    const int lq = lane & 15, lg = lane >> 4;
    const int blk = blockIdx.x;
    const int qt = blk >> 6;                     // balance: CU's blocks span qt values
    const int bh = blk & 63;
    const int h = bh & (H_-1), b = bh >> 5;
    const int g = h >> 2;                        // GQA: kv head = h/4
    const int q0 = qt*64 + w*16;
    const int q  = q0 + lq;

    const __hip_bfloat16* qbase = qr + (((size_t)b*H_ + h)*S_ + q0) * D_;
    const __hip_bfloat16* kbase = kr + ((size_t)b*KVH_ + g) * (size_t)S_ * D_;
    const __hip_bfloat16* vbase = vt + ((size_t)b*KVH_ + g) * (size_t)D_ * S_;

    // staging lane constants
    const int srK = lane >> 4, scK = lane & 15;  // K: 4 rows x 16 chunks per wave-instr
    const int srV = lane >> 3, scV = lane & 7;   // V: 8 rows x 8 chunks per wave-instr

#define STAGE(nb, k0s) do {                                                              \
    _Pragma("unroll")                                                                    \
    for (int s_ = 0; s_ < 4; ++s_) {                                                     \
        const int rK_ = s_*16 + w*4 + srK;                                               \
        const __hip_bfloat16* srcK_ = kbase + (size_t)((k0s) + rK_)*D_                   \
                                      + ((scK ^ sigk_(rK_)) * 8);                        \
        __builtin_amdgcn_global_load_lds((const GAS void*)srcK_,                         \
            (LAS void*)&Ksl[nb][(s_*16 + w*4)*D_], 16, 0, 0);                            \
    }                                                                                    \
    _Pragma("unroll")                                                                    \
    for (int s_ = 0; s_ < 4; ++s_) {                                                     \
        const int dV_ = s_*32 + w*8 + srV;                                               \
        const __hip_bfloat16* srcV_ = vbase + (size_t)dV_*S_ + (k0s)                     \
                                      + ((scV ^ (dV_ & 7)) * 8);                         \
        __builtin_amdgcn_global_load_lds((const GAS void*)srcV_,                         \
            (LAS void*)&Vsl[nb][(s_*32 + w*8)*64], 16, 0, 0);                            \
    }                                                                                    \
} while (0)

    // Q as B-operand fragment: B[k][col=q], col=lane&15, k=lg*8+j (+32*kk)
    bf16x8 qf[4];
    #pragma unroll
    for (int kk = 0; kk < 4; ++kk)
        qf[kk] = *(const bf16x8*)(qbase + lq*D_ + kk*32 + lg*8);

    f32x4 o[8] = {};                             // out^T frags: d = n*16 + lg*4 + r, col q = lq
    float m = -1e30f, l = 0.f;

    int kst = qt*64 - (WIN_ - 1); if (kst < 0) kst = 0; kst &= ~63;
    const int nt = qt + 1 - (kst >> 6);          // tiles for the whole block (uniform)
    // A-row -> key permutation: key = 8*(row>>2) + 4*f + (row&3)
    const int kldrow = 8*(lq >> 2) + (lq & 3);

    STAGE(0, kst);

    for (int t = 0; t < nt; ++t) {
        const int k0 = kst + t*64;
        const int buf = t & 1;
        if (t + 1 < nt) {
            STAGE((t + 1) & 1, k0 + 64);
            asm volatile("s_waitcnt vmcnt(8)" ::: "memory");   // tile t staged; t+1 in flight
        } else {
            asm volatile("s_waitcnt vmcnt(0)" ::: "memory");
        }
        __builtin_amdgcn_s_barrier();

        // ---- QK^T from LDS: held value (kb,f,r): key = k0+kb*32+8*lg+4f+r
        f32x4 sc[2][2] = {};
        __builtin_amdgcn_s_setprio(1);
        #pragma unroll
        for (int kb = 0; kb < 2; ++kb)
            #pragma unroll
            for (int f = 0; f < 2; ++f) {
                const int rA = kb*32 + 4*f + kldrow;
                const __hip_bfloat16* kp = &Ksl[buf][rA*D_];
                #pragma unroll
                for (int kk = 0; kk < 4; ++kk) {
                    bf16x8 ka = *(const bf16x8*)(kp + (((kk*4 + lg) ^ sigk_(rA)) * 8));
                    sc[kb][f] = __builtin_amdgcn_mfma_f32_16x16x32_bf16(ka, qf[kk], sc[kb][f], 0, 0, 0);
                }
            }
        __builtin_amdgcn_s_setprio(0);

        // ---- online softmax, log2 domain, lane-local row
        const int dqk = q - (k0 + 8*lg);         // q - key = dqk - (kb*32+4f+r)
        float pv[16];
        float mx = -INFINITY;
        #pragma unroll
        for (int kb = 0; kb < 2; ++kb)
            #pragma unroll
            for (int f = 0; f < 2; ++f)
                #pragma unroll
                for (int r = 0; r < 4; ++r) {
                    const int c = kb*32 + 4*f + r;
                    const int d = dqk - c;
                    float v = (d >= 0 && d < WIN_) ? sc[kb][f][r] * SL2E_ : -INFINITY;
                    pv[kb*8 + f*4 + r] = v;
                    mx = fmaxf(mx, v);
                }
        mx = fmaxf(mx, __shfl_xor(mx, 16));
        mx = fmaxf(mx, __shfl_xor(mx, 32));
        const float mn = fmaxf(m, mx);
        const float alpha = exp2f(m - mn);
        float ls = 0.f;
        union { bf16x8 v; __hip_bfloat16 e[8]; } pu[2];
        #pragma unroll
        for (int kb = 0; kb < 2; ++kb)
            #pragma unroll
            for (int j = 0; j < 8; ++j) {
                const float p = exp2f(pv[kb*8 + j] - mn);
                ls += p;
                pu[kb].e[j] = __float2bfloat16(p);
            }
        ls += __shfl_xor(ls, 16);
        ls += __shfl_xor(ls, 32);
        l = l * alpha + ls;
        m = mn;
        #pragma unroll
        for (int n = 0; n < 8; ++n) {
            o[n][0] *= alpha; o[n][1] *= alpha; o[n][2] *= alpha; o[n][3] *= alpha;
        }

        // ---- PV from LDS: out^T[d][q] += V^T[d][k] * P^T[k][q]; P^T regs ARE the B-frag
        __builtin_amdgcn_s_setprio(1);
        #pragma unroll
        for (int kb = 0; kb < 2; ++kb)
            #pragma unroll
            for (int n = 0; n < 8; ++n) {
                const int dR = n*16 + lq;
                bf16x8 vf8 = *(const bf16x8*)(&Vsl[buf][dR*64] + (((kb*4 + lg) ^ (dR & 7)) * 8));
                o[n] = __builtin_amdgcn_mfma_f32_16x16x32_bf16(vf8, pu[kb].v, o[n], 0, 0, 0);
            }
        __builtin_amdgcn_s_setprio(0);

        if (t + 1 < nt) __builtin_amdgcn_s_barrier();   // all reads of buf done before overwrite
    }
#undef STAGE

    const float rinv = 1.f / l;
    #pragma unroll
    for (int n = 0; n < 8; ++n) {
        union { bf16x4 v; __hip_bfloat16 e[4]; } ov;
        #pragma unroll
        for (int r = 0; r < 4; ++r) ov.e[r] = __float2bfloat16(o[n][r] * rinv);
        *(bf16x4*)(ao + ((size_t)b*S_ + q)*(H_*D_) + h*D_ + n*16 + lg*4) = ov.v;
    }
}

// ----------------------------------------------------------------- host
extern "C" void kernel_launch(void* const* d_in, const int* in_sizes, int n_in,
                              void* d_out, int out_size, void* d_ws, size_t ws_size,
                              hipStream_t stream) {
    const float* hidden = (const float*)d_in[0];
    const int*   pids   = (const int*)  d_in[1];
    const float* cosT   = (const float*)d_in[2];
    const float* sinT   = (const float*)d_in[3];
    const float* wq     = (const float*)d_in[4];
    const float* wk     = (const float*)d_in[5];
    const float* wv     = (const float*)d_in[6];
    const float* wo     = (const float*)d_in[7];
    const float* qnw    = (const float*)d_in[8];
    const float* knw    = (const float*)d_in[9];
    float* out = (float*)d_out;

    char* base = (char*)d_ws;
    size_t off = 0;
    auto take = [&](size_t bytes) -> void* {
        void* q = base + off;
        off = (off + bytes + 255) & ~(size_t)255;
        return q;
    };
    float* qf            = (float*)take((size_t)NROW_*HID_*4);          // also reused as ao
    __hip_bfloat16* hb   = (__hip_bfloat16*)take((size_t)NROW_*HID_*2);
    __hip_bfloat16* wqT  = (__hip_bfloat16*)take((size_t)HID_*HID_*2);
    __hip_bfloat16* wkT  = (__hip_bfloat16*)take((size_t)HID_*KVH_*D_*2);
    __hip_bfloat16* wvT  = (__hip_bfloat16*)take((size_t)HID_*KVH_*D_*2);
    __hip_bfloat16* woT  = (__hip_bfloat16*)take((size_t)HID_*HID_*2);
    float* kf            = (float*)take((size_t)NROW_*KVH_*D_*4);
    float* vf            = (float*)take((size_t)NROW_*KVH_*D_*4);
    __hip_bfloat16* qr   = (__hip_bfloat16*)take((size_t)B_*H_*S_*D_*2);
    __hip_bfloat16* kr   = (__hip_bfloat16*)take((size_t)B_*KVH_*S_*D_*2);
    __hip_bfloat16* vt   = (__hip_bfloat16*)take((size_t)B_*KVH_*S_*D_*2);
    __hip_bfloat16* ao   = (__hip_bfloat16*)qf;    // alias: qf dead after ln_rope

    if (off > ws_size) {
        fprintf(stderr, "WORKSPACE TOO SMALL: need %zu have %zu\n", off, ws_size);
        return;
    }

    // 1. converts / transposes
    cvt_bf16<<<(NROW_*HID_)/1024, 256, 0, stream>>>(hidden, hb, NROW_*HID_);
    transpose_cvt<<<dim3((H_*D_)/32,   HID_/32), dim3(32,8), 0, stream>>>(wq, wqT, HID_, H_*D_);
    transpose_cvt<<<dim3((KVH_*D_)/32, HID_/32), dim3(32,8), 0, stream>>>(wk, wkT, HID_, KVH_*D_);
    transpose_cvt<<<dim3((KVH_*D_)/32, HID_/32), dim3(32,8), 0, stream>>>(wv, wvT, HID_, KVH_*D_);
    transpose_cvt<<<dim3(HID_/32, (H_*D_)/32),   dim3(32,8), 0, stream>>>(wo, woT, H_*D_, HID_);

    // 2. QKV projections
    gemm_bt<<<dim3((H_*D_)/128,   NROW_/128), 256, 0, stream>>>(hb, wqT, qf, NROW_, H_*D_,   HID_);
    gemm_bt<<<dim3((KVH_*D_)/128, NROW_/128), 256, 0, stream>>>(hb, wkT, kf, NROW_, KVH_*D_, HID_);
    gemm_bt<<<dim3((KVH_*D_)/128, NROW_/128), 256, 0, stream>>>(hb, wvT, vf, NROW_, KVH_*D_, HID_);

    // 3. LN + RoPE (q, k), V transpose
    ln_rope<H_><<<(B_*S_*H_)/4,     256, 0, stream>>>(qf, qnw, cosT, sinT, pids, qr);
    ln_rope<KVH_><<<(B_*S_*KVH_)/4, 256, 0, stream>>>(kf, knw, cosT, sinT, pids, kr);
    v_transpose<<<dim3(S_/32, D_/32, B_*KVH_), dim3(32,8), 0, stream>>>(vf, vt);

    // 4. attention
    attn_fwd<<<B_*H_*(S_/64), 256, 0, stream>>>(qr, kr, vt, ao);

    // 5. output projection -> d_out (f32)
    gemm_bt<<<dim3(HID_/128, NROW_/128), 256, 0, stream>>>(ao, woT, out, NROW_, HID_, H_*D_ /*K=4096*/);
}

// Round 4
// 548.913 us; speedup vs baseline: 1.8744x; 1.5274x over previous
//
#include <hip/hip_runtime.h>
#include <hip/hip_bf16.h>
#include <cstdio>
#include <cstdint>

#define B_    2
#define S_    2048
#define H_    32
#define KVH_  8
#define D_    128
#define HID_  4096
#define WIN_  512
#define NROW_ (B_*S_)          // 4096 rows for projection GEMMs
#define NQKV_ 6144             // fused q|k|v output width
#define SCALE_ 0.08838834764831845f          // 128^-0.5
#define SL2E_  0.12751744932973953f          // SCALE_ * log2(e)

typedef __attribute__((ext_vector_type(8))) __bf16 bf16x8;
typedef __attribute__((ext_vector_type(4))) __bf16 bf16x4;
typedef __attribute__((ext_vector_type(4))) float  f32x4;

#define GAS __attribute__((address_space(1)))
#define LAS __attribute__((address_space(3)))

// ---------------------------------------------------------------- cvt f32->bf16
__global__ __launch_bounds__(256) void cvt_bf16(const float* __restrict__ in,
                                                __hip_bfloat16* __restrict__ out, int n) {
    int i = (blockIdx.x * 256 + threadIdx.x) * 4;
    if (i >= n) return;
    float4 v = *(const float4*)(in + i);
    __hip_bfloat162 a, b;
    a.x = __float2bfloat16(v.x); a.y = __float2bfloat16(v.y);
    b.x = __float2bfloat16(v.z); b.y = __float2bfloat16(v.w);
    *(__hip_bfloat162*)(out + i)     = a;
    *(__hip_bfloat162*)(out + i + 2) = b;
}

// ------------------------------------------------- transpose + cvt: (R,C) f32 -> (C,R) bf16
__global__ __launch_bounds__(256) void transpose_cvt(const float* __restrict__ in,
                                                     __hip_bfloat16* __restrict__ out,
                                                     int R, int C) {
    __shared__ float t[32][33];
    int tx = threadIdx.x, ty = threadIdx.y;             // (32,8)
    int r0 = blockIdx.y * 32, c0 = blockIdx.x * 32;
    #pragma unroll
    for (int i = 0; i < 4; ++i)
        t[ty + 8*i][tx] = in[(size_t)(r0 + ty + 8*i) * C + c0 + tx];
    __syncthreads();
    #pragma unroll
    for (int i = 0; i < 4; ++i)
        out[(size_t)(c0 + ty + 8*i) * R + r0 + tx] = __float2bfloat16(t[tx][ty + 8*i]);
}

// ------------------------------------------------- V: qkv f32 (cols 5120..6143) -> (B,KVH,D,S) bf16
__global__ __launch_bounds__(256) void v_transpose(const float* __restrict__ qkv,
                                                   __hip_bfloat16* __restrict__ vt) {
    __shared__ float t[32][33];
    int tx = threadIdx.x, ty = threadIdx.y;             // (32,8)
    int plane = blockIdx.z, b = plane >> 3, g = plane & 7;
    int s0 = blockIdx.x * 32, d0 = blockIdx.y * 32;
    #pragma unroll
    for (int i = 0; i < 4; ++i) {
        int s = s0 + ty + 8*i;
        t[ty + 8*i][tx] = qkv[((size_t)b*S_ + s) * NQKV_ + (HID_ + KVH_*D_) + g*D_ + d0 + tx];
    }
    __syncthreads();
    #pragma unroll
    for (int i = 0; i < 4; ++i) {
        int d = d0 + ty + 8*i;
        vt[(((size_t)b*KVH_ + g) * D_ + d) * S_ + s0 + tx] = __float2bfloat16(t[tx][ty + 8*i]);
    }
}

// ------------------------------------------------- GEMM 256x256, BK=32, deep-pipelined
// A(MxK) bf16 * Bt(NxK)^T -> C(MxN) f32.  8 waves (2Mx4N), per-wave C = 128x64.
// 4-slot LDS ring, prefetch 3 K-tiles ahead (global_load_lds w16), counted vmcnt(10),
// XOR swizzle chunk^((row>>1)&3) on stage-source and ds_read (linear LDS dest),
// 2 phases/K-tile with setprio around the 16-MFMA clusters, XCD-aware block swizzle.
__global__ __launch_bounds__(512, 2) void gemm_bt256(const __hip_bfloat16* __restrict__ A,
                                                     const __hip_bfloat16* __restrict__ Bt,
                                                     float* __restrict__ C,
                                                     int M, int N, int K, int nbx) {
    __shared__ __align__(16) __hip_bfloat16 L[4][2][256*32];   // 128 KiB: ring of 4 x (A,B) tiles
    const int tid  = threadIdx.x;
    const int lane = tid & 63, w = tid >> 6;
    const int wm = w >> 2, wn = w & 3;                  // 2 x 4 wave grid
    const int lc = lane & 15, lg = lane >> 4;
    // XCD-aware bijective swizzle (gridDim.x % 8 == 0 by construction)
    const int nwg = gridDim.x, cpx = nwg >> 3;
    const int bid = blockIdx.x;
    const int swz = (bid & 7) * cpx + (bid >> 3);
    const int by = swz / nbx, bx = swz - by * nbx;
    const size_t row0 = (size_t)by * 256, col0 = (size_t)bx * 256;
    const int nt = K >> 5;                              // BK = 32

    const int srow = tid >> 2;                          // staging: 0..127 rows per round
    const int spc  = tid & 3;                           // phys 16B chunk
    const int slch = spc ^ ((srow >> 1) & 3);           // pre-inverse-swizzled logical chunk
    const __hip_bfloat16* Ab = A  + row0 * K;
    const __hip_bfloat16* Bb = Bt + col0 * K;

#define STG256(s, ab, rh, kt) do {                                                        \
    const __hip_bfloat16* gb_ = (ab) ? Bb : Ab;                                           \
    const __hip_bfloat16* src_ = gb_ + (size_t)((rh)*128 + srow) * K + (size_t)(kt)*32 + slch*8; \
    __builtin_amdgcn_global_load_lds((const GAS void*)src_,                               \
        (LAS void*)&L[s][ab][(rh)*4096 + w*512], 16, 0, 0);                               \
} while (0)

    // prologue: stage tiles 0..2 into slots 0..2 (12 loads/thread)
    #pragma unroll
    for (int u = 0; u < 3; ++u) {
        STG256(u, 0, 0, u); STG256(u, 0, 1, u);
        STG256(u, 1, 0, u); STG256(u, 1, 1, u);
    }

    f32x4 acc[2][4][4] = {};
    bf16x8 bfr[4], afr[4];

    for (int t = 0; t < nt; ++t) {
        const int sc = t & 3, ss = (t + 3) & 3;
        const int ts = (t + 3 < nt) ? (t + 3) : (nt - 1);   // clamped tail keeps vmcnt uniform

        // ---- phase 0: stage A-half of tile t+3; confirm tile t landed; quadrant qm=0
        STG256(ss, 0, 0, ts); STG256(ss, 0, 1, ts);
        asm volatile("s_waitcnt vmcnt(10)" ::: "memory");   // my tile-t loads landed
        asm volatile("s_barrier" ::: "memory");             // => all waves' tile-t loads landed
        __builtin_amdgcn_sched_barrier(0);
        #pragma unroll
        for (int fn = 0; fn < 4; ++fn) {
            const int rB = wn*64 + fn*16 + lc;
            bfr[fn] = *(const bf16x8*)&L[sc][1][rB*32 + ((lg ^ ((rB >> 1) & 3)) * 8)];
        }
        #pragma unroll
        for (int fm = 0; fm < 4; ++fm) {
            const int rA = wm*128 + fm*16 + lc;
            afr[fm] = *(const bf16x8*)&L[sc][0][rA*32 + ((lg ^ ((rA >> 1) & 3)) * 8)];
        }
        __builtin_amdgcn_s_setprio(1);
        #pragma unroll
        for (int fm = 0; fm < 4; ++fm)
            #pragma unroll
            for (int fn = 0; fn < 4; ++fn)
                acc[0][fm][fn] = __builtin_amdgcn_mfma_f32_16x16x32_bf16(afr[fm], bfr[fn], acc[0][fm][fn], 0, 0, 0);
        __builtin_amdgcn_s_setprio(0);
        asm volatile("s_barrier" ::: "memory");

        // ---- phase 1: stage B-half of tile t+3; quadrant qm=1 (reuse bfr)
        STG256(ss, 1, 0, ts); STG256(ss, 1, 1, ts);
        #pragma unroll
        for (int fm = 0; fm < 4; ++fm) {
            const int rA = wm*128 + 64 + fm*16 + lc;
            afr[fm] = *(const bf16x8*)&L[sc][0][rA*32 + ((lg ^ ((rA >> 1) & 3)) * 8)];
        }
        __builtin_amdgcn_s_setprio(1);
        #pragma unroll
        for (int fm = 0; fm < 4; ++fm)
            #pragma unroll
            for (int fn = 0; fn < 4; ++fn)
                acc[1][fm][fn] = __builtin_amdgcn_mfma_f32_16x16x32_bf16(afr[fm], bfr[fn], acc[1][fm][fn], 0, 0, 0);
        __builtin_amdgcn_s_setprio(0);
        asm volatile("s_barrier" ::: "memory");             // WAR guard for slot recycling
    }
#undef STG256
    asm volatile("s_waitcnt vmcnt(0)" ::: "memory");        // drain stray tail stages

    #pragma unroll
    for (int qm = 0; qm < 2; ++qm)
        #pragma unroll
        for (int fm = 0; fm < 4; ++fm)
            #pragma unroll
            for (int fn = 0; fn < 4; ++fn) {
                const size_t col = col0 + wn*64 + fn*16 + lc;
                #pragma unroll
                for (int rr = 0; rr < 4; ++rr) {
                    const size_t row = row0 + wm*128 + qm*64 + fm*16 + lg*4 + rr;
                    C[row * N + col] = acc[qm][fm][fn][rr];
                }
            }
}

// ------------------------------------------------- per-head LN + interleaved RoPE
// in: qkv (B*S, NQKV_) f32; head block at XOFF.  out: (B, NH, S, D) bf16.
template <int NH, int XOFF>
__global__ __launch_bounds__(256) void ln_rope(const float* __restrict__ x,
                                               const float* __restrict__ wln,
                                               const float* __restrict__ cosT,
                                               const float* __restrict__ sinT,
                                               const int* __restrict__ pids,
                                               __hip_bfloat16* __restrict__ out) {
    const int lane = threadIdx.x & 63, wv = threadIdx.x >> 6;
    const int r = blockIdx.x * 4 + wv;                 // row over B*S*NH
    const int h = r % NH;
    const int bs = r / NH;
    const int b = bs / S_, s = bs % S_;
    const float2 xv = *(const float2*)(x + (size_t)bs * NQKV_ + XOFF + h*D_ + lane*2);
    float sum = xv.x + xv.y;
    #pragma unroll
    for (int o = 32; o; o >>= 1) sum += __shfl_xor(sum, o);
    const float mu = sum * (1.f / D_);
    const float dx = xv.x - mu, dy = xv.y - mu;
    float vs = dx*dx + dy*dy;
    #pragma unroll
    for (int o = 32; o; o >>= 1) vs += __shfl_xor(vs, o);
    const float rs = rsqrtf(vs * (1.f / D_) + 1e-5f);
    const float2 w2 = *(const float2*)(wln + lane*2);
    const float y0 = w2.x * dx * rs, y1 = w2.y * dy * rs;
    const int p = pids[bs];
    const float2 c  = *(const float2*)(cosT + (size_t)p * D_ + lane*2);
    const float2 sn = *(const float2*)(sinT + (size_t)p * D_ + lane*2);
    __hip_bfloat162 ov;
    ov.x = __float2bfloat16(y0 * c.x - y1 * sn.x);     // even: x0*c - x1*s
    ov.y = __float2bfloat16(y1 * c.y + y0 * sn.y);     // odd:  x1*c + x0*s
    *(__hip_bfloat162*)(out + (((size_t)b * NH + h) * S_ + s) * D_ + lane*2) = ov;
}

// chunk swizzle for K tile (16B chunks, 16/row): spread over 8 bank-groups per 16-lane read
static __device__ __forceinline__ int sigk_(int r) { return (r & 3) | ((r >> 1) & 4); }

// ------------------------------------------------- sliding-window GQA flash attention v3
// Swapped QK^T (in-register P^T == PV B-frag) + block-level LDS staging of K/V^T
// via global_load_lds, double-buffered with counted vmcnt + raw s_barrier.
__global__ __launch_bounds__(256) void attn_fwd(const __hip_bfloat16* __restrict__ qr,
                                                const __hip_bfloat16* __restrict__ kr,
                                                const __hip_bfloat16* __restrict__ vt,
                                                __hip_bfloat16* __restrict__ ao) {
    __shared__ __align__(16) __hip_bfloat16 Ksl[2][64*D_];    // 2 x 16KB
    __shared__ __align__(16) __hip_bfloat16 Vsl[2][D_*64];    // 2 x 16KB
    const int lane = threadIdx.x & 63, w = threadIdx.x >> 6;
    const int lq = lane & 15, lg = lane >> 4;
    const int blk = blockIdx.x;
    const int qt = blk >> 6;                     // balance: CU's blocks span qt values
    const int bh = blk & 63;
    const int h = bh & (H_-1), b = bh >> 5;
    const int g = h >> 2;                        // GQA: kv head = h/4
    const int q0 = qt*64 + w*16;
    const int q  = q0 + lq;

    const __hip_bfloat16* qbase = qr + (((size_t)b*H_ + h)*S_ + q0) * D_;
    const __hip_bfloat16* kbase = kr + ((size_t)b*KVH_ + g) * (size_t)S_ * D_;
    const __hip_bfloat16* vbase = vt + ((size_t)b*KVH_ + g) * (size_t)D_ * S_;

    // staging lane constants
    const int srK = lane >> 4, scK = lane & 15;  // K: 4 rows x 16 chunks per wave-instr
    const int srV = lane >> 3, scV = lane & 7;   // V: 8 rows x 8 chunks per wave-instr

#define STAGE(nb, k0s) do {                                                              \
    _Pragma("unroll")                                                                    \
    for (int s_ = 0; s_ < 4; ++s_) {                                                     \
        const int rK_ = s_*16 + w*4 + srK;                                               \
        const __hip_bfloat16* srcK_ = kbase + (size_t)((k0s) + rK_)*D_                   \
                                      + ((scK ^ sigk_(rK_)) * 8);                        \
        __builtin_amdgcn_global_load_lds((const GAS void*)srcK_,                         \
            (LAS void*)&Ksl[nb][(s_*16 + w*4)*D_], 16, 0, 0);                            \
    }                                                                                    \
    _Pragma("unroll")                                                                    \
    for (int s_ = 0; s_ < 4; ++s_) {                                                     \
        const int dV_ = s_*32 + w*8 + srV;                                               \
        const __hip_bfloat16* srcV_ = vbase + (size_t)dV_*S_ + (k0s)                     \
                                      + ((scV ^ (dV_ & 7)) * 8);                         \
        __builtin_amdgcn_global_load_lds((const GAS void*)srcV_,                         \
            (LAS void*)&Vsl[nb][(s_*32 + w*8)*64], 16, 0, 0);                            \
    }                                                                                    \
} while (0)

    // Q as B-operand fragment: B[k][col=q], col=lane&15, k=lg*8+j (+32*kk)
    bf16x8 qf[4];
    #pragma unroll
    for (int kk = 0; kk < 4; ++kk)
        qf[kk] = *(const bf16x8*)(qbase + lq*D_ + kk*32 + lg*8);

    f32x4 o[8] = {};                             // out^T frags: d = n*16 + lg*4 + r, col q = lq
    float m = -1e30f, l = 0.f;

    int kst = qt*64 - (WIN_ - 1); if (kst < 0) kst = 0; kst &= ~63;
    const int nt = qt + 1 - (kst >> 6);          // tiles for the whole block (uniform)
    // A-row -> key permutation: key = 8*(row>>2) + 4*f + (row&3)
    const int kldrow = 8*(lq >> 2) + (lq & 3);

    STAGE(0, kst);

    for (int t = 0; t < nt; ++t) {
        const int k0 = kst + t*64;
        const int buf = t & 1;
        if (t + 1 < nt) {
            STAGE((t + 1) & 1, k0 + 64);
            asm volatile("s_waitcnt vmcnt(8)" ::: "memory");   // tile t staged; t+1 in flight
        } else {
            asm volatile("s_waitcnt vmcnt(0)" ::: "memory");
        }
        __builtin_amdgcn_s_barrier();

        // ---- QK^T from LDS: held value (kb,f,r): key = k0+kb*32+8*lg+4f+r
        f32x4 sc[2][2] = {};
        __builtin_amdgcn_s_setprio(1);
        #pragma unroll
        for (int kb = 0; kb < 2; ++kb)
            #pragma unroll
            for (int f = 0; f < 2; ++f) {
                const int rA = kb*32 + 4*f + kldrow;
                const __hip_bfloat16* kp = &Ksl[buf][rA*D_];
                #pragma unroll
                for (int kk = 0; kk < 4; ++kk) {
                    bf16x8 ka = *(const bf16x8*)(kp + (((kk*4 + lg) ^ sigk_(rA)) * 8));
                    sc[kb][f] = __builtin_amdgcn_mfma_f32_16x16x32_bf16(ka, qf[kk], sc[kb][f], 0, 0, 0);
                }
            }
        __builtin_amdgcn_s_setprio(0);

        // ---- online softmax, log2 domain, lane-local row
        const int dqk = q - (k0 + 8*lg);         // q - key = dqk - (kb*32+4f+r)
        float pv[16];
        float mx = -INFINITY;
        #pragma unroll
        for (int kb = 0; kb < 2; ++kb)
            #pragma unroll
            for (int f = 0; f < 2; ++f)
                #pragma unroll
                for (int r = 0; r < 4; ++r) {
                    const int c = kb*32 + 4*f + r;
                    const int d = dqk - c;
                    float v = (d >= 0 && d < WIN_) ? sc[kb][f][r] * SL2E_ : -INFINITY;
                    pv[kb*8 + f*4 + r] = v;
                    mx = fmaxf(mx, v);
                }
        mx = fmaxf(mx, __shfl_xor(mx, 16));
        mx = fmaxf(mx, __shfl_xor(mx, 32));
        const float mn = fmaxf(m, mx);
        const float alpha = exp2f(m - mn);
        float ls = 0.f;
        union { bf16x8 v; __hip_bfloat16 e[8]; } pu[2];
        #pragma unroll
        for (int kb = 0; kb < 2; ++kb)
            #pragma unroll
            for (int j = 0; j < 8; ++j) {
                const float p = exp2f(pv[kb*8 + j] - mn);
                ls += p;
                pu[kb].e[j] = __float2bfloat16(p);
            }
        ls += __shfl_xor(ls, 16);
        ls += __shfl_xor(ls, 32);
        l = l * alpha + ls;
        m = mn;
        #pragma unroll
        for (int n = 0; n < 8; ++n) {
            o[n][0] *= alpha; o[n][1] *= alpha; o[n][2] *= alpha; o[n][3] *= alpha;
        }

        // ---- PV from LDS: out^T[d][q] += V^T[d][k] * P^T[k][q]; P^T regs ARE the B-frag
        __builtin_amdgcn_s_setprio(1);
        #pragma unroll
        for (int kb = 0; kb < 2; ++kb)
            #pragma unroll
            for (int n = 0; n < 8; ++n) {
                const int dR = n*16 + lq;
                bf16x8 vf8 = *(const bf16x8*)(&Vsl[buf][dR*64] + (((kb*4 + lg) ^ (dR & 7)) * 8));
                o[n] = __builtin_amdgcn_mfma_f32_16x16x32_bf16(vf8, pu[kb].v, o[n], 0, 0, 0);
            }
        __builtin_amdgcn_s_setprio(0);

        if (t + 1 < nt) __builtin_amdgcn_s_barrier();   // all reads of buf done before overwrite
    }
#undef STAGE

    const float rinv = 1.f / l;
    #pragma unroll
    for (int n = 0; n < 8; ++n) {
        union { bf16x4 v; __hip_bfloat16 e[4]; } ov;
        #pragma unroll
        for (int r = 0; r < 4; ++r) ov.e[r] = __float2bfloat16(o[n][r] * rinv);
        *(bf16x4*)(ao + ((size_t)b*S_ + q)*(H_*D_) + h*D_ + n*16 + lg*4) = ov.v;
    }
}

// ----------------------------------------------------------------- host
extern "C" void kernel_launch(void* const* d_in, const int* in_sizes, int n_in,
                              void* d_out, int out_size, void* d_ws, size_t ws_size,
                              hipStream_t stream) {
    const float* hidden = (const float*)d_in[0];
    const int*   pids   = (const int*)  d_in[1];
    const float* cosT   = (const float*)d_in[2];
    const float* sinT   = (const float*)d_in[3];
    const float* wq     = (const float*)d_in[4];
    const float* wk     = (const float*)d_in[5];
    const float* wv     = (const float*)d_in[6];
    const float* wo     = (const float*)d_in[7];
    const float* qnw    = (const float*)d_in[8];
    const float* knw    = (const float*)d_in[9];
    float* out = (float*)d_out;

    char* base = (char*)d_ws;
    size_t off = 0;
    auto take = [&](size_t bytes) -> void* {
        void* q = base + off;
        off = (off + bytes + 255) & ~(size_t)255;
        return q;
    };
    float* qkvf          = (float*)take((size_t)NROW_*NQKV_*4);         // 96MB, reused as ao
    __hip_bfloat16* hb   = (__hip_bfloat16*)take((size_t)NROW_*HID_*2);
    __hip_bfloat16* wT   = (__hip_bfloat16*)take((size_t)NQKV_*HID_*2); // q|k|v weights^T contiguous
    __hip_bfloat16* woT  = (__hip_bfloat16*)take((size_t)HID_*HID_*2);
    __hip_bfloat16* qr   = (__hip_bfloat16*)take((size_t)B_*H_*S_*D_*2);
    __hip_bfloat16* kr   = (__hip_bfloat16*)take((size_t)B_*KVH_*S_*D_*2);
    __hip_bfloat16* vt   = (__hip_bfloat16*)take((size_t)B_*KVH_*S_*D_*2);
    __hip_bfloat16* ao   = (__hip_bfloat16*)qkvf;   // alias: q-region dead after ln_rope

    if (off > ws_size) {
        fprintf(stderr, "WORKSPACE TOO SMALL: need %zu have %zu\n", off, ws_size);
        return;
    }

    // 1. converts / transposes (wq|wk|wv into one contiguous B^T of 6144 rows)
    cvt_bf16<<<(NROW_*HID_)/1024, 256, 0, stream>>>(hidden, hb, NROW_*HID_);
    transpose_cvt<<<dim3((H_*D_)/32,   HID_/32), dim3(32,8), 0, stream>>>(wq, wT, HID_, H_*D_);
    transpose_cvt<<<dim3((KVH_*D_)/32, HID_/32), dim3(32,8), 0, stream>>>(wk, wT + (size_t)HID_*HID_, HID_, KVH_*D_);
    transpose_cvt<<<dim3((KVH_*D_)/32, HID_/32), dim3(32,8), 0, stream>>>(wv, wT + (size_t)(HID_ + KVH_*D_)*HID_, HID_, KVH_*D_);
    transpose_cvt<<<dim3(HID_/32, (H_*D_)/32),   dim3(32,8), 0, stream>>>(wo, woT, H_*D_, HID_);

    // 2. fused QKV projection: (4096 x 4096) x (6144 x 4096)^T -> (4096 x 6144)
    gemm_bt256<<<(NROW_/256)*(NQKV_/256), 512, 0, stream>>>(hb, wT, qkvf, NROW_, NQKV_, HID_, NQKV_/256);

    // 3. LN + RoPE (q, k), V transpose
    ln_rope<H_, 0><<<(B_*S_*H_)/4,                256, 0, stream>>>(qkvf, qnw, cosT, sinT, pids, qr);
    ln_rope<KVH_, HID_><<<(B_*S_*KVH_)/4,         256, 0, stream>>>(qkvf, knw, cosT, sinT, pids, kr);
    v_transpose<<<dim3(S_/32, D_/32, B_*KVH_), dim3(32,8), 0, stream>>>(qkvf, vt);

    // 4. attention
    attn_fwd<<<B_*H_*(S_/64), 256, 0, stream>>>(qr, kr, vt, ao);

    // 5. output projection -> d_out (f32)
    gemm_bt256<<<(NROW_/256)*(HID_/256), 512, 0, stream>>>(ao, woT, out, NROW_, HID_, H_*D_, HID_/256);
}

// Round 5
// 538.963 us; speedup vs baseline: 1.9090x; 1.0185x over previous
//
#include <hip/hip_runtime.h>
#include <hip/hip_bf16.h>
#include <cstdio>
#include <cstdint>

#define B_    2
#define S_    2048
#define H_    32
#define KVH_  8
#define D_    128
#define HID_  4096
#define WIN_  512
#define NROW_ (B_*S_)          // 4096 rows for projection GEMMs
#define NQKV_ 6144             // fused q|k|v output width
#define SCALE_ 0.08838834764831845f          // 128^-0.5
#define SL2E_  0.12751744932973953f          // SCALE_ * log2(e)

typedef __attribute__((ext_vector_type(8))) __bf16 bf16x8;
typedef __attribute__((ext_vector_type(4))) __bf16 bf16x4;
typedef __attribute__((ext_vector_type(4))) float  f32x4;

#define GAS __attribute__((address_space(1)))
#define LAS __attribute__((address_space(3)))

// ---------------------------------------------------------------- cvt f32->bf16
__global__ __launch_bounds__(256) void cvt_bf16(const float* __restrict__ in,
                                                __hip_bfloat16* __restrict__ out, int n) {
    int i = (blockIdx.x * 256 + threadIdx.x) * 4;
    if (i >= n) return;
    float4 v = *(const float4*)(in + i);
    __hip_bfloat162 a, b;
    a.x = __float2bfloat16(v.x); a.y = __float2bfloat16(v.y);
    b.x = __float2bfloat16(v.z); b.y = __float2bfloat16(v.w);
    *(__hip_bfloat162*)(out + i)     = a;
    *(__hip_bfloat162*)(out + i + 2) = b;
}

// ------------------------------------------------- transpose + cvt: (R,C) f32 -> (C,R) bf16
__global__ __launch_bounds__(256) void transpose_cvt(const float* __restrict__ in,
                                                     __hip_bfloat16* __restrict__ out,
                                                     int R, int C) {
    __shared__ float t[32][33];
    int tx = threadIdx.x, ty = threadIdx.y;             // (32,8)
    int r0 = blockIdx.y * 32, c0 = blockIdx.x * 32;
    #pragma unroll
    for (int i = 0; i < 4; ++i)
        t[ty + 8*i][tx] = in[(size_t)(r0 + ty + 8*i) * C + c0 + tx];
    __syncthreads();
    #pragma unroll
    for (int i = 0; i < 4; ++i)
        out[(size_t)(c0 + ty + 8*i) * R + r0 + tx] = __float2bfloat16(t[tx][ty + 8*i]);
}

// ------------------------------------------------- V: qkv f32 (cols 5120..6143) -> (B,KVH,D,S) bf16
__global__ __launch_bounds__(256) void v_transpose(const float* __restrict__ qkv,
                                                   __hip_bfloat16* __restrict__ vt) {
    __shared__ float t[32][33];
    int tx = threadIdx.x, ty = threadIdx.y;             // (32,8)
    int plane = blockIdx.z, b = plane >> 3, g = plane & 7;
    int s0 = blockIdx.x * 32, d0 = blockIdx.y * 32;
    #pragma unroll
    for (int i = 0; i < 4; ++i) {
        int s = s0 + ty + 8*i;
        t[ty + 8*i][tx] = qkv[((size_t)b*S_ + s) * NQKV_ + (HID_ + KVH_*D_) + g*D_ + d0 + tx];
    }
    __syncthreads();
    #pragma unroll
    for (int i = 0; i < 4; ++i) {
        int d = d0 + ty + 8*i;
        vt[(((size_t)b*KVH_ + g) * D_ + d) * S_ + s0 + tx] = __float2bfloat16(t[tx][ty + 8*i]);
    }
}

// ------------------------------------------------- GEMM 256x256, BK=32, deep-pipelined
// A(MxK) bf16 * Bt(NxK)^T -> C(MxN) f32.  8 waves (2Mx4N), per-wave C = 128x64.
// 4-slot LDS ring, prefetch 3 K-tiles ahead (global_load_lds w16).
// m201 phase order: {ds_read , stage} -> s_barrier -> lgkmcnt(0) -> 16 MFMA -> s_barrier,
// so post-barrier each wave issues next-phase ds_reads while MFMAs drain.
// vmcnt(8) once per K-tile (phase B) confirms tile t+1; never drains to 0 in loop.
__global__ __launch_bounds__(512, 2) void gemm_bt256(const __hip_bfloat16* __restrict__ A,
                                                     const __hip_bfloat16* __restrict__ Bt,
                                                     float* __restrict__ C,
                                                     int M, int N, int K, int nbx) {
    __shared__ __align__(16) __hip_bfloat16 L[4][2][256*32];   // 128 KiB: ring of 4 x (A,B) tiles
    const int tid  = threadIdx.x;
    const int lane = tid & 63, w = tid >> 6;
    const int wm = w >> 2, wn = w & 3;                  // 2 x 4 wave grid
    const int lc = lane & 15, lg = lane >> 4;
    // XCD-aware bijective swizzle (gridDim.x % 8 == 0 by construction)
    const int nwg = gridDim.x, cpx = nwg >> 3;
    const int bid = blockIdx.x;
    const int swz = (bid & 7) * cpx + (bid >> 3);
    const int by = swz / nbx, bx = swz - by * nbx;
    const size_t row0 = (size_t)by * 256, col0 = (size_t)bx * 256;
    const int nt = K >> 5;                              // BK = 32

    const int srow = tid >> 2;                          // staging: 0..127 rows per round
    const int spc  = tid & 3;                           // phys 16B chunk
    const int slch = spc ^ ((srow >> 1) & 3);           // pre-inverse-swizzled logical chunk
    const __hip_bfloat16* Ab = A  + row0 * K;
    const __hip_bfloat16* Bb = Bt + col0 * K;

#define STG256(s, ab, rh, kt) do {                                                        \
    const __hip_bfloat16* gb_ = (ab) ? Bb : Ab;                                           \
    const __hip_bfloat16* src_ = gb_ + (size_t)((rh)*128 + srow) * K + (size_t)(kt)*32 + slch*8; \
    __builtin_amdgcn_global_load_lds((const GAS void*)src_,                               \
        (LAS void*)&L[s][ab][(rh)*4096 + w*512], 16, 0, 0);                               \
} while (0)

    // prologue: stage tiles 0..2 into slots 0..2 (12 loads/thread); confirm tile 0
    #pragma unroll
    for (int u = 0; u < 3; ++u) {
        STG256(u, 0, 0, u); STG256(u, 0, 1, u);
        STG256(u, 1, 0, u); STG256(u, 1, 1, u);
    }
    asm volatile("s_waitcnt vmcnt(8)" ::: "memory");
    asm volatile("s_barrier" ::: "memory");

    f32x4 acc[2][4][4] = {};
    bf16x8 bfr[4], afr[4];

    for (int t = 0; t < nt; ++t) {
        const int sc = t & 3, ss = (t + 3) & 3;
        const int ts = (t + 3 < nt) ? (t + 3) : (nt - 1);   // clamped tail keeps vmcnt uniform

        // ---- phase A: ds_read {B all, A quad0} of tile t ; stage A-halves of t+3
        #pragma unroll
        for (int fn = 0; fn < 4; ++fn) {
            const int rB = wn*64 + fn*16 + lc;
            bfr[fn] = *(const bf16x8*)&L[sc][1][rB*32 + ((lg ^ ((rB >> 1) & 3)) * 8)];
        }
        #pragma unroll
        for (int fm = 0; fm < 4; ++fm) {
            const int rA = wm*128 + fm*16 + lc;
            afr[fm] = *(const bf16x8*)&L[sc][0][rA*32 + ((lg ^ ((rA >> 1) & 3)) * 8)];
        }
        STG256(ss, 0, 0, ts); STG256(ss, 0, 1, ts);
        asm volatile("s_barrier" ::: "memory");
        asm volatile("s_waitcnt lgkmcnt(0)" ::: "memory");
        __builtin_amdgcn_sched_barrier(0);
        __builtin_amdgcn_s_setprio(1);
        #pragma unroll
        for (int fm = 0; fm < 4; ++fm)
            #pragma unroll
            for (int fn = 0; fn < 4; ++fn)
                acc[0][fm][fn] = __builtin_amdgcn_mfma_f32_16x16x32_bf16(afr[fm], bfr[fn], acc[0][fm][fn], 0, 0, 0);
        __builtin_amdgcn_s_setprio(0);
        asm volatile("s_barrier" ::: "memory");

        // ---- phase B: ds_read {A quad1} of tile t ; stage B-halves of t+3 ; confirm t+1
        #pragma unroll
        for (int fm = 0; fm < 4; ++fm) {
            const int rA = wm*128 + 64 + fm*16 + lc;
            afr[fm] = *(const bf16x8*)&L[sc][0][rA*32 + ((lg ^ ((rA >> 1) & 3)) * 8)];
        }
        STG256(ss, 1, 0, ts); STG256(ss, 1, 1, ts);
        asm volatile("s_waitcnt vmcnt(8)" ::: "memory");    // t+1 landed; t+2,t+3 in flight
        asm volatile("s_barrier" ::: "memory");
        asm volatile("s_waitcnt lgkmcnt(0)" ::: "memory");
        __builtin_amdgcn_sched_barrier(0);
        __builtin_amdgcn_s_setprio(1);
        #pragma unroll
        for (int fm = 0; fm < 4; ++fm)
            #pragma unroll
            for (int fn = 0; fn < 4; ++fn)
                acc[1][fm][fn] = __builtin_amdgcn_mfma_f32_16x16x32_bf16(afr[fm], bfr[fn], acc[1][fm][fn], 0, 0, 0);
        __builtin_amdgcn_s_setprio(0);
        asm volatile("s_barrier" ::: "memory");             // WAR guard for slot recycling
    }
#undef STG256
    asm volatile("s_waitcnt vmcnt(0)" ::: "memory");        // drain stray tail stages

    #pragma unroll
    for (int qm = 0; qm < 2; ++qm)
        #pragma unroll
        for (int fm = 0; fm < 4; ++fm)
            #pragma unroll
            for (int fn = 0; fn < 4; ++fn) {
                const size_t col = col0 + wn*64 + fn*16 + lc;
                #pragma unroll
                for (int rr = 0; rr < 4; ++rr) {
                    const size_t row = row0 + wm*128 + qm*64 + fm*16 + lg*4 + rr;
                    C[row * N + col] = acc[qm][fm][fn][rr];
                }
            }
}

// ------------------------------------------------- per-head LN + interleaved RoPE
// in: qkv (B*S, NQKV_) f32; head block at XOFF.  out: (B, NH, S, D) bf16.
template <int NH, int XOFF>
__global__ __launch_bounds__(256) void ln_rope(const float* __restrict__ x,
                                               const float* __restrict__ wln,
                                               const float* __restrict__ cosT,
                                               const float* __restrict__ sinT,
                                               const int* __restrict__ pids,
                                               __hip_bfloat16* __restrict__ out) {
    const int lane = threadIdx.x & 63, wv = threadIdx.x >> 6;
    const int r = blockIdx.x * 4 + wv;                 // row over B*S*NH
    const int h = r % NH;
    const int bs = r / NH;
    const int b = bs / S_, s = bs % S_;
    const float2 xv = *(const float2*)(x + (size_t)bs * NQKV_ + XOFF + h*D_ + lane*2);
    float sum = xv.x + xv.y;
    #pragma unroll
    for (int o = 32; o; o >>= 1) sum += __shfl_xor(sum, o);
    const float mu = sum * (1.f / D_);
    const float dx = xv.x - mu, dy = xv.y - mu;
    float vs = dx*dx + dy*dy;
    #pragma unroll
    for (int o = 32; o; o >>= 1) vs += __shfl_xor(vs, o);
    const float rs = rsqrtf(vs * (1.f / D_) + 1e-5f);
    const float2 w2 = *(const float2*)(wln + lane*2);
    const float y0 = w2.x * dx * rs, y1 = w2.y * dy * rs;
    const int p = pids[bs];
    const float2 c  = *(const float2*)(cosT + (size_t)p * D_ + lane*2);
    const float2 sn = *(const float2*)(sinT + (size_t)p * D_ + lane*2);
    __hip_bfloat162 ov;
    ov.x = __float2bfloat16(y0 * c.x - y1 * sn.x);     // even: x0*c - x1*s
    ov.y = __float2bfloat16(y1 * c.y + y0 * sn.y);     // odd:  x1*c + x0*s
    *(__hip_bfloat162*)(out + (((size_t)b * NH + h) * S_ + s) * D_ + lane*2) = ov;
}

// chunk swizzle for K tile (16B chunks, 16/row): spread over 8 bank-groups per 16-lane read
static __device__ __forceinline__ int sigk_(int r) { return (r & 3) | ((r >> 1) & 4); }

// ------------------------------------------------- sliding-window GQA flash attention v3
// Swapped QK^T (in-register P^T == PV B-frag) + block-level LDS staging of K/V^T
// via global_load_lds, double-buffered with counted vmcnt + raw s_barrier.
__global__ __launch_bounds__(256) void attn_fwd(const __hip_bfloat16* __restrict__ qr,
                                                const __hip_bfloat16* __restrict__ kr,
                                                const __hip_bfloat16* __restrict__ vt,
                                                __hip_bfloat16* __restrict__ ao) {
    __shared__ __align__(16) __hip_bfloat16 Ksl[2][64*D_];    // 2 x 16KB
    __shared__ __align__(16) __hip_bfloat16 Vsl[2][D_*64];    // 2 x 16KB
    const int lane = threadIdx.x & 63, w = threadIdx.x >> 6;
    const int lq = lane & 15, lg = lane >> 4;
    const int blk = blockIdx.x;
    const int qt = blk >> 6;                     // balance: CU's blocks span qt values
    const int bh = blk & 63;
    const int h = bh & (H_-1), b = bh >> 5;
    const int g = h >> 2;                        // GQA: kv head = h/4
    const int q0 = qt*64 + w*16;
    const int q  = q0 + lq;

    const __hip_bfloat16* qbase = qr + (((size_t)b*H_ + h)*S_ + q0) * D_;
    const __hip_bfloat16* kbase = kr + ((size_t)b*KVH_ + g) * (size_t)S_ * D_;
    const __hip_bfloat16* vbase = vt + ((size_t)b*KVH_ + g) * (size_t)D_ * S_;

    // staging lane constants
    const int srK = lane >> 4, scK = lane & 15;  // K: 4 rows x 16 chunks per wave-instr
    const int srV = lane >> 3, scV = lane & 7;   // V: 8 rows x 8 chunks per wave-instr

#define STAGE(nb, k0s) do {                                                              \
    _Pragma("unroll")                                                                    \
    for (int s_ = 0; s_ < 4; ++s_) {                                                     \
        const int rK_ = s_*16 + w*4 + srK;                                               \
        const __hip_bfloat16* srcK_ = kbase + (size_t)((k0s) + rK_)*D_                   \
                                      + ((scK ^ sigk_(rK_)) * 8);                        \
        __builtin_amdgcn_global_load_lds((const GAS void*)srcK_,                         \
            (LAS void*)&Ksl[nb][(s_*16 + w*4)*D_], 16, 0, 0);                            \
    }                                                                                    \
    _Pragma("unroll")                                                                    \
    for (int s_ = 0; s_ < 4; ++s_) {                                                     \
        const int dV_ = s_*32 + w*8 + srV;                                               \
        const __hip_bfloat16* srcV_ = vbase + (size_t)dV_*S_ + (k0s)                     \
                                      + ((scV ^ (dV_ & 7)) * 8);                         \
        __builtin_amdgcn_global_load_lds((const GAS void*)srcV_,                         \
            (LAS void*)&Vsl[nb][(s_*32 + w*8)*64], 16, 0, 0);                            \
    }                                                                                    \
} while (0)

    // Q as B-operand fragment: B[k][col=q], col=lane&15, k=lg*8+j (+32*kk)
    bf16x8 qf[4];
    #pragma unroll
    for (int kk = 0; kk < 4; ++kk)
        qf[kk] = *(const bf16x8*)(qbase + lq*D_ + kk*32 + lg*8);

    f32x4 o[8] = {};                             // out^T frags: d = n*16 + lg*4 + r, col q = lq
    float m = -1e30f, l = 0.f;

    int kst = qt*64 - (WIN_ - 1); if (kst < 0) kst = 0; kst &= ~63;
    const int nt = qt + 1 - (kst >> 6);          // tiles for the whole block (uniform)
    // A-row -> key permutation: key = 8*(row>>2) + 4*f + (row&3)
    const int kldrow = 8*(lq >> 2) + (lq & 3);

    STAGE(0, kst);

    for (int t = 0; t < nt; ++t) {
        const int k0 = kst + t*64;
        const int buf = t & 1;
        if (t + 1 < nt) {
            STAGE((t + 1) & 1, k0 + 64);
            asm volatile("s_waitcnt vmcnt(8)" ::: "memory");   // tile t staged; t+1 in flight
        } else {
            asm volatile("s_waitcnt vmcnt(0)" ::: "memory");
        }
        __builtin_amdgcn_s_barrier();

        // ---- QK^T from LDS: held value (kb,f,r): key = k0+kb*32+8*lg+4f+r
        f32x4 sc[2][2] = {};
        __builtin_amdgcn_s_setprio(1);
        #pragma unroll
        for (int kb = 0; kb < 2; ++kb)
            #pragma unroll
            for (int f = 0; f < 2; ++f) {
                const int rA = kb*32 + 4*f + kldrow;
                const __hip_bfloat16* kp = &Ksl[buf][rA*D_];
                #pragma unroll
                for (int kk = 0; kk < 4; ++kk) {
                    bf16x8 ka = *(const bf16x8*)(kp + (((kk*4 + lg) ^ sigk_(rA)) * 8));
                    sc[kb][f] = __builtin_amdgcn_mfma_f32_16x16x32_bf16(ka, qf[kk], sc[kb][f], 0, 0, 0);
                }
            }
        __builtin_amdgcn_s_setprio(0);

        // ---- online softmax, log2 domain, lane-local row
        const int dqk = q - (k0 + 8*lg);         // q - key = dqk - (kb*32+4f+r)
        float pv[16];
        float mx = -INFINITY;
        #pragma unroll
        for (int kb = 0; kb < 2; ++kb)
            #pragma unroll
            for (int f = 0; f < 2; ++f)
                #pragma unroll
                for (int r = 0; r < 4; ++r) {
                    const int c = kb*32 + 4*f + r;
                    const int d = dqk - c;
                    float v = (d >= 0 && d < WIN_) ? sc[kb][f][r] * SL2E_ : -INFINITY;
                    pv[kb*8 + f*4 + r] = v;
                    mx = fmaxf(mx, v);
                }
        mx = fmaxf(mx, __shfl_xor(mx, 16));
        mx = fmaxf(mx, __shfl_xor(mx, 32));
        const float mn = fmaxf(m, mx);
        const float alpha = exp2f(m - mn);
        float ls = 0.f;
        union { bf16x8 v; __hip_bfloat16 e[8]; } pu[2];
        #pragma unroll
        for (int kb = 0; kb < 2; ++kb)
            #pragma unroll
            for (int j = 0; j < 8; ++j) {
                const float p = exp2f(pv[kb*8 + j] - mn);
                ls += p;
                pu[kb].e[j] = __float2bfloat16(p);
            }
        ls += __shfl_xor(ls, 16);
        ls += __shfl_xor(ls, 32);
        l = l * alpha + ls;
        m = mn;
        #pragma unroll
        for (int n = 0; n < 8; ++n) {
            o[n][0] *= alpha; o[n][1] *= alpha; o[n][2] *= alpha; o[n][3] *= alpha;
        }

        // ---- PV from LDS: out^T[d][q] += V^T[d][k] * P^T[k][q]; P^T regs ARE the B-frag
        __builtin_amdgcn_s_setprio(1);
        #pragma unroll
        for (int kb = 0; kb < 2; ++kb)
            #pragma unroll
            for (int n = 0; n < 8; ++n) {
                const int dR = n*16 + lq;
                bf16x8 vf8 = *(const bf16x8*)(&Vsl[buf][dR*64] + (((kb*4 + lg) ^ (dR & 7)) * 8));
                o[n] = __builtin_amdgcn_mfma_f32_16x16x32_bf16(vf8, pu[kb].v, o[n], 0, 0, 0);
            }
        __builtin_amdgcn_s_setprio(0);

        if (t + 1 < nt) __builtin_amdgcn_s_barrier();   // all reads of buf done before overwrite
    }
#undef STAGE

    const float rinv = 1.f / l;
    #pragma unroll
    for (int n = 0; n < 8; ++n) {
        union { bf16x4 v; __hip_bfloat16 e[4]; } ov;
        #pragma unroll
        for (int r = 0; r < 4; ++r) ov.e[r] = __float2bfloat16(o[n][r] * rinv);
        *(bf16x4*)(ao + ((size_t)b*S_ + q)*(H_*D_) + h*D_ + n*16 + lg*4) = ov.v;
    }
}

// ----------------------------------------------------------------- host
extern "C" void kernel_launch(void* const* d_in, const int* in_sizes, int n_in,
                              void* d_out, int out_size, void* d_ws, size_t ws_size,
                              hipStream_t stream) {
    const float* hidden = (const float*)d_in[0];
    const int*   pids   = (const int*)  d_in[1];
    const float* cosT   = (const float*)d_in[2];
    const float* sinT   = (const float*)d_in[3];
    const float* wq     = (const float*)d_in[4];
    const float* wk     = (const float*)d_in[5];
    const float* wv     = (const float*)d_in[6];
    const float* wo     = (const float*)d_in[7];
    const float* qnw    = (const float*)d_in[8];
    const float* knw    = (const float*)d_in[9];
    float* out = (float*)d_out;

    char* base = (char*)d_ws;
    size_t off = 0;
    auto take = [&](size_t bytes) -> void* {
        void* q = base + off;
        off = (off + bytes + 255) & ~(size_t)255;
        return q;
    };
    float* qkvf          = (float*)take((size_t)NROW_*NQKV_*4);         // 96MB, reused as ao
    __hip_bfloat16* hb   = (__hip_bfloat16*)take((size_t)NROW_*HID_*2);
    __hip_bfloat16* wT   = (__hip_bfloat16*)take((size_t)NQKV_*HID_*2); // q|k|v weights^T contiguous
    __hip_bfloat16* woT  = (__hip_bfloat16*)take((size_t)HID_*HID_*2);
    __hip_bfloat16* qr   = (__hip_bfloat16*)take((size_t)B_*H_*S_*D_*2);
    __hip_bfloat16* kr   = (__hip_bfloat16*)take((size_t)B_*KVH_*S_*D_*2);
    __hip_bfloat16* vt   = (__hip_bfloat16*)take((size_t)B_*KVH_*S_*D_*2);
    __hip_bfloat16* ao   = (__hip_bfloat16*)qkvf;   // alias: q-region dead after ln_rope

    if (off > ws_size) {
        fprintf(stderr, "WORKSPACE TOO SMALL: need %zu have %zu\n", off, ws_size);
        return;
    }

    // 1. converts / transposes (wq|wk|wv into one contiguous B^T of 6144 rows)
    cvt_bf16<<<(NROW_*HID_)/1024, 256, 0, stream>>>(hidden, hb, NROW_*HID_);
    transpose_cvt<<<dim3((H_*D_)/32,   HID_/32), dim3(32,8), 0, stream>>>(wq, wT, HID_, H_*D_);
    transpose_cvt<<<dim3((KVH_*D_)/32, HID_/32), dim3(32,8), 0, stream>>>(wk, wT + (size_t)HID_*HID_, HID_, KVH_*D_);
    transpose_cvt<<<dim3((KVH_*D_)/32, HID_/32), dim3(32,8), 0, stream>>>(wv, wT + (size_t)(HID_ + KVH_*D_)*HID_, HID_, KVH_*D_);
    transpose_cvt<<<dim3(HID_/32, (H_*D_)/32),   dim3(32,8), 0, stream>>>(wo, woT, H_*D_, HID_);

    // 2. fused QKV projection: (4096 x 4096) x (6144 x 4096)^T -> (4096 x 6144)
    gemm_bt256<<<(NROW_/256)*(NQKV_/256), 512, 0, stream>>>(hb, wT, qkvf, NROW_, NQKV_, HID_, NQKV_/256);

    // 3. LN + RoPE (q, k), V transpose
    ln_rope<H_, 0><<<(B_*S_*H_)/4,                256, 0, stream>>>(qkvf, qnw, cosT, sinT, pids, qr);
    ln_rope<KVH_, HID_><<<(B_*S_*KVH_)/4,         256, 0, stream>>>(qkvf, knw, cosT, sinT, pids, kr);
    v_transpose<<<dim3(S_/32, D_/32, B_*KVH_), dim3(32,8), 0, stream>>>(qkvf, vt);

    // 4. attention
    attn_fwd<<<B_*H_*(S_/64), 256, 0, stream>>>(qr, kr, vt, ao);

    // 5. output projection -> d_out (f32)
    gemm_bt256<<<(NROW_/256)*(HID_/256), 512, 0, stream>>>(ao, woT, out, NROW_, HID_, H_*D_, HID_/256);
}

// Round 6
// 519.012 us; speedup vs baseline: 1.9824x; 1.0384x over previous
//
#include <hip/hip_runtime.h>
#include <hip/hip_bf16.h>
#include <cstdio>
#include <cstdint>

#define B_    2
#define S_    2048
#define H_    32
#define KVH_  8
#define D_    128
#define HID_  4096
#define WIN_  512
#define NROW_ (B_*S_)          // 4096 rows for projection GEMMs
#define NKV_  2048             // fused k|v output width
#define SCALE_ 0.08838834764831845f          // 128^-0.5
#define SL2E_  0.12751744932973953f          // SCALE_ * log2(e)

typedef __attribute__((ext_vector_type(8))) __bf16 bf16x8;
typedef __attribute__((ext_vector_type(4))) __bf16 bf16x4;
typedef __attribute__((ext_vector_type(4))) float  f32x4;

#define GAS __attribute__((address_space(1)))
#define LAS __attribute__((address_space(3)))

// ---------------------------------------------------------------- cvt f32->bf16
__global__ __launch_bounds__(256) void cvt_bf16(const float* __restrict__ in,
                                                __hip_bfloat16* __restrict__ out, int n) {
    int i = (blockIdx.x * 256 + threadIdx.x) * 4;
    if (i >= n) return;
    float4 v = *(const float4*)(in + i);
    __hip_bfloat162 a, b;
    a.x = __float2bfloat16(v.x); a.y = __float2bfloat16(v.y);
    b.x = __float2bfloat16(v.z); b.y = __float2bfloat16(v.w);
    *(__hip_bfloat162*)(out + i)     = a;
    *(__hip_bfloat162*)(out + i + 2) = b;
}

// ------------------------------------------------- transpose + cvt: (R,C) f32 -> (C,R) bf16
__global__ __launch_bounds__(256) void transpose_cvt(const float* __restrict__ in,
                                                     __hip_bfloat16* __restrict__ out,
                                                     int R, int C) {
    __shared__ float t[32][33];
    int tx = threadIdx.x, ty = threadIdx.y;             // (32,8)
    int r0 = blockIdx.y * 32, c0 = blockIdx.x * 32;
    #pragma unroll
    for (int i = 0; i < 4; ++i)
        t[ty + 8*i][tx] = in[(size_t)(r0 + ty + 8*i) * C + c0 + tx];
    __syncthreads();
    #pragma unroll
    for (int i = 0; i < 4; ++i)
        out[(size_t)(c0 + ty + 8*i) * R + r0 + tx] = __float2bfloat16(t[tx][ty + 8*i]);
}

// ------------------------------------------------- V: kvf f32 (cols 1024..2047) -> (B,KVH,D,S) bf16
__global__ __launch_bounds__(256) void v_transpose(const float* __restrict__ kvf,
                                                   __hip_bfloat16* __restrict__ vt) {
    __shared__ float t[32][33];
    int tx = threadIdx.x, ty = threadIdx.y;             // (32,8)
    int plane = blockIdx.z, b = plane >> 3, g = plane & 7;
    int s0 = blockIdx.x * 32, d0 = blockIdx.y * 32;
    #pragma unroll
    for (int i = 0; i < 4; ++i) {
        int s = s0 + ty + 8*i;
        t[ty + 8*i][tx] = kvf[((size_t)b*S_ + s) * NKV_ + (KVH_*D_) + g*D_ + d0 + tx];
    }
    __syncthreads();
    #pragma unroll
    for (int i = 0; i < 4; ++i) {
        int d = d0 + ty + 8*i;
        vt[(((size_t)b*KVH_ + g) * D_ + d) * S_ + s0 + tx] = __float2bfloat16(t[tx][ty + 8*i]);
    }
}

// ------------------------------------------------- GEMM 256xBN, BK=32, deep-pipelined
// A(MxK) bf16 * Bt(NxK)^T -> C(MxN) f32.  8 waves (2Mx4N); BN = FN*64; per-wave C = 128x(FN*16).
// Ring-4 LDS slots, 3-tile prefetch lead via global_load_lds w16.
// Phase (one per K-tile): {FN+8 ds_read ; stage 1 tile (L loads) ; vmcnt(2L) ; s_barrier ;
//   lgkmcnt(0)+sched_barrier ; 8*FN MFMA in setprio(1)}.  ONE barrier per 32 MFMA (FN=4).
// Hazards: slot t confirmed by phase(t-2)'s vmcnt+barrier; slot reuse WAR safe because all
// reads of a slot precede that phase's barrier and the overwriting stage issues after it.
template <int FN>
__global__ __launch_bounds__(512, 2) void gemm_t(const __hip_bfloat16* __restrict__ A,
                                                 const __hip_bfloat16* __restrict__ Bt,
                                                 float* __restrict__ C,
                                                 int M, int N, int K, int nbx) {
    constexpr int BN   = FN * 64;
    constexpr int SLOT = (256 + BN) * 32;               // elems per ring slot (A then B)
    constexpr int LPT  = 2 + BN / 128;                  // stage loads per thread per tile
    __shared__ __align__(16) __hip_bfloat16 L[4 * SLOT];
    const int tid  = threadIdx.x;
    const int lane = tid & 63, w = tid >> 6;
    const int wm = w >> 2, wn = w & 3;                  // 2 x 4 wave grid
    const int lc = lane & 15, lg = lane >> 4;
    // XCD-aware bijective swizzle (gridDim.x % 8 == 0 by construction)
    const int nwg = gridDim.x, cpx = nwg >> 3;
    const int bid = blockIdx.x;
    const int swz = (bid & 7) * cpx + (bid >> 3);
    const int by = swz / nbx, bx = swz - by * nbx;
    const size_t row0 = (size_t)by * 256, col0 = (size_t)bx * BN;
    const int nt = K >> 5;                              // BK = 32, nt even

    const int srow = tid >> 2;                          // staging row 0..127 per load
    const int spc  = tid & 3;                           // phys 16B chunk in row
    const int slx  = spc ^ ((srow >> 1) & 3);           // pre-inverse-swizzled source chunk
    const __hip_bfloat16* Ab = A  + row0 * K;
    const __hip_bfloat16* Bb = Bt + col0 * K;

#define STG(tile_) do {                                                                    \
    const int ss_ = (tile_) & 3;                                                           \
    const int kt_ = ((tile_) < nt) ? (tile_) : (nt - 1);  /* clamped tail, uniform count */\
    _Pragma("unroll")                                                                      \
    for (int rh_ = 0; rh_ < 2; ++rh_)                                                      \
        __builtin_amdgcn_global_load_lds(                                                  \
            (const GAS void*)(Ab + (size_t)(rh_*128 + srow) * K + kt_*32 + slx*8),         \
            (LAS void*)&L[ss_*SLOT + rh_*4096 + w*512], 16, 0, 0);                         \
    _Pragma("unroll")                                                                      \
    for (int bh_ = 0; bh_ < BN/128; ++bh_)                                                 \
        __builtin_amdgcn_global_load_lds(                                                  \
            (const GAS void*)(Bb + (size_t)(bh_*128 + srow) * K + kt_*32 + slx*8),         \
            (LAS void*)&L[ss_*SLOT + 8192 + bh_*4096 + w*512], 16, 0, 0);                  \
} while (0)

#define VMW() do {                                                                         \
    if constexpr (FN == 4) asm volatile("s_waitcnt vmcnt(8)" ::: "memory");                \
    else                   asm volatile("s_waitcnt vmcnt(6)" ::: "memory");                \
} while (0)

    f32x4 acc[2][4][FN] = {};
    bf16x8 afr[2][4], bfr[FN];

#define PHASE(tt_) do {                                                                    \
    const int s_ = (tt_) & 3;                                                              \
    _Pragma("unroll")                                                                      \
    for (int fn = 0; fn < FN; ++fn) {                                                      \
        const int rB = wn*(FN*16) + fn*16 + lc;                                            \
        bfr[fn] = *(const bf16x8*)&L[s_*SLOT + 8192 + rB*32 + ((lg ^ ((rB >> 1) & 3)) * 8)]; \
    }                                                                                      \
    _Pragma("unroll")                                                                      \
    for (int qm = 0; qm < 2; ++qm)                                                         \
        _Pragma("unroll")                                                                  \
        for (int fm = 0; fm < 4; ++fm) {                                                   \
            const int rA = wm*128 + qm*64 + fm*16 + lc;                                    \
            afr[qm][fm] = *(const bf16x8*)&L[s_*SLOT + rA*32 + ((lg ^ ((rA >> 1) & 3)) * 8)]; \
        }                                                                                  \
    STG((tt_) + 3);                                                                        \
    VMW();                                                                                 \
    asm volatile("s_barrier" ::: "memory");                                                \
    asm volatile("s_waitcnt lgkmcnt(0)" ::: "memory");                                     \
    __builtin_amdgcn_sched_barrier(0);                                                     \
    __builtin_amdgcn_s_setprio(1);                                                         \
    _Pragma("unroll")                                                                      \
    for (int qm = 0; qm < 2; ++qm)                                                         \
        _Pragma("unroll")                                                                  \
        for (int fm = 0; fm < 4; ++fm)                                                     \
            _Pragma("unroll")                                                              \
            for (int fn = 0; fn < FN; ++fn)                                                \
                acc[qm][fm][fn] = __builtin_amdgcn_mfma_f32_16x16x32_bf16(                 \
                    afr[qm][fm], bfr[fn], acc[qm][fm][fn], 0, 0, 0);                       \
    __builtin_amdgcn_s_setprio(0);                                                         \
} while (0)

    // prologue: stage tiles 0..2 into slots 0..2; confirm tile 0
    STG(0); STG(1); STG(2);
    VMW();
    asm volatile("s_barrier" ::: "memory");

    for (int t = 0; t < nt; t += 2) {
        PHASE(t);
        PHASE(t + 1);
    }
#undef PHASE
#undef STG
#undef VMW
    asm volatile("s_waitcnt vmcnt(0)" ::: "memory");    // drain clamped tail stages

    #pragma unroll
    for (int qm = 0; qm < 2; ++qm)
        #pragma unroll
        for (int fm = 0; fm < 4; ++fm)
            #pragma unroll
            for (int fn = 0; fn < FN; ++fn) {
                const size_t col = col0 + wn*(FN*16) + fn*16 + lc;
                #pragma unroll
                for (int rr = 0; rr < 4; ++rr) {
                    const size_t row = row0 + wm*128 + qm*64 + fm*16 + lg*4 + rr;
                    C[row * N + col] = acc[qm][fm][fn][rr];
                }
            }
}

// ------------------------------------------------- per-head LN + interleaved RoPE
// in: x (B*S, LD) f32; head block at XOFF.  out: (B, NH, S, D) bf16.
template <int NH, int LD, int XOFF>
__global__ __launch_bounds__(256) void ln_rope(const float* __restrict__ x,
                                               const float* __restrict__ wln,
                                               const float* __restrict__ cosT,
                                               const float* __restrict__ sinT,
                                               const int* __restrict__ pids,
                                               __hip_bfloat16* __restrict__ out) {
    const int lane = threadIdx.x & 63, wv = threadIdx.x >> 6;
    const int r = blockIdx.x * 4 + wv;                 // row over B*S*NH
    const int h = r % NH;
    const int bs = r / NH;
    const int b = bs / S_, s = bs % S_;
    const float2 xv = *(const float2*)(x + (size_t)bs * LD + XOFF + h*D_ + lane*2);
    float sum = xv.x + xv.y;
    #pragma unroll
    for (int o = 32; o; o >>= 1) sum += __shfl_xor(sum, o);
    const float mu = sum * (1.f / D_);
    const float dx = xv.x - mu, dy = xv.y - mu;
    float vs = dx*dx + dy*dy;
    #pragma unroll
    for (int o = 32; o; o >>= 1) vs += __shfl_xor(vs, o);
    const float rs = rsqrtf(vs * (1.f / D_) + 1e-5f);
    const float2 w2 = *(const float2*)(wln + lane*2);
    const float y0 = w2.x * dx * rs, y1 = w2.y * dy * rs;
    const int p = pids[bs];
    const float2 c  = *(const float2*)(cosT + (size_t)p * D_ + lane*2);
    const float2 sn = *(const float2*)(sinT + (size_t)p * D_ + lane*2);
    __hip_bfloat162 ov;
    ov.x = __float2bfloat16(y0 * c.x - y1 * sn.x);     // even: x0*c - x1*s
    ov.y = __float2bfloat16(y1 * c.y + y0 * sn.y);     // odd:  x1*c + x0*s
    *(__hip_bfloat162*)(out + (((size_t)b * NH + h) * S_ + s) * D_ + lane*2) = ov;
}

// chunk swizzle for K tile (16B chunks, 16/row): spread over 8 bank-groups per 16-lane read
static __device__ __forceinline__ int sigk_(int r) { return (r & 3) | ((r >> 1) & 4); }

// ------------------------------------------------- sliding-window GQA flash attention v3
// Swapped QK^T (in-register P^T == PV B-frag) + block-level LDS staging of K/V^T
// via global_load_lds, double-buffered with counted vmcnt + raw s_barrier.
__global__ __launch_bounds__(256) void attn_fwd(const __hip_bfloat16* __restrict__ qr,
                                                const __hip_bfloat16* __restrict__ kr,
                                                const __hip_bfloat16* __restrict__ vt,
                                                __hip_bfloat16* __restrict__ ao) {
    __shared__ __align__(16) __hip_bfloat16 Ksl[2][64*D_];    // 2 x 16KB
    __shared__ __align__(16) __hip_bfloat16 Vsl[2][D_*64];    // 2 x 16KB
    const int lane = threadIdx.x & 63, w = threadIdx.x >> 6;
    const int lq = lane & 15, lg = lane >> 4;
    const int blk = blockIdx.x;
    const int qt = blk >> 6;                     // balance: CU's blocks span qt values
    const int bh = blk & 63;
    const int h = bh & (H_-1), b = bh >> 5;
    const int g = h >> 2;                        // GQA: kv head = h/4
    const int q0 = qt*64 + w*16;
    const int q  = q0 + lq;

    const __hip_bfloat16* qbase = qr + (((size_t)b*H_ + h)*S_ + q0) * D_;
    const __hip_bfloat16* kbase = kr + ((size_t)b*KVH_ + g) * (size_t)S_ * D_;
    const __hip_bfloat16* vbase = vt + ((size_t)b*KVH_ + g) * (size_t)D_ * S_;

    // staging lane constants
    const int srK = lane >> 4, scK = lane & 15;  // K: 4 rows x 16 chunks per wave-instr
    const int srV = lane >> 3, scV = lane & 7;   // V: 8 rows x 8 chunks per wave-instr

#define STAGE(nb, k0s) do {                                                              \
    _Pragma("unroll")                                                                    \
    for (int s_ = 0; s_ < 4; ++s_) {                                                     \
        const int rK_ = s_*16 + w*4 + srK;                                               \
        const __hip_bfloat16* srcK_ = kbase + (size_t)((k0s) + rK_)*D_                   \
                                      + ((scK ^ sigk_(rK_)) * 8);                        \
        __builtin_amdgcn_global_load_lds((const GAS void*)srcK_,                         \
            (LAS void*)&Ksl[nb][(s_*16 + w*4)*D_], 16, 0, 0);                            \
    }                                                                                    \
    _Pragma("unroll")                                                                    \
    for (int s_ = 0; s_ < 4; ++s_) {                                                     \
        const int dV_ = s_*32 + w*8 + srV;                                               \
        const __hip_bfloat16* srcV_ = vbase + (size_t)dV_*S_ + (k0s)                     \
                                      + ((scV ^ (dV_ & 7)) * 8);                         \
        __builtin_amdgcn_global_load_lds((const GAS void*)srcV_,                         \
            (LAS void*)&Vsl[nb][(s_*32 + w*8)*64], 16, 0, 0);                            \
    }                                                                                    \
} while (0)

    // Q as B-operand fragment: B[k][col=q], col=lane&15, k=lg*8+j (+32*kk)
    bf16x8 qf[4];
    #pragma unroll
    for (int kk = 0; kk < 4; ++kk)
        qf[kk] = *(const bf16x8*)(qbase + lq*D_ + kk*32 + lg*8);

    f32x4 o[8] = {};                             // out^T frags: d = n*16 + lg*4 + r, col q = lq
    float m = -1e30f, l = 0.f;

    int kst = qt*64 - (WIN_ - 1); if (kst < 0) kst = 0; kst &= ~63;
    const int nt = qt + 1 - (kst >> 6);          // tiles for the whole block (uniform)
    // A-row -> key permutation: key = 8*(row>>2) + 4*f + (row&3)
    const int kldrow = 8*(lq >> 2) + (lq & 3);

    STAGE(0, kst);

    for (int t = 0; t < nt; ++t) {
        const int k0 = kst + t*64;
        const int buf = t & 1;
        if (t + 1 < nt) {
            STAGE((t + 1) & 1, k0 + 64);
            asm volatile("s_waitcnt vmcnt(8)" ::: "memory");   // tile t staged; t+1 in flight
        } else {
            asm volatile("s_waitcnt vmcnt(0)" ::: "memory");
        }
        __builtin_amdgcn_s_barrier();

        // ---- QK^T from LDS: held value (kb,f,r): key = k0+kb*32+8*lg+4f+r
        f32x4 sc[2][2] = {};
        __builtin_amdgcn_s_setprio(1);
        #pragma unroll
        for (int kb = 0; kb < 2; ++kb)
            #pragma unroll
            for (int f = 0; f < 2; ++f) {
                const int rA = kb*32 + 4*f + kldrow;
                const __hip_bfloat16* kp = &Ksl[buf][rA*D_];
                #pragma unroll
                for (int kk = 0; kk < 4; ++kk) {
                    bf16x8 ka = *(const bf16x8*)(kp + (((kk*4 + lg) ^ sigk_(rA)) * 8));
                    sc[kb][f] = __builtin_amdgcn_mfma_f32_16x16x32_bf16(ka, qf[kk], sc[kb][f], 0, 0, 0);
                }
            }
        __builtin_amdgcn_s_setprio(0);

        // ---- online softmax, log2 domain, lane-local row
        const int dqk = q - (k0 + 8*lg);         // q - key = dqk - (kb*32+4f+r)
        float pv[16];
        float mx = -INFINITY;
        #pragma unroll
        for (int kb = 0; kb < 2; ++kb)
            #pragma unroll
            for (int f = 0; f < 2; ++f)
                #pragma unroll
                for (int r = 0; r < 4; ++r) {
                    const int c = kb*32 + 4*f + r;
                    const int d = dqk - c;
                    float v = (d >= 0 && d < WIN_) ? sc[kb][f][r] * SL2E_ : -INFINITY;
                    pv[kb*8 + f*4 + r] = v;
                    mx = fmaxf(mx, v);
                }
        mx = fmaxf(mx, __shfl_xor(mx, 16));
        mx = fmaxf(mx, __shfl_xor(mx, 32));
        const float mn = fmaxf(m, mx);
        const float alpha = exp2f(m - mn);
        float ls = 0.f;
        union { bf16x8 v; __hip_bfloat16 e[8]; } pu[2];
        #pragma unroll
        for (int kb = 0; kb < 2; ++kb)
            #pragma unroll
            for (int j = 0; j < 8; ++j) {
                const float p = exp2f(pv[kb*8 + j] - mn);
                ls += p;
                pu[kb].e[j] = __float2bfloat16(p);
            }
        ls += __shfl_xor(ls, 16);
        ls += __shfl_xor(ls, 32);
        l = l * alpha + ls;
        m = mn;
        #pragma unroll
        for (int n = 0; n < 8; ++n) {
            o[n][0] *= alpha; o[n][1] *= alpha; o[n][2] *= alpha; o[n][3] *= alpha;
        }

        // ---- PV from LDS: out^T[d][q] += V^T[d][k] * P^T[k][q]; P^T regs ARE the B-frag
        __builtin_amdgcn_s_setprio(1);
        #pragma unroll
        for (int kb = 0; kb < 2; ++kb)
            #pragma unroll
            for (int n = 0; n < 8; ++n) {
                const int dR = n*16 + lq;
                bf16x8 vf8 = *(const bf16x8*)(&Vsl[buf][dR*64] + (((kb*4 + lg) ^ (dR & 7)) * 8));
                o[n] = __builtin_amdgcn_mfma_f32_16x16x32_bf16(vf8, pu[kb].v, o[n], 0, 0, 0);
            }
        __builtin_amdgcn_s_setprio(0);

        if (t + 1 < nt) __builtin_amdgcn_s_barrier();   // all reads of buf done before overwrite
    }
#undef STAGE

    const float rinv = 1.f / l;
    #pragma unroll
    for (int n = 0; n < 8; ++n) {
        union { bf16x4 v; __hip_bfloat16 e[4]; } ov;
        #pragma unroll
        for (int r = 0; r < 4; ++r) ov.e[r] = __float2bfloat16(o[n][r] * rinv);
        *(bf16x4*)(ao + ((size_t)b*S_ + q)*(H_*D_) + h*D_ + n*16 + lg*4) = ov.v;
    }
}

// ----------------------------------------------------------------- host
extern "C" void kernel_launch(void* const* d_in, const int* in_sizes, int n_in,
                              void* d_out, int out_size, void* d_ws, size_t ws_size,
                              hipStream_t stream) {
    const float* hidden = (const float*)d_in[0];
    const int*   pids   = (const int*)  d_in[1];
    const float* cosT   = (const float*)d_in[2];
    const float* sinT   = (const float*)d_in[3];
    const float* wq     = (const float*)d_in[4];
    const float* wk     = (const float*)d_in[5];
    const float* wv     = (const float*)d_in[6];
    const float* wo     = (const float*)d_in[7];
    const float* qnw    = (const float*)d_in[8];
    const float* knw    = (const float*)d_in[9];
    float* out = (float*)d_out;

    char* base = (char*)d_ws;
    size_t off = 0;
    auto take = [&](size_t bytes) -> void* {
        void* q = base + off;
        off = (off + bytes + 255) & ~(size_t)255;
        return q;
    };
    float* qf            = (float*)take((size_t)NROW_*HID_*4);          // 64MB, reused as ao
    float* kvf           = (float*)take((size_t)NROW_*NKV_*4);          // 32MB
    __hip_bfloat16* hb   = (__hip_bfloat16*)take((size_t)NROW_*HID_*2);
    __hip_bfloat16* wqT  = (__hip_bfloat16*)take((size_t)HID_*HID_*2);
    __hip_bfloat16* wkvT = (__hip_bfloat16*)take((size_t)NKV_*HID_*2);  // k|v weights^T contiguous
    __hip_bfloat16* woT  = (__hip_bfloat16*)take((size_t)HID_*HID_*2);
    __hip_bfloat16* qr   = (__hip_bfloat16*)take((size_t)B_*H_*S_*D_*2);
    __hip_bfloat16* kr   = (__hip_bfloat16*)take((size_t)B_*KVH_*S_*D_*2);
    __hip_bfloat16* vt   = (__hip_bfloat16*)take((size_t)B_*KVH_*S_*D_*2);
    __hip_bfloat16* ao   = (__hip_bfloat16*)qf;     // alias: qf dead after ln_rope<Q>

    if (off > ws_size) {
        fprintf(stderr, "WORKSPACE TOO SMALL: need %zu have %zu\n", off, ws_size);
        return;
    }

    // 1. converts / transposes (wk|wv into one contiguous B^T of 2048 rows)
    cvt_bf16<<<(NROW_*HID_)/1024, 256, 0, stream>>>(hidden, hb, NROW_*HID_);
    transpose_cvt<<<dim3((H_*D_)/32,   HID_/32), dim3(32,8), 0, stream>>>(wq, wqT, HID_, H_*D_);
    transpose_cvt<<<dim3((KVH_*D_)/32, HID_/32), dim3(32,8), 0, stream>>>(wk, wkvT, HID_, KVH_*D_);
    transpose_cvt<<<dim3((KVH_*D_)/32, HID_/32), dim3(32,8), 0, stream>>>(wv, wkvT + (size_t)(KVH_*D_)*HID_, HID_, KVH_*D_);
    transpose_cvt<<<dim3(HID_/32, (H_*D_)/32),   dim3(32,8), 0, stream>>>(wo, woT, H_*D_, HID_);

    // 2. projections — every grid exactly 256 blocks (1 round on 256 CUs)
    gemm_t<4><<<(NROW_/256)*(HID_/256), 512, 0, stream>>>(hb, wqT,  qf,  NROW_, HID_, HID_, HID_/256);
    gemm_t<2><<<(NROW_/256)*(NKV_/128), 512, 0, stream>>>(hb, wkvT, kvf, NROW_, NKV_, HID_, NKV_/128);

    // 3. LN + RoPE (q, k), V transpose
    ln_rope<H_,   HID_, 0><<<(B_*S_*H_)/4,   256, 0, stream>>>(qf,  qnw, cosT, sinT, pids, qr);
    ln_rope<KVH_, NKV_, 0><<<(B_*S_*KVH_)/4, 256, 0, stream>>>(kvf, knw, cosT, sinT, pids, kr);
    v_transpose<<<dim3(S_/32, D_/32, B_*KVH_), dim3(32,8), 0, stream>>>(kvf, vt);

    // 4. attention
    attn_fwd<<<B_*H_*(S_/64), 256, 0, stream>>>(qr, kr, vt, ao);

    // 5. output projection -> d_out (f32)
    gemm_t<4><<<(NROW_/256)*(HID_/256), 512, 0, stream>>>(ao, woT, out, NROW_, HID_, H_*D_, HID_/256);
}

// Round 7
// 513.176 us; speedup vs baseline: 2.0049x; 1.0114x over previous
//
#include <hip/hip_runtime.h>
#include <hip/hip_bf16.h>
#include <cstdio>
#include <cstdint>

#define B_    2
#define S_    2048
#define H_    32
#define KVH_  8
#define D_    128
#define HID_  4096
#define WIN_  512
#define NROW_ (B_*S_)          // 4096 rows for projection GEMMs
#define NKV_  2048             // fused k|v output width
#define SCALE_ 0.08838834764831845f          // 128^-0.5
#define SL2E_  0.12751744932973953f          // SCALE_ * log2(e)

typedef __attribute__((ext_vector_type(8))) __bf16 bf16x8;
typedef __attribute__((ext_vector_type(4))) __bf16 bf16x4;
typedef __attribute__((ext_vector_type(4))) float  f32x4;

#define GAS __attribute__((address_space(1)))
#define LAS __attribute__((address_space(3)))

// ---------------------------------------------------------------- cvt f32->bf16
__global__ __launch_bounds__(256) void cvt_bf16(const float* __restrict__ in,
                                                __hip_bfloat16* __restrict__ out, int n) {
    int i = (blockIdx.x * 256 + threadIdx.x) * 4;
    if (i >= n) return;
    float4 v = *(const float4*)(in + i);
    __hip_bfloat162 a, b;
    a.x = __float2bfloat16(v.x); a.y = __float2bfloat16(v.y);
    b.x = __float2bfloat16(v.z); b.y = __float2bfloat16(v.w);
    *(__hip_bfloat162*)(out + i)     = a;
    *(__hip_bfloat162*)(out + i + 2) = b;
}

// ------------------------------------------------- transpose + cvt: (R,C) f32 -> (C,R) bf16
__global__ __launch_bounds__(256) void transpose_cvt(const float* __restrict__ in,
                                                     __hip_bfloat16* __restrict__ out,
                                                     int R, int C) {
    __shared__ float t[32][33];
    int tx = threadIdx.x, ty = threadIdx.y;             // (32,8)
    int r0 = blockIdx.y * 32, c0 = blockIdx.x * 32;
    #pragma unroll
    for (int i = 0; i < 4; ++i)
        t[ty + 8*i][tx] = in[(size_t)(r0 + ty + 8*i) * C + c0 + tx];
    __syncthreads();
    #pragma unroll
    for (int i = 0; i < 4; ++i)
        out[(size_t)(c0 + ty + 8*i) * R + r0 + tx] = __float2bfloat16(t[tx][ty + 8*i]);
}

// ------------------------------------------------- V: kvf f32 (cols 1024..2047) -> (B,KVH,D,S) bf16
__global__ __launch_bounds__(256) void v_transpose(const float* __restrict__ kvf,
                                                   __hip_bfloat16* __restrict__ vt) {
    __shared__ float t[32][33];
    int tx = threadIdx.x, ty = threadIdx.y;             // (32,8)
    int plane = blockIdx.z, b = plane >> 3, g = plane & 7;
    int s0 = blockIdx.x * 32, d0 = blockIdx.y * 32;
    #pragma unroll
    for (int i = 0; i < 4; ++i) {
        int s = s0 + ty + 8*i;
        t[ty + 8*i][tx] = kvf[((size_t)b*S_ + s) * NKV_ + (KVH_*D_) + g*D_ + d0 + tx];
    }
    __syncthreads();
    #pragma unroll
    for (int i = 0; i < 4; ++i) {
        int d = d0 + ty + 8*i;
        vt[(((size_t)b*KVH_ + g) * D_ + d) * S_ + s0 + tx] = __float2bfloat16(t[tx][ty + 8*i]);
    }
}

// ------------------------------------------------- GEMM 256xBN, BK=32, deep-pipelined, 2-phase/tile
// A(MxK) bf16 * Bt(NxK)^T -> C(MxN) f32.  8 waves (2Mx4N); BN = FN*64; per-wave C = 128x(FN*16).
// Ring-4 LDS slots, 3-tile prefetch lead via global_load_lds w16.
// Tile t = 2 phases of 16*FN/2 MFMA (quadrant split on M):
//   alpha: {ds_read B(FN)+A q0(4) ; STGA(t+3) ; vmcnt(10|8) ; s_barrier ; lgkm(0) ; 16 MFMA}
//   beta : {ds_read A q1(4)      ; STGB(t+3) ;              lgkm(0)  ; 16 MFMA ; s_barrier}
// beta has NO pre-MFMA barrier -> waves de-sync within the tile (finer MFMA packing, T3).
// WAR: stage at (t,*) targets slot t-1; all slot t-1 reads complete before the (t-1,beta)
// end-barrier / (t,alpha) barrier preceding the stage issue.  vmcnt: tile t staged 6 phases
// back; loads issued after = 10 (FN4) / 8 (FN2).
template <int FN>
__global__ __launch_bounds__(512, 2) void gemm_t(const __hip_bfloat16* __restrict__ A,
                                                 const __hip_bfloat16* __restrict__ Bt,
                                                 float* __restrict__ C,
                                                 int M, int N, int K, int nbx) {
    constexpr int BN   = FN * 64;
    constexpr int BLD  = BN / 128;                      // B stage loads/thread/tile (2 or 1)
    constexpr int SLOT = (256 + BN) * 32;               // elems per ring slot (A then B)
    __shared__ __align__(16) __hip_bfloat16 L[4 * SLOT];
    const int tid  = threadIdx.x;
    const int lane = tid & 63, w = tid >> 6;
    const int wm = w >> 2, wn = w & 3;                  // 2 x 4 wave grid
    const int lc = lane & 15, lg = lane >> 4;
    // XCD-aware bijective swizzle (gridDim.x % 8 == 0 by construction)
    const int nwg = gridDim.x, cpx = nwg >> 3;
    const int bid = blockIdx.x;
    const int swz = (bid & 7) * cpx + (bid >> 3);
    const int by = swz / nbx, bx = swz - by * nbx;
    const size_t row0 = (size_t)by * 256, col0 = (size_t)bx * BN;
    const int nt = K >> 5;                              // BK = 32

    const int srow = tid >> 2;                          // staging row 0..127 per load
    const int spc  = tid & 3;                           // phys 16B chunk in row
    const int slx  = spc ^ ((srow >> 1) & 3);           // pre-inverse-swizzled source chunk
    const __hip_bfloat16* Ab = A  + row0 * K;
    const __hip_bfloat16* Bb = Bt + col0 * K;

#define STGA(tile_) do {                                                                   \
    const int ss_ = (tile_) & 3;                                                           \
    const int kt_ = ((tile_) < nt) ? (tile_) : (nt - 1);  /* clamped tail, uniform count */\
    _Pragma("unroll")                                                                      \
    for (int rh_ = 0; rh_ < 2; ++rh_)                                                      \
        __builtin_amdgcn_global_load_lds(                                                  \
            (const GAS void*)(Ab + (size_t)(rh_*128 + srow) * K + kt_*32 + slx*8),         \
            (LAS void*)&L[ss_*SLOT + rh_*4096 + w*512], 16, 0, 0);                         \
} while (0)

#define STGB(tile_) do {                                                                   \
    const int ss_ = (tile_) & 3;                                                           \
    const int kt_ = ((tile_) < nt) ? (tile_) : (nt - 1);                                   \
    _Pragma("unroll")                                                                      \
    for (int bh_ = 0; bh_ < BLD; ++bh_)                                                    \
        __builtin_amdgcn_global_load_lds(                                                  \
            (const GAS void*)(Bb + (size_t)(bh_*128 + srow) * K + kt_*32 + slx*8),         \
            (LAS void*)&L[ss_*SLOT + 8192 + bh_*4096 + w*512], 16, 0, 0);                  \
} while (0)

    f32x4 acc[2][4][FN] = {};
    bf16x8 afr[4], bfr[FN];

    // prologue: stage tiles 0..2 into slots 0..2; confirm tile 0
    STGA(0); STGB(0); STGA(1); STGB(1); STGA(2); STGB(2);
    if constexpr (FN == 4) asm volatile("s_waitcnt vmcnt(8)" ::: "memory");
    else                   asm volatile("s_waitcnt vmcnt(6)" ::: "memory");
    asm volatile("s_barrier" ::: "memory");

    for (int t = 0; t < nt; ++t) {
        const int s_ = t & 3;

        // ---- phase alpha: B frags + A quadrant 0 ; stage A of t+3
        #pragma unroll
        for (int fn = 0; fn < FN; ++fn) {
            const int rB = wn*(FN*16) + fn*16 + lc;
            bfr[fn] = *(const bf16x8*)&L[s_*SLOT + 8192 + rB*32 + ((lg ^ ((rB >> 1) & 3)) * 8)];
        }
        #pragma unroll
        for (int fm = 0; fm < 4; ++fm) {
            const int rA = wm*128 + fm*16 + lc;
            afr[fm] = *(const bf16x8*)&L[s_*SLOT + rA*32 + ((lg ^ ((rA >> 1) & 3)) * 8)];
        }
        STGA(t + 3);
        if constexpr (FN == 4) asm volatile("s_waitcnt vmcnt(10)" ::: "memory");
        else                   asm volatile("s_waitcnt vmcnt(8)"  ::: "memory");
        asm volatile("s_barrier" ::: "memory");
        asm volatile("s_waitcnt lgkmcnt(0)" ::: "memory");
        __builtin_amdgcn_sched_barrier(0);
        __builtin_amdgcn_s_setprio(1);
        #pragma unroll
        for (int fm = 0; fm < 4; ++fm)
            #pragma unroll
            for (int fn = 0; fn < FN; ++fn)
                acc[0][fm][fn] = __builtin_amdgcn_mfma_f32_16x16x32_bf16(
                    afr[fm], bfr[fn], acc[0][fm][fn], 0, 0, 0);
        __builtin_amdgcn_s_setprio(0);

        // ---- phase beta: A quadrant 1 ; stage B of t+3 ; NO pre-MFMA barrier
        #pragma unroll
        for (int fm = 0; fm < 4; ++fm) {
            const int rA = wm*128 + 64 + fm*16 + lc;
            afr[fm] = *(const bf16x8*)&L[s_*SLOT + rA*32 + ((lg ^ ((rA >> 1) & 3)) * 8)];
        }
        STGB(t + 3);
        asm volatile("s_waitcnt lgkmcnt(0)" ::: "memory");
        __builtin_amdgcn_sched_barrier(0);
        __builtin_amdgcn_s_setprio(1);
        #pragma unroll
        for (int fm = 0; fm < 4; ++fm)
            #pragma unroll
            for (int fn = 0; fn < FN; ++fn)
                acc[1][fm][fn] = __builtin_amdgcn_mfma_f32_16x16x32_bf16(
                    afr[fm], bfr[fn], acc[1][fm][fn], 0, 0, 0);
        __builtin_amdgcn_s_setprio(0);
        asm volatile("s_barrier" ::: "memory");         // end-of-tile: guards slot recycling
    }
#undef STGA
#undef STGB
    asm volatile("s_waitcnt vmcnt(0)" ::: "memory");    // drain clamped tail stages

    #pragma unroll
    for (int qm = 0; qm < 2; ++qm)
        #pragma unroll
        for (int fm = 0; fm < 4; ++fm)
            #pragma unroll
            for (int fn = 0; fn < FN; ++fn) {
                const size_t col = col0 + wn*(FN*16) + fn*16 + lc;
                #pragma unroll
                for (int rr = 0; rr < 4; ++rr) {
                    const size_t row = row0 + wm*128 + qm*64 + fm*16 + lg*4 + rr;
                    C[row * N + col] = acc[qm][fm][fn][rr];
                }
            }
}

// ------------------------------------------------- per-head LN + interleaved RoPE
// in: x (B*S, LD) f32; head block at XOFF.  out: (B, NH, S, D) bf16.
template <int NH, int LD, int XOFF>
__global__ __launch_bounds__(256) void ln_rope(const float* __restrict__ x,
                                               const float* __restrict__ wln,
                                               const float* __restrict__ cosT,
                                               const float* __restrict__ sinT,
                                               const int* __restrict__ pids,
                                               __hip_bfloat16* __restrict__ out) {
    const int lane = threadIdx.x & 63, wv = threadIdx.x >> 6;
    const int r = blockIdx.x * 4 + wv;                 // row over B*S*NH
    const int h = r % NH;
    const int bs = r / NH;
    const int b = bs / S_, s = bs % S_;
    const float2 xv = *(const float2*)(x + (size_t)bs * LD + XOFF + h*D_ + lane*2);
    float sum = xv.x + xv.y;
    #pragma unroll
    for (int o = 32; o; o >>= 1) sum += __shfl_xor(sum, o);
    const float mu = sum * (1.f / D_);
    const float dx = xv.x - mu, dy = xv.y - mu;
    float vs = dx*dx + dy*dy;
    #pragma unroll
    for (int o = 32; o; o >>= 1) vs += __shfl_xor(vs, o);
    const float rs = rsqrtf(vs * (1.f / D_) + 1e-5f);
    const float2 w2 = *(const float2*)(wln + lane*2);
    const float y0 = w2.x * dx * rs, y1 = w2.y * dy * rs;
    const int p = pids[bs];
    const float2 c  = *(const float2*)(cosT + (size_t)p * D_ + lane*2);
    const float2 sn = *(const float2*)(sinT + (size_t)p * D_ + lane*2);
    __hip_bfloat162 ov;
    ov.x = __float2bfloat16(y0 * c.x - y1 * sn.x);     // even: x0*c - x1*s
    ov.y = __float2bfloat16(y1 * c.y + y0 * sn.y);     // odd:  x1*c + x0*s
    *(__hip_bfloat162*)(out + (((size_t)b * NH + h) * S_ + s) * D_ + lane*2) = ov;
}

// chunk swizzle for K tile (16B chunks, 16/row): spread over 8 bank-groups per 16-lane read
static __device__ __forceinline__ int sigk_(int r) { return (r & 3) | ((r >> 1) & 4); }

// ------------------------------------------------- sliding-window GQA flash attention v3
// Swapped QK^T (in-register P^T == PV B-frag) + block-level LDS staging of K/V^T
// via global_load_lds, double-buffered with counted vmcnt + raw s_barrier.
__global__ __launch_bounds__(256) void attn_fwd(const __hip_bfloat16* __restrict__ qr,
                                                const __hip_bfloat16* __restrict__ kr,
                                                const __hip_bfloat16* __restrict__ vt,
                                                __hip_bfloat16* __restrict__ ao) {
    __shared__ __align__(16) __hip_bfloat16 Ksl[2][64*D_];    // 2 x 16KB
    __shared__ __align__(16) __hip_bfloat16 Vsl[2][D_*64];    // 2 x 16KB
    const int lane = threadIdx.x & 63, w = threadIdx.x >> 6;
    const int lq = lane & 15, lg = lane >> 4;
    const int blk = blockIdx.x;
    const int qt = blk >> 6;                     // balance: CU's blocks span qt values
    const int bh = blk & 63;
    const int h = bh & (H_-1), b = bh >> 5;
    const int g = h >> 2;                        // GQA: kv head = h/4
    const int q0 = qt*64 + w*16;
    const int q  = q0 + lq;

    const __hip_bfloat16* qbase = qr + (((size_t)b*H_ + h)*S_ + q0) * D_;
    const __hip_bfloat16* kbase = kr + ((size_t)b*KVH_ + g) * (size_t)S_ * D_;
    const __hip_bfloat16* vbase = vt + ((size_t)b*KVH_ + g) * (size_t)D_ * S_;

    // staging lane constants
    const int srK = lane >> 4, scK = lane & 15;  // K: 4 rows x 16 chunks per wave-instr
    const int srV = lane >> 3, scV = lane & 7;   // V: 8 rows x 8 chunks per wave-instr

#define STAGE(nb, k0s) do {                                                              \
    _Pragma("unroll")                                                                    \
    for (int s_ = 0; s_ < 4; ++s_) {                                                     \
        const int rK_ = s_*16 + w*4 + srK;                                               \
        const __hip_bfloat16* srcK_ = kbase + (size_t)((k0s) + rK_)*D_                   \
                                      + ((scK ^ sigk_(rK_)) * 8);                        \
        __builtin_amdgcn_global_load_lds((const GAS void*)srcK_,                         \
            (LAS void*)&Ksl[nb][(s_*16 + w*4)*D_], 16, 0, 0);                            \
    }                                                                                    \
    _Pragma("unroll")                                                                    \
    for (int s_ = 0; s_ < 4; ++s_) {                                                     \
        const int dV_ = s_*32 + w*8 + srV;                                               \
        const __hip_bfloat16* srcV_ = vbase + (size_t)dV_*S_ + (k0s)                     \
                                      + ((scV ^ (dV_ & 7)) * 8);                         \
        __builtin_amdgcn_global_load_lds((const GAS void*)srcV_,                         \
            (LAS void*)&Vsl[nb][(s_*32 + w*8)*64], 16, 0, 0);                            \
    }                                                                                    \
} while (0)

    // Q as B-operand fragment: B[k][col=q], col=lane&15, k=lg*8+j (+32*kk)
    bf16x8 qf[4];
    #pragma unroll
    for (int kk = 0; kk < 4; ++kk)
        qf[kk] = *(const bf16x8*)(qbase + lq*D_ + kk*32 + lg*8);

    f32x4 o[8] = {};                             // out^T frags: d = n*16 + lg*4 + r, col q = lq
    float m = -1e30f, l = 0.f;

    int kst = qt*64 - (WIN_ - 1); if (kst < 0) kst = 0; kst &= ~63;
    const int nt = qt + 1 - (kst >> 6);          // tiles for the whole block (uniform)
    // A-row -> key permutation: key = 8*(row>>2) + 4*f + (row&3)
    const int kldrow = 8*(lq >> 2) + (lq & 3);

    STAGE(0, kst);

    for (int t = 0; t < nt; ++t) {
        const int k0 = kst + t*64;
        const int buf = t & 1;
        if (t + 1 < nt) {
            STAGE((t + 1) & 1, k0 + 64);
            asm volatile("s_waitcnt vmcnt(8)" ::: "memory");   // tile t staged; t+1 in flight
        } else {
            asm volatile("s_waitcnt vmcnt(0)" ::: "memory");
        }
        __builtin_amdgcn_s_barrier();

        // ---- QK^T from LDS: held value (kb,f,r): key = k0+kb*32+8*lg+4f+r
        f32x4 sc[2][2] = {};
        __builtin_amdgcn_s_setprio(1);
        #pragma unroll
        for (int kb = 0; kb < 2; ++kb)
            #pragma unroll
            for (int f = 0; f < 2; ++f) {
                const int rA = kb*32 + 4*f + kldrow;
                const __hip_bfloat16* kp = &Ksl[buf][rA*D_];
                #pragma unroll
                for (int kk = 0; kk < 4; ++kk) {
                    bf16x8 ka = *(const bf16x8*)(kp + (((kk*4 + lg) ^ sigk_(rA)) * 8));
                    sc[kb][f] = __builtin_amdgcn_mfma_f32_16x16x32_bf16(ka, qf[kk], sc[kb][f], 0, 0, 0);
                }
            }
        __builtin_amdgcn_s_setprio(0);

        // ---- online softmax, log2 domain, lane-local row
        const int dqk = q - (k0 + 8*lg);         // q - key = dqk - (kb*32+4f+r)
        float pv[16];
        float mx = -INFINITY;
        #pragma unroll
        for (int kb = 0; kb < 2; ++kb)
            #pragma unroll
            for (int f = 0; f < 2; ++f)
                #pragma unroll
                for (int r = 0; r < 4; ++r) {
                    const int c = kb*32 + 4*f + r;
                    const int d = dqk - c;
                    float v = (d >= 0 && d < WIN_) ? sc[kb][f][r] * SL2E_ : -INFINITY;
                    pv[kb*8 + f*4 + r] = v;
                    mx = fmaxf(mx, v);
                }
        mx = fmaxf(mx, __shfl_xor(mx, 16));
        mx = fmaxf(mx, __shfl_xor(mx, 32));
        const float mn = fmaxf(m, mx);
        const float alpha = exp2f(m - mn);
        float ls = 0.f;
        union { bf16x8 v; __hip_bfloat16 e[8]; } pu[2];
        #pragma unroll
        for (int kb = 0; kb < 2; ++kb)
            #pragma unroll
            for (int j = 0; j < 8; ++j) {
                const float p = exp2f(pv[kb*8 + j] - mn);
                ls += p;
                pu[kb].e[j] = __float2bfloat16(p);
            }
        ls += __shfl_xor(ls, 16);
        ls += __shfl_xor(ls, 32);
        l = l * alpha + ls;
        m = mn;
        #pragma unroll
        for (int n = 0; n < 8; ++n) {
            o[n][0] *= alpha; o[n][1] *= alpha; o[n][2] *= alpha; o[n][3] *= alpha;
        }

        // ---- PV from LDS: out^T[d][q] += V^T[d][k] * P^T[k][q]; P^T regs ARE the B-frag
        __builtin_amdgcn_s_setprio(1);
        #pragma unroll
        for (int kb = 0; kb < 2; ++kb)
            #pragma unroll
            for (int n = 0; n < 8; ++n) {
                const int dR = n*16 + lq;
                bf16x8 vf8 = *(const bf16x8*)(&Vsl[buf][dR*64] + (((kb*4 + lg) ^ (dR & 7)) * 8));
                o[n] = __builtin_amdgcn_mfma_f32_16x16x32_bf16(vf8, pu[kb].v, o[n], 0, 0, 0);
            }
        __builtin_amdgcn_s_setprio(0);

        if (t + 1 < nt) __builtin_amdgcn_s_barrier();   // all reads of buf done before overwrite
    }
#undef STAGE

    const float rinv = 1.f / l;
    #pragma unroll
    for (int n = 0; n < 8; ++n) {
        union { bf16x4 v; __hip_bfloat16 e[4]; } ov;
        #pragma unroll
        for (int r = 0; r < 4; ++r) ov.e[r] = __float2bfloat16(o[n][r] * rinv);
        *(bf16x4*)(ao + ((size_t)b*S_ + q)*(H_*D_) + h*D_ + n*16 + lg*4) = ov.v;
    }
}

// ----------------------------------------------------------------- host
extern "C" void kernel_launch(void* const* d_in, const int* in_sizes, int n_in,
                              void* d_out, int out_size, void* d_ws, size_t ws_size,
                              hipStream_t stream) {
    const float* hidden = (const float*)d_in[0];
    const int*   pids   = (const int*)  d_in[1];
    const float* cosT   = (const float*)d_in[2];
    const float* sinT   = (const float*)d_in[3];
    const float* wq     = (const float*)d_in[4];
    const float* wk     = (const float*)d_in[5];
    const float* wv     = (const float*)d_in[6];
    const float* wo     = (const float*)d_in[7];
    const float* qnw    = (const float*)d_in[8];
    const float* knw    = (const float*)d_in[9];
    float* out = (float*)d_out;

    char* base = (char*)d_ws;
    size_t off = 0;
    auto take = [&](size_t bytes) -> void* {
        void* q = base + off;
        off = (off + bytes + 255) & ~(size_t)255;
        return q;
    };
    float* qf            = (float*)take((size_t)NROW_*HID_*4);          // 64MB, reused as ao
    float* kvf           = (float*)take((size_t)NROW_*NKV_*4);          // 32MB
    __hip_bfloat16* hb   = (__hip_bfloat16*)take((size_t)NROW_*HID_*2);
    __hip_bfloat16* wqT  = (__hip_bfloat16*)take((size_t)HID_*HID_*2);
    __hip_bfloat16* wkvT = (__hip_bfloat16*)take((size_t)NKV_*HID_*2);  // k|v weights^T contiguous
    __hip_bfloat16* woT  = (__hip_bfloat16*)take((size_t)HID_*HID_*2);
    __hip_bfloat16* qr   = (__hip_bfloat16*)take((size_t)B_*H_*S_*D_*2);
    __hip_bfloat16* kr   = (__hip_bfloat16*)take((size_t)B_*KVH_*S_*D_*2);
    __hip_bfloat16* vt   = (__hip_bfloat16*)take((size_t)B_*KVH_*S_*D_*2);
    __hip_bfloat16* ao   = (__hip_bfloat16*)qf;     // alias: qf dead after ln_rope<Q>

    if (off > ws_size) {
        fprintf(stderr, "WORKSPACE TOO SMALL: need %zu have %zu\n", off, ws_size);
        return;
    }

    // 1. converts / transposes (wk|wv into one contiguous B^T of 2048 rows)
    cvt_bf16<<<(NROW_*HID_)/1024, 256, 0, stream>>>(hidden, hb, NROW_*HID_);
    transpose_cvt<<<dim3((H_*D_)/32,   HID_/32), dim3(32,8), 0, stream>>>(wq, wqT, HID_, H_*D_);
    transpose_cvt<<<dim3((KVH_*D_)/32, HID_/32), dim3(32,8), 0, stream>>>(wk, wkvT, HID_, KVH_*D_);
    transpose_cvt<<<dim3((KVH_*D_)/32, HID_/32), dim3(32,8), 0, stream>>>(wv, wkvT + (size_t)(KVH_*D_)*HID_, HID_, KVH_*D_);
    transpose_cvt<<<dim3(HID_/32, (H_*D_)/32),   dim3(32,8), 0, stream>>>(wo, woT, H_*D_, HID_);

    // 2. projections — every grid exactly 256 blocks (1 round on 256 CUs)
    gemm_t<4><<<(NROW_/256)*(HID_/256), 512, 0, stream>>>(hb, wqT,  qf,  NROW_, HID_, HID_, HID_/256);
    gemm_t<2><<<(NROW_/256)*(NKV_/128), 512, 0, stream>>>(hb, wkvT, kvf, NROW_, NKV_, HID_, NKV_/128);

    // 3. LN + RoPE (q, k), V transpose
    ln_rope<H_,   HID_, 0><<<(B_*S_*H_)/4,   256, 0, stream>>>(qf,  qnw, cosT, sinT, pids, qr);
    ln_rope<KVH_, NKV_, 0><<<(B_*S_*KVH_)/4, 256, 0, stream>>>(kvf, knw, cosT, sinT, pids, kr);
    v_transpose<<<dim3(S_/32, D_/32, B_*KVH_), dim3(32,8), 0, stream>>>(kvf, vt);

    // 4. attention
    attn_fwd<<<B_*H_*(S_/64), 256, 0, stream>>>(qr, kr, vt, ao);

    // 5. output projection -> d_out (f32)
    gemm_t<4><<<(NROW_/256)*(HID_/256), 512, 0, stream>>>(ao, woT, out, NROW_, HID_, H_*D_, HID_/256);
}

// Round 8
// 490.312 us; speedup vs baseline: 2.0984x; 1.0466x over previous
//
#include <hip/hip_runtime.h>
#include <hip/hip_bf16.h>
#include <cstdio>
#include <cstdint>

#define B_    2
#define S_    2048
#define H_    32
#define KVH_  8
#define D_    128
#define HID_  4096
#define WIN_  512
#define NROW_ (B_*S_)          // 4096 rows for projection GEMMs
#define NKV_  2048             // fused k|v output width
#define SCALE_ 0.08838834764831845f          // 128^-0.5
#define SL2E_  0.12751744932973953f          // SCALE_ * log2(e)

typedef __attribute__((ext_vector_type(8))) __bf16 bf16x8;
typedef __attribute__((ext_vector_type(4))) __bf16 bf16x4;
typedef __attribute__((ext_vector_type(4))) float  f32x4;

#define GAS __attribute__((address_space(1)))
#define LAS __attribute__((address_space(3)))

// ---------------------------------------------------------------- cvt f32->bf16
__global__ __launch_bounds__(256) void cvt_bf16(const float* __restrict__ in,
                                                __hip_bfloat16* __restrict__ out, int n) {
    int i = (blockIdx.x * 256 + threadIdx.x) * 4;
    if (i >= n) return;
    float4 v = *(const float4*)(in + i);
    __hip_bfloat162 a, b;
    a.x = __float2bfloat16(v.x); a.y = __float2bfloat16(v.y);
    b.x = __float2bfloat16(v.z); b.y = __float2bfloat16(v.w);
    *(__hip_bfloat162*)(out + i)     = a;
    *(__hip_bfloat162*)(out + i + 2) = b;
}

// ------------------------------------------------- merged weight transposes (4 segs, 1 launch)
// seg0 wq (4096x4096)->wqT ; seg1 wk -> wkvT[0:1024] ; seg2 wv -> wkvT[1024:2048] ; seg3 wo -> woT
__global__ __launch_bounds__(256) void wtrans_all(const float* __restrict__ wq,
                                                  const float* __restrict__ wk,
                                                  const float* __restrict__ wv,
                                                  const float* __restrict__ wo,
                                                  __hip_bfloat16* __restrict__ wqT,
                                                  __hip_bfloat16* __restrict__ wkvT,
                                                  __hip_bfloat16* __restrict__ woT) {
    __shared__ float t[32][33];
    const int tx = threadIdx.x, ty = threadIdx.y;       // (32,8)
    const int bid = blockIdx.x;
    const float* src; __hip_bfloat16* dst; int C, idx;  // R always 4096
    if (bid < 16384)      { src = wq; dst = wqT;  C = 4096; idx = bid; }
    else if (bid < 20480) { src = wk; dst = wkvT; C = 1024; idx = bid - 16384; }
    else if (bid < 24576) { src = wv; dst = wkvT + (size_t)1024*HID_; C = 1024; idx = bid - 20480; }
    else                  { src = wo; dst = woT;  C = 4096; idx = bid - 24576; }
    const int ctiles = C >> 5;
    const int c0 = (idx % ctiles) * 32, r0 = (idx / ctiles) * 32;
    #pragma unroll
    for (int i = 0; i < 4; ++i)
        t[ty + 8*i][tx] = src[(size_t)(r0 + ty + 8*i) * C + c0 + tx];
    __syncthreads();
    #pragma unroll
    for (int i = 0; i < 4; ++i)
        dst[(size_t)(c0 + ty + 8*i) * HID_ + r0 + tx] = __float2bfloat16(t[tx][ty + 8*i]);
}

// ------------------------------------------------- GEMM 256xBN, BK=32, ring-4, 2-phase/tile
// A(MxK) bf16 * Bt(NxK)^T.  8 waves (2Mx4N); BN = FN*64; per-wave C = 128x(FN*16).
// OMODE 0: C f32 flat (LD N).  1: C bf16 flat (LD N).  2: KV split — bx<8: K cols bf16 flat
// (LD 1024 into C); bx>=8: V cols transposed via LDS into C2 = vt (B,KVH,D,S) bf16.
// Pipeline per tile t:
//   alpha: {ds_read B(FN)+A q0(4) ; STGA(t+3) ; s_barrier ; lgkm(0) ; MFMA}
//   beta : {ds_read A q1(4) ; STGB(t+3) ; lgkm(0) ; MFMA ; vmcnt(2L) ; s_barrier}
// beta's vmcnt confirms tile t+1 BEFORE the barrier that precedes alpha(t+1)'s reads
// (fixes the latent read-before-confirm race of R6/R7).  L = loads/thread/tile = 2+BLD.
template <int FN, int OMODE>
__global__ __launch_bounds__(512, 2) void gemm_t(const __hip_bfloat16* __restrict__ A,
                                                 const __hip_bfloat16* __restrict__ Bt,
                                                 void* __restrict__ Cv, void* __restrict__ C2,
                                                 int M, int N, int K, int nbx) {
    constexpr int BN   = FN * 64;
    constexpr int BLD  = BN / 128;                      // B stage loads/thread/tile (2 or 1)
    constexpr int LPT  = 2 + BLD;                       // loads/thread/tile
    constexpr int SLOT = (256 + BN) * 32;               // elems per ring slot (A then B)
    __shared__ __align__(16) __hip_bfloat16 L[4 * SLOT];
    const int tid  = threadIdx.x;
    const int lane = tid & 63, w = tid >> 6;
    const int wm = w >> 2, wn = w & 3;                  // 2 x 4 wave grid
    const int lc = lane & 15, lg = lane >> 4;
    // XCD-aware bijective swizzle (gridDim.x % 8 == 0 by construction)
    const int nwg = gridDim.x, cpx = nwg >> 3;
    const int bid = blockIdx.x;
    const int swz = (bid & 7) * cpx + (bid >> 3);
    const int by = swz / nbx, bx = swz - by * nbx;
    const size_t row0 = (size_t)by * 256, col0 = (size_t)bx * BN;
    const int nt = K >> 5;                              // BK = 32

    const int srow = tid >> 2;                          // staging row 0..127 per load
    const int spc  = tid & 3;                           // phys 16B chunk in row
    const int slx  = spc ^ ((srow >> 1) & 3);           // pre-inverse-swizzled source chunk
    const __hip_bfloat16* Ab = A  + row0 * K;
    const __hip_bfloat16* Bb = Bt + col0 * K;

#define STGA(tile_) do {                                                                   \
    const int ss_ = (tile_) & 3;                                                           \
    const int kt_ = ((tile_) < nt) ? (tile_) : (nt - 1);  /* clamped tail, uniform count */\
    _Pragma("unroll")                                                                      \
    for (int rh_ = 0; rh_ < 2; ++rh_)                                                      \
        __builtin_amdgcn_global_load_lds(                                                  \
            (const GAS void*)(Ab + (size_t)(rh_*128 + srow) * K + kt_*32 + slx*8),         \
            (LAS void*)&L[ss_*SLOT + rh_*4096 + w*512], 16, 0, 0);                         \
} while (0)

#define STGB(tile_) do {                                                                   \
    const int ss_ = (tile_) & 3;                                                           \
    const int kt_ = ((tile_) < nt) ? (tile_) : (nt - 1);                                   \
    _Pragma("unroll")                                                                      \
    for (int bh_ = 0; bh_ < BLD; ++bh_)                                                    \
        __builtin_amdgcn_global_load_lds(                                                  \
            (const GAS void*)(Bb + (size_t)(bh_*128 + srow) * K + kt_*32 + slx*8),         \
            (LAS void*)&L[ss_*SLOT + 8192 + bh_*4096 + w*512], 16, 0, 0);                  \
} while (0)

#define VMW2L() do {                                                                       \
    if constexpr (FN == 4) asm volatile("s_waitcnt vmcnt(8)" ::: "memory");                \
    else                   asm volatile("s_waitcnt vmcnt(6)" ::: "memory");                \
} while (0)

    f32x4 acc[2][4][FN] = {};
    bf16x8 afr[4], bfr[FN];

    // prologue: stage tiles 0..2 into slots 0..2; confirm tile 0 (outstanding 3L, wait 2L)
    STGA(0); STGB(0); STGA(1); STGB(1); STGA(2); STGB(2);
    VMW2L();
    asm volatile("s_barrier" ::: "memory");

    for (int t = 0; t < nt; ++t) {
        const int s_ = t & 3;

        // ---- phase alpha: B frags + A quadrant 0 (slot t, confirmed last beta) ; stage A of t+3
        #pragma unroll
        for (int fn = 0; fn < FN; ++fn) {
            const int rB = wn*(FN*16) + fn*16 + lc;
            bfr[fn] = *(const bf16x8*)&L[s_*SLOT + 8192 + rB*32 + ((lg ^ ((rB >> 1) & 3)) * 8)];
        }
        #pragma unroll
        for (int fm = 0; fm < 4; ++fm) {
            const int rA = wm*128 + fm*16 + lc;
            afr[fm] = *(const bf16x8*)&L[s_*SLOT + rA*32 + ((lg ^ ((rA >> 1) & 3)) * 8)];
        }
        STGA(t + 3);
        asm volatile("s_barrier" ::: "memory");
        asm volatile("s_waitcnt lgkmcnt(0)" ::: "memory");
        __builtin_amdgcn_sched_barrier(0);
        __builtin_amdgcn_s_setprio(1);
        #pragma unroll
        for (int fm = 0; fm < 4; ++fm)
            #pragma unroll
            for (int fn = 0; fn < FN; ++fn)
                acc[0][fm][fn] = __builtin_amdgcn_mfma_f32_16x16x32_bf16(
                    afr[fm], bfr[fn], acc[0][fm][fn], 0, 0, 0);
        __builtin_amdgcn_s_setprio(0);

        // ---- phase beta: A quadrant 1 ; stage B of t+3 ; MFMA ; confirm t+1 ; end-barrier
        #pragma unroll
        for (int fm = 0; fm < 4; ++fm) {
            const int rA = wm*128 + 64 + fm*16 + lc;
            afr[fm] = *(const bf16x8*)&L[s_*SLOT + rA*32 + ((lg ^ ((rA >> 1) & 3)) * 8)];
        }
        STGB(t + 3);
        asm volatile("s_waitcnt lgkmcnt(0)" ::: "memory");
        __builtin_amdgcn_sched_barrier(0);
        __builtin_amdgcn_s_setprio(1);
        #pragma unroll
        for (int fm = 0; fm < 4; ++fm)
            #pragma unroll
            for (int fn = 0; fn < FN; ++fn)
                acc[1][fm][fn] = __builtin_amdgcn_mfma_f32_16x16x32_bf16(
                    afr[fm], bfr[fn], acc[1][fm][fn], 0, 0, 0);
        __builtin_amdgcn_s_setprio(0);
        VMW2L();                                        // tile t+1 fully landed (2L outstanding)
        asm volatile("s_barrier" ::: "memory");         // ... before alpha(t+1) reads it
    }
#undef STGA
#undef STGB
#undef VMW2L
    asm volatile("s_waitcnt vmcnt(0)" ::: "memory");    // drain clamped tail stages

    // ------------------------------ epilogues
    if constexpr (OMODE == 0) {
        float* C = (float*)Cv;
        #pragma unroll
        for (int qm = 0; qm < 2; ++qm)
            #pragma unroll
            for (int fm = 0; fm < 4; ++fm)
                #pragma unroll
                for (int fn = 0; fn < FN; ++fn) {
                    const size_t col = col0 + wn*(FN*16) + fn*16 + lc;
                    #pragma unroll
                    for (int rr = 0; rr < 4; ++rr) {
                        const size_t row = row0 + wm*128 + qm*64 + fm*16 + lg*4 + rr;
                        C[row * N + col] = acc[qm][fm][fn][rr];
                    }
                }
    } else if constexpr (OMODE == 1) {
        __hip_bfloat16* C = (__hip_bfloat16*)Cv;
        #pragma unroll
        for (int qm = 0; qm < 2; ++qm)
            #pragma unroll
            for (int fm = 0; fm < 4; ++fm)
                #pragma unroll
                for (int fn = 0; fn < FN; ++fn) {
                    const size_t col = col0 + wn*(FN*16) + fn*16 + lc;
                    #pragma unroll
                    for (int rr = 0; rr < 4; ++rr) {
                        const size_t row = row0 + wm*128 + qm*64 + fm*16 + lg*4 + rr;
                        C[row * N + col] = __float2bfloat16(acc[qm][fm][fn][rr]);
                    }
                }
    } else {                                            // OMODE 2: KV split (FN==2, BN=128)
        if (bx < 8) {                                   // K columns -> kf bf16, LD 1024
            __hip_bfloat16* C = (__hip_bfloat16*)Cv;
            #pragma unroll
            for (int qm = 0; qm < 2; ++qm)
                #pragma unroll
                for (int fm = 0; fm < 4; ++fm)
                    #pragma unroll
                    for (int fn = 0; fn < FN; ++fn) {
                        const size_t col = col0 + wn*32 + fn*16 + lc;
                        #pragma unroll
                        for (int rr = 0; rr < 4; ++rr) {
                            const size_t row = row0 + wm*128 + qm*64 + fm*16 + lg*4 + rr;
                            C[row * 1024 + col] = __float2bfloat16(acc[qm][fm][fn][rr]);
                        }
                    }
        } else {                                        // V columns -> vt (B,KVH,D,S) via LDS
            __hip_bfloat16* lt = (__hip_bfloat16*)L;    // [128 d][264 pad] bf16 = 67.5KB
            __syncthreads();                            // all ring reads done before reuse
            #pragma unroll
            for (int qm = 0; qm < 2; ++qm)
                #pragma unroll
                for (int fm = 0; fm < 4; ++fm)
                    #pragma unroll
                    for (int fn = 0; fn < FN; ++fn) {
                        const int cl = wn*32 + fn*16 + lc;
                        #pragma unroll
                        for (int rr = 0; rr < 4; ++rr) {
                            const int rl = wm*128 + qm*64 + fm*16 + lg*4 + rr;
                            lt[cl*264 + rl] = __float2bfloat16(acc[qm][fm][fn][rr]);
                        }
                    }
            __syncthreads();
            const int bb = (int)(row0 >> 11), s0 = (int)(row0 & 2047);
            const int g  = (int)((col0 - 1024) >> 7);
            __hip_bfloat16* vto = (__hip_bfloat16*)C2 + (((size_t)bb*KVH_ + g) * D_) * (size_t)S_;
            const int d = tid >> 2, sc0 = (tid & 3) * 64;
            #pragma unroll
            for (int j = 0; j < 64; j += 8) {
                bf16x8 v = *(const bf16x8*)&lt[d*264 + sc0 + j];
                *(bf16x8*)&vto[(size_t)d*S_ + s0 + sc0 + j] = v;
            }
        }
    }
}

// ------------------------------------------------- per-head LN + interleaved RoPE (bf16 in)
// in: x (B*S, LD) bf16; head block at XOFF.  out: (B, NH, S, D) bf16.
template <int NH, int LD, int XOFF>
__global__ __launch_bounds__(256) void ln_rope(const __hip_bfloat16* __restrict__ x,
                                               const float* __restrict__ wln,
                                               const float* __restrict__ cosT,
                                               const float* __restrict__ sinT,
                                               const int* __restrict__ pids,
                                               __hip_bfloat16* __restrict__ out) {
    const int lane = threadIdx.x & 63, wv = threadIdx.x >> 6;
    const int r = blockIdx.x * 4 + wv;                 // row over B*S*NH
    const int h = r % NH;
    const int bs = r / NH;
    const int b = bs / S_, s = bs % S_;
    const __hip_bfloat162 xv2 = *(const __hip_bfloat162*)(x + (size_t)bs * LD + XOFF + h*D_ + lane*2);
    const float x0 = __bfloat162float(xv2.x), x1 = __bfloat162float(xv2.y);
    float sum = x0 + x1;
    #pragma unroll
    for (int o = 32; o; o >>= 1) sum += __shfl_xor(sum, o);
    const float mu = sum * (1.f / D_);
    const float dx = x0 - mu, dy = x1 - mu;
    float vs = dx*dx + dy*dy;
    #pragma unroll
    for (int o = 32; o; o >>= 1) vs += __shfl_xor(vs, o);
    const float rs = rsqrtf(vs * (1.f / D_) + 1e-5f);
    const float2 w2 = *(const float2*)(wln + lane*2);
    const float y0 = w2.x * dx * rs, y1 = w2.y * dy * rs;
    const int p = pids[bs];
    const float2 c  = *(const float2*)(cosT + (size_t)p * D_ + lane*2);
    const float2 sn = *(const float2*)(sinT + (size_t)p * D_ + lane*2);
    __hip_bfloat162 ov;
    ov.x = __float2bfloat16(y0 * c.x - y1 * sn.x);     // even: x0*c - x1*s
    ov.y = __float2bfloat16(y1 * c.y + y0 * sn.y);     // odd:  x1*c + x0*s
    *(__hip_bfloat162*)(out + (((size_t)b * NH + h) * S_ + s) * D_ + lane*2) = ov;
}

// chunk swizzle for K tile (16B chunks, 16/row): spread over 8 bank-groups per 16-lane read
static __device__ __forceinline__ int sigk_(int r) { return (r & 3) | ((r >> 1) & 4); }

// ------------------------------------------------- sliding-window GQA flash attention v3
// Swapped QK^T (in-register P^T == PV B-frag) + block-level LDS staging of K/V^T
// via global_load_lds, double-buffered with counted vmcnt + raw s_barrier.
__global__ __launch_bounds__(256) void attn_fwd(const __hip_bfloat16* __restrict__ qr,
                                                const __hip_bfloat16* __restrict__ kr,
                                                const __hip_bfloat16* __restrict__ vt,
                                                __hip_bfloat16* __restrict__ ao) {
    __shared__ __align__(16) __hip_bfloat16 Ksl[2][64*D_];    // 2 x 16KB
    __shared__ __align__(16) __hip_bfloat16 Vsl[2][D_*64];    // 2 x 16KB
    const int lane = threadIdx.x & 63, w = threadIdx.x >> 6;
    const int lq = lane & 15, lg = lane >> 4;
    const int blk = blockIdx.x;
    const int qt = blk >> 6;                     // balance: CU's blocks span qt values
    const int bh = blk & 63;
    const int h = bh & (H_-1), b = bh >> 5;
    const int g = h >> 2;                        // GQA: kv head = h/4
    const int q0 = qt*64 + w*16;
    const int q  = q0 + lq;

    const __hip_bfloat16* qbase = qr + (((size_t)b*H_ + h)*S_ + q0) * D_;
    const __hip_bfloat16* kbase = kr + ((size_t)b*KVH_ + g) * (size_t)S_ * D_;
    const __hip_bfloat16* vbase = vt + ((size_t)b*KVH_ + g) * (size_t)D_ * S_;

    // staging lane constants
    const int srK = lane >> 4, scK = lane & 15;  // K: 4 rows x 16 chunks per wave-instr
    const int srV = lane >> 3, scV = lane & 7;   // V: 8 rows x 8 chunks per wave-instr

#define STAGE(nb, k0s) do {                                                              \
    _Pragma("unroll")                                                                    \
    for (int s_ = 0; s_ < 4; ++s_) {                                                     \
        const int rK_ = s_*16 + w*4 + srK;                                               \
        const __hip_bfloat16* srcK_ = kbase + (size_t)((k0s) + rK_)*D_                   \
                                      + ((scK ^ sigk_(rK_)) * 8);                        \
        __builtin_amdgcn_global_load_lds((const GAS void*)srcK_,                         \
            (LAS void*)&Ksl[nb][(s_*16 + w*4)*D_], 16, 0, 0);                            \
    }                                                                                    \
    _Pragma("unroll")                                                                    \
    for (int s_ = 0; s_ < 4; ++s_) {                                                     \
        const int dV_ = s_*32 + w*8 + srV;                                               \
        const __hip_bfloat16* srcV_ = vbase + (size_t)dV_*S_ + (k0s)                     \
                                      + ((scV ^ (dV_ & 7)) * 8);                         \
        __builtin_amdgcn_global_load_lds((const GAS void*)srcV_,                         \
            (LAS void*)&Vsl[nb][(s_*32 + w*8)*64], 16, 0, 0);                            \
    }                                                                                    \
} while (0)

    // Q as B-operand fragment: B[k][col=q], col=lane&15, k=lg*8+j (+32*kk)
    bf16x8 qf[4];
    #pragma unroll
    for (int kk = 0; kk < 4; ++kk)
        qf[kk] = *(const bf16x8*)(qbase + lq*D_ + kk*32 + lg*8);

    f32x4 o[8] = {};                             // out^T frags: d = n*16 + lg*4 + r, col q = lq
    float m = -1e30f, l = 0.f;

    int kst = qt*64 - (WIN_ - 1); if (kst < 0) kst = 0; kst &= ~63;
    const int nt = qt + 1 - (kst >> 6);          // tiles for the whole block (uniform)
    // A-row -> key permutation: key = 8*(row>>2) + 4*f + (row&3)
    const int kldrow = 8*(lq >> 2) + (lq & 3);

    STAGE(0, kst);

    for (int t = 0; t < nt; ++t) {
        const int k0 = kst + t*64;
        const int buf = t & 1;
        if (t + 1 < nt) {
            STAGE((t + 1) & 1, k0 + 64);
            asm volatile("s_waitcnt vmcnt(8)" ::: "memory");   // tile t staged; t+1 in flight
        } else {
            asm volatile("s_waitcnt vmcnt(0)" ::: "memory");
        }
        __builtin_amdgcn_s_barrier();

        // ---- QK^T from LDS: held value (kb,f,r): key = k0+kb*32+8*lg+4f+r
        f32x4 sc[2][2] = {};
        __builtin_amdgcn_s_setprio(1);
        #pragma unroll
        for (int kb = 0; kb < 2; ++kb)
            #pragma unroll
            for (int f = 0; f < 2; ++f) {
                const int rA = kb*32 + 4*f + kldrow;
                const __hip_bfloat16* kp = &Ksl[buf][rA*D_];
                #pragma unroll
                for (int kk = 0; kk < 4; ++kk) {
                    bf16x8 ka = *(const bf16x8*)(kp + (((kk*4 + lg) ^ sigk_(rA)) * 8));
                    sc[kb][f] = __builtin_amdgcn_mfma_f32_16x16x32_bf16(ka, qf[kk], sc[kb][f], 0, 0, 0);
                }
            }
        __builtin_amdgcn_s_setprio(0);

        // ---- online softmax, log2 domain, lane-local row
        const int dqk = q - (k0 + 8*lg);         // q - key = dqk - (kb*32+4f+r)
        float pv[16];
        float mx = -INFINITY;
        #pragma unroll
        for (int kb = 0; kb < 2; ++kb)
            #pragma unroll
            for (int f = 0; f < 2; ++f)
                #pragma unroll
                for (int r = 0; r < 4; ++r) {
                    const int c = kb*32 + 4*f + r;
                    const int d = dqk - c;
                    float v = (d >= 0 && d < WIN_) ? sc[kb][f][r] * SL2E_ : -INFINITY;
                    pv[kb*8 + f*4 + r] = v;
                    mx = fmaxf(mx, v);
                }
        mx = fmaxf(mx, __shfl_xor(mx, 16));
        mx = fmaxf(mx, __shfl_xor(mx, 32));
        const float mn = fmaxf(m, mx);
        const float alpha = exp2f(m - mn);
        float ls = 0.f;
        union { bf16x8 v; __hip_bfloat16 e[8]; } pu[2];
        #pragma unroll
        for (int kb = 0; kb < 2; ++kb)
            #pragma unroll
            for (int j = 0; j < 8; ++j) {
                const float p = exp2f(pv[kb*8 + j] - mn);
                ls += p;
                pu[kb].e[j] = __float2bfloat16(p);
            }
        ls += __shfl_xor(ls, 16);
        ls += __shfl_xor(ls, 32);
        l = l * alpha + ls;
        m = mn;
        #pragma unroll
        for (int n = 0; n < 8; ++n) {
            o[n][0] *= alpha; o[n][1] *= alpha; o[n][2] *= alpha; o[n][3] *= alpha;
        }

        // ---- PV from LDS: out^T[d][q] += V^T[d][k] * P^T[k][q]; P^T regs ARE the B-frag
        __builtin_amdgcn_s_setprio(1);
        #pragma unroll
        for (int kb = 0; kb < 2; ++kb)
            #pragma unroll
            for (int n = 0; n < 8; ++n) {
                const int dR = n*16 + lq;
                bf16x8 vf8 = *(const bf16x8*)(&Vsl[buf][dR*64] + (((kb*4 + lg) ^ (dR & 7)) * 8));
                o[n] = __builtin_amdgcn_mfma_f32_16x16x32_bf16(vf8, pu[kb].v, o[n], 0, 0, 0);
            }
        __builtin_amdgcn_s_setprio(0);

        if (t + 1 < nt) __builtin_amdgcn_s_barrier();   // all reads of buf done before overwrite
    }
#undef STAGE

    const float rinv = 1.f / l;
    #pragma unroll
    for (int n = 0; n < 8; ++n) {
        union { bf16x4 v; __hip_bfloat16 e[4]; } ov;
        #pragma unroll
        for (int r = 0; r < 4; ++r) ov.e[r] = __float2bfloat16(o[n][r] * rinv);
        *(bf16x4*)(ao + ((size_t)b*S_ + q)*(H_*D_) + h*D_ + n*16 + lg*4) = ov.v;
    }
}

// ----------------------------------------------------------------- host
extern "C" void kernel_launch(void* const* d_in, const int* in_sizes, int n_in,
                              void* d_out, int out_size, void* d_ws, size_t ws_size,
                              hipStream_t stream) {
    const float* hidden = (const float*)d_in[0];
    const int*   pids   = (const int*)  d_in[1];
    const float* cosT   = (const float*)d_in[2];
    const float* sinT   = (const float*)d_in[3];
    const float* wq     = (const float*)d_in[4];
    const float* wk     = (const float*)d_in[5];
    const float* wv     = (const float*)d_in[6];
    const float* wo     = (const float*)d_in[7];
    const float* qnw    = (const float*)d_in[8];
    const float* knw    = (const float*)d_in[9];
    float* out = (float*)d_out;

    char* base = (char*)d_ws;
    size_t off = 0;
    auto take = [&](size_t bytes) -> void* {
        void* q = base + off;
        off = (off + bytes + 255) & ~(size_t)255;
        return q;
    };
    __hip_bfloat16* qfb  = (__hip_bfloat16*)take((size_t)NROW_*HID_*2);   // Q proj bf16; reused as ao
    __hip_bfloat16* kf   = (__hip_bfloat16*)take((size_t)NROW_*1024*2);   // K proj bf16
    __hip_bfloat16* hb   = (__hip_bfloat16*)take((size_t)NROW_*HID_*2);
    __hip_bfloat16* wqT  = (__hip_bfloat16*)take((size_t)HID_*HID_*2);
    __hip_bfloat16* wkvT = (__hip_bfloat16*)take((size_t)NKV_*HID_*2);    // k|v weights^T contiguous
    __hip_bfloat16* woT  = (__hip_bfloat16*)take((size_t)HID_*HID_*2);
    __hip_bfloat16* qr   = (__hip_bfloat16*)take((size_t)B_*H_*S_*D_*2);
    __hip_bfloat16* kr   = (__hip_bfloat16*)take((size_t)B_*KVH_*S_*D_*2);
    __hip_bfloat16* vt   = (__hip_bfloat16*)take((size_t)B_*KVH_*S_*D_*2);
    __hip_bfloat16* ao   = qfb;                     // alias: qfb dead after ln_rope<Q>

    if (off > ws_size) {
        fprintf(stderr, "WORKSPACE TOO SMALL: need %zu have %zu\n", off, ws_size);
        return;
    }

    // 1. input convert + merged weight transposes (1 launch)
    cvt_bf16<<<(NROW_*HID_)/1024, 256, 0, stream>>>(hidden, hb, NROW_*HID_);
    wtrans_all<<<40960, dim3(32,8), 0, stream>>>(wq, wk, wv, wo, wqT, wkvT, woT);

    // 2. projections — every grid exactly 256 blocks (1 round on 256 CUs)
    gemm_t<4,1><<<(NROW_/256)*(HID_/256), 512, 0, stream>>>(hb, wqT,  qfb, nullptr, NROW_, HID_, HID_, HID_/256);
    gemm_t<2,2><<<(NROW_/256)*(NKV_/128), 512, 0, stream>>>(hb, wkvT, kf,  vt,      NROW_, NKV_, HID_, NKV_/128);

    // 3. LN + RoPE (q, k)  — V already transposed in-GEMM
    ln_rope<H_,   HID_, 0><<<(B_*S_*H_)/4,   256, 0, stream>>>(qfb, qnw, cosT, sinT, pids, qr);
    ln_rope<KVH_, 1024, 0><<<(B_*S_*KVH_)/4, 256, 0, stream>>>(kf,  knw, cosT, sinT, pids, kr);

    // 4. attention
    attn_fwd<<<B_*H_*(S_/64), 256, 0, stream>>>(qr, kr, vt, ao);

    // 5. output projection -> d_out (f32)
    gemm_t<4,0><<<(NROW_/256)*(HID_/256), 512, 0, stream>>>(ao, woT, out, nullptr, NROW_, HID_, H_*D_, HID_/256);
}

// Round 9
// 483.337 us; speedup vs baseline: 2.1287x; 1.0144x over previous
//
#include <hip/hip_runtime.h>
#include <hip/hip_bf16.h>
#include <cstdio>
#include <cstdint>

#define B_    2
#define S_    2048
#define H_    32
#define KVH_  8
#define D_    128
#define HID_  4096
#define WIN_  512
#define NROW_ (B_*S_)          // 4096 rows for projection GEMMs
#define NKV_  2048             // fused k|v output width
#define SCALE_ 0.08838834764831845f          // 128^-0.5
#define SL2E_  0.12751744932973953f          // SCALE_ * log2(e)

typedef __attribute__((ext_vector_type(8))) __bf16 bf16x8;
typedef __attribute__((ext_vector_type(4))) __bf16 bf16x4;
typedef __attribute__((ext_vector_type(4))) float  f32x4;

#define GAS __attribute__((address_space(1)))
#define LAS __attribute__((address_space(3)))

// ------------------------------------------------- merged prep: cvt hidden + 4 weight transposes
// bid < 16384 : hidden f32 -> bf16 (4 elems/thread)
// else        : 32x32 transpose tiles; seg wq / wk / wv / wo -> wqT / wkvT[0|1024] / woT
__global__ __launch_bounds__(256) void prep_all(const float* __restrict__ hidden,
                                                const float* __restrict__ wq,
                                                const float* __restrict__ wk,
                                                const float* __restrict__ wv,
                                                const float* __restrict__ wo,
                                                __hip_bfloat16* __restrict__ hb,
                                                __hip_bfloat16* __restrict__ wqT,
                                                __hip_bfloat16* __restrict__ wkvT,
                                                __hip_bfloat16* __restrict__ woT) {
    __shared__ float t[32][33];
    const int bid = blockIdx.x;
    if (bid < 16384) {
        const int i = (bid * 256 + threadIdx.x) * 4;
        float4 v = *(const float4*)(hidden + i);
        __hip_bfloat162 a, b;
        a.x = __float2bfloat16(v.x); a.y = __float2bfloat16(v.y);
        b.x = __float2bfloat16(v.z); b.y = __float2bfloat16(v.w);
        *(__hip_bfloat162*)(hb + i)     = a;
        *(__hip_bfloat162*)(hb + i + 2) = b;
        return;
    }
    const int tx = threadIdx.x & 31, ty = threadIdx.x >> 5;
    const int id = bid - 16384;
    const float* src; __hip_bfloat16* dst; int C, idx;   // R always 4096
    if (id < 16384)      { src = wq; dst = wqT;  C = 4096; idx = id; }
    else if (id < 20480) { src = wk; dst = wkvT; C = 1024; idx = id - 16384; }
    else if (id < 24576) { src = wv; dst = wkvT + (size_t)1024*HID_; C = 1024; idx = id - 20480; }
    else                 { src = wo; dst = woT;  C = 4096; idx = id - 24576; }
    const int ctiles = C >> 5;
    const int c0 = (idx % ctiles) * 32, r0 = (idx / ctiles) * 32;
    #pragma unroll
    for (int i = 0; i < 4; ++i)
        t[ty + 8*i][tx] = src[(size_t)(r0 + ty + 8*i) * C + c0 + tx];
    __syncthreads();
    #pragma unroll
    for (int i = 0; i < 4; ++i)
        dst[(size_t)(c0 + ty + 8*i) * HID_ + r0 + tx] = __float2bfloat16(t[tx][ty + 8*i]);
}

// ------------------------------------------------- GEMM 256xBN, BK=32, ring-4, 1-barrier/tile
// A(MxK) bf16 * Bt(NxK)^T.  8 waves (2Mx4N); BN = FN*64; per-wave C = 128x(FN*16).
// OMODE 0: C f32 flat.  1: C bf16 flat.  2: KV split (K flat bf16 / V transposed to C2).
// Per tile t (slot t confirmed by tile t-1's trailing vmcnt+barrier):
//   {ds_read B+Aq0 ; SB0 ; ds_read Aq1 ; STGA(t+3) ; lgkm(4) ; SB0 ; 16*FN/4 MFMA alpha ;
//    STGB(t+3) ; lgkm(0) ; SB0 ; MFMA beta ; vmcnt(2L) ; s_barrier}
// - partial lgkm(4): A-quad1 reads drain UNDER alpha's MFMAs (read order pinned by SB0).
// - no mid-tile barrier: STGA targets slot t-1 whose reads all completed before the t-1
//   end-barrier that precedes this STGA in every wave's program order.
// - waves self-pace within a tile -> cross-wave LDS/MFMA pipe overlap (2 waves/SIMD).
template <int FN, int OMODE>
__global__ __launch_bounds__(512, 2) void gemm_t(const __hip_bfloat16* __restrict__ A,
                                                 const __hip_bfloat16* __restrict__ Bt,
                                                 void* __restrict__ Cv, void* __restrict__ C2,
                                                 int M, int N, int K, int nbx) {
    constexpr int BN   = FN * 64;
    constexpr int BLD  = BN / 128;                      // B stage loads/thread/tile (2 or 1)
    constexpr int SLOT = (256 + BN) * 32;               // elems per ring slot (A then B)
    __shared__ __align__(16) __hip_bfloat16 L[4 * SLOT];
    const int tid  = threadIdx.x;
    const int lane = tid & 63, w = tid >> 6;
    const int wm = w >> 2, wn = w & 3;                  // 2 x 4 wave grid
    const int lc = lane & 15, lg = lane >> 4;
    // XCD-aware bijective swizzle (gridDim.x % 8 == 0 by construction)
    const int nwg = gridDim.x, cpx = nwg >> 3;
    const int bid = blockIdx.x;
    const int swz = (bid & 7) * cpx + (bid >> 3);
    const int by = swz / nbx, bx = swz - by * nbx;
    const size_t row0 = (size_t)by * 256, col0 = (size_t)bx * BN;
    const int nt = K >> 5;                              // BK = 32

    const int srow = tid >> 2;                          // staging row 0..127 per load
    const int spc  = tid & 3;                           // phys 16B chunk in row
    const int slx  = spc ^ ((srow >> 1) & 3);           // pre-inverse-swizzled source chunk
    const __hip_bfloat16* Ab = A  + row0 * K;
    const __hip_bfloat16* Bb = Bt + col0 * K;

#define STGA(tile_) do {                                                                   \
    const int ss_ = (tile_) & 3;                                                           \
    const int kt_ = ((tile_) < nt) ? (tile_) : (nt - 1);  /* clamped tail, uniform count */\
    _Pragma("unroll")                                                                      \
    for (int rh_ = 0; rh_ < 2; ++rh_)                                                      \
        __builtin_amdgcn_global_load_lds(                                                  \
            (const GAS void*)(Ab + (size_t)(rh_*128 + srow) * K + kt_*32 + slx*8),         \
            (LAS void*)&L[ss_*SLOT + rh_*4096 + w*512], 16, 0, 0);                         \
} while (0)

#define STGB(tile_) do {                                                                   \
    const int ss_ = (tile_) & 3;                                                           \
    const int kt_ = ((tile_) < nt) ? (tile_) : (nt - 1);                                   \
    _Pragma("unroll")                                                                      \
    for (int bh_ = 0; bh_ < BLD; ++bh_)                                                    \
        __builtin_amdgcn_global_load_lds(                                                  \
            (const GAS void*)(Bb + (size_t)(bh_*128 + srow) * K + kt_*32 + slx*8),         \
            (LAS void*)&L[ss_*SLOT + 8192 + bh_*4096 + w*512], 16, 0, 0);                  \
} while (0)

#define VMW2L() do {                                                                       \
    if constexpr (FN == 4) asm volatile("s_waitcnt vmcnt(8)" ::: "memory");                \
    else                   asm volatile("s_waitcnt vmcnt(6)" ::: "memory");                \
} while (0)

    f32x4 acc[2][4][FN] = {};
    bf16x8 afr0[4], afr1[4], bfr[FN];

    // prologue: stage tiles 0..2 into slots 0..2; confirm tile 0 (outstanding 3L, wait 2L)
    STGA(0); STGB(0); STGA(1); STGB(1); STGA(2); STGB(2);
    VMW2L();
    asm volatile("s_barrier" ::: "memory");

    for (int t = 0; t < nt; ++t) {
        const int s_ = t & 3;

        // ---- read group 1: B frags + A quadrant 0 (oldest 8 lgkm ops)
        #pragma unroll
        for (int fn = 0; fn < FN; ++fn) {
            const int rB = wn*(FN*16) + fn*16 + lc;
            bfr[fn] = *(const bf16x8*)&L[s_*SLOT + 8192 + rB*32 + ((lg ^ ((rB >> 1) & 3)) * 8)];
        }
        #pragma unroll
        for (int fm = 0; fm < 4; ++fm) {
            const int rA = wm*128 + fm*16 + lc;
            afr0[fm] = *(const bf16x8*)&L[s_*SLOT + rA*32 + ((lg ^ ((rA >> 1) & 3)) * 8)];
        }
        __builtin_amdgcn_sched_barrier(0);              // pin group order for counted lgkm
        // ---- read group 2: A quadrant 1 (newest 4 lgkm ops)
        #pragma unroll
        for (int fm = 0; fm < 4; ++fm) {
            const int rA = wm*128 + 64 + fm*16 + lc;
            afr1[fm] = *(const bf16x8*)&L[s_*SLOT + rA*32 + ((lg ^ ((rA >> 1) & 3)) * 8)];
        }
        STGA(t + 3);
        asm volatile("s_waitcnt lgkmcnt(4)" ::: "memory");   // group 1 done; group 2 in flight
        __builtin_amdgcn_sched_barrier(0);
        __builtin_amdgcn_s_setprio(1);
        #pragma unroll
        for (int fm = 0; fm < 4; ++fm)
            #pragma unroll
            for (int fn = 0; fn < FN; ++fn)
                acc[0][fm][fn] = __builtin_amdgcn_mfma_f32_16x16x32_bf16(
                    afr0[fm], bfr[fn], acc[0][fm][fn], 0, 0, 0);
        __builtin_amdgcn_s_setprio(0);

        STGB(t + 3);
        asm volatile("s_waitcnt lgkmcnt(0)" ::: "memory");   // group 2 drained under alpha
        __builtin_amdgcn_sched_barrier(0);
        __builtin_amdgcn_s_setprio(1);
        #pragma unroll
        for (int fm = 0; fm < 4; ++fm)
            #pragma unroll
            for (int fn = 0; fn < FN; ++fn)
                acc[1][fm][fn] = __builtin_amdgcn_mfma_f32_16x16x32_bf16(
                    afr1[fm], bfr[fn], acc[1][fm][fn], 0, 0, 0);
        __builtin_amdgcn_s_setprio(0);
        VMW2L();                                        // tile t+1 fully landed (2L outstanding)
        asm volatile("s_barrier" ::: "memory");         // ... before tile t+1's reads
    }
#undef STGA
#undef STGB
#undef VMW2L
    asm volatile("s_waitcnt vmcnt(0)" ::: "memory");    // drain clamped tail stages

    // ------------------------------ epilogues
    if constexpr (OMODE == 0) {
        float* C = (float*)Cv;
        #pragma unroll
        for (int qm = 0; qm < 2; ++qm)
            #pragma unroll
            for (int fm = 0; fm < 4; ++fm)
                #pragma unroll
                for (int fn = 0; fn < FN; ++fn) {
                    const size_t col = col0 + wn*(FN*16) + fn*16 + lc;
                    #pragma unroll
                    for (int rr = 0; rr < 4; ++rr) {
                        const size_t row = row0 + wm*128 + qm*64 + fm*16 + lg*4 + rr;
                        C[row * N + col] = acc[qm][fm][fn][rr];
                    }
                }
    } else if constexpr (OMODE == 1) {
        __hip_bfloat16* C = (__hip_bfloat16*)Cv;
        #pragma unroll
        for (int qm = 0; qm < 2; ++qm)
            #pragma unroll
            for (int fm = 0; fm < 4; ++fm)
                #pragma unroll
                for (int fn = 0; fn < FN; ++fn) {
                    const size_t col = col0 + wn*(FN*16) + fn*16 + lc;
                    #pragma unroll
                    for (int rr = 0; rr < 4; ++rr) {
                        const size_t row = row0 + wm*128 + qm*64 + fm*16 + lg*4 + rr;
                        C[row * N + col] = __float2bfloat16(acc[qm][fm][fn][rr]);
                    }
                }
    } else {                                            // OMODE 2: KV split (FN==2, BN=128)
        if (bx < 8) {                                   // K columns -> kf bf16, LD 1024
            __hip_bfloat16* C = (__hip_bfloat16*)Cv;
            #pragma unroll
            for (int qm = 0; qm < 2; ++qm)
                #pragma unroll
                for (int fm = 0; fm < 4; ++fm)
                    #pragma unroll
                    for (int fn = 0; fn < FN; ++fn) {
                        const size_t col = col0 + wn*32 + fn*16 + lc;
                        #pragma unroll
                        for (int rr = 0; rr < 4; ++rr) {
                            const size_t row = row0 + wm*128 + qm*64 + fm*16 + lg*4 + rr;
                            C[row * 1024 + col] = __float2bfloat16(acc[qm][fm][fn][rr]);
                        }
                    }
        } else {                                        // V columns -> vt (B,KVH,D,S) via LDS
            __hip_bfloat16* lt = (__hip_bfloat16*)L;    // [128 d][264 pad] bf16 = 67.5KB
            __syncthreads();                            // all ring reads done before reuse
            #pragma unroll
            for (int qm = 0; qm < 2; ++qm)
                #pragma unroll
                for (int fm = 0; fm < 4; ++fm)
                    #pragma unroll
                    for (int fn = 0; fn < FN; ++fn) {
                        const int cl = wn*32 + fn*16 + lc;
                        #pragma unroll
                        for (int rr = 0; rr < 4; ++rr) {
                            const int rl = wm*128 + qm*64 + fm*16 + lg*4 + rr;
                            lt[cl*264 + rl] = __float2bfloat16(acc[qm][fm][fn][rr]);
                        }
                    }
            __syncthreads();
            const int bb = (int)(row0 >> 11), s0 = (int)(row0 & 2047);
            const int g  = (int)((col0 - 1024) >> 7);
            __hip_bfloat16* vto = (__hip_bfloat16*)C2 + (((size_t)bb*KVH_ + g) * D_) * (size_t)S_;
            const int d = tid >> 2, sc0 = (tid & 3) * 64;
            #pragma unroll
            for (int j = 0; j < 64; j += 8) {
                bf16x8 v = *(const bf16x8*)&lt[d*264 + sc0 + j];
                *(bf16x8*)&vto[(size_t)d*S_ + s0 + sc0 + j] = v;
            }
        }
    }
}

// ------------------------------------------------- per-head LN + interleaved RoPE (bf16 in)
// in: x (B*S, LD) bf16; head block at XOFF.  out: (B, NH, S, D) bf16.
template <int NH, int LD, int XOFF>
__global__ __launch_bounds__(256) void ln_rope(const __hip_bfloat16* __restrict__ x,
                                               const float* __restrict__ wln,
                                               const float* __restrict__ cosT,
                                               const float* __restrict__ sinT,
                                               const int* __restrict__ pids,
                                               __hip_bfloat16* __restrict__ out) {
    const int lane = threadIdx.x & 63, wv = threadIdx.x >> 6;
    const int r = blockIdx.x * 4 + wv;                 // row over B*S*NH
    const int h = r % NH;
    const int bs = r / NH;
    const int b = bs / S_, s = bs % S_;
    const __hip_bfloat162 xv2 = *(const __hip_bfloat162*)(x + (size_t)bs * LD + XOFF + h*D_ + lane*2);
    const float x0 = __bfloat162float(xv2.x), x1 = __bfloat162float(xv2.y);
    float sum = x0 + x1;
    #pragma unroll
    for (int o = 32; o; o >>= 1) sum += __shfl_xor(sum, o);
    const float mu = sum * (1.f / D_);
    const float dx = x0 - mu, dy = x1 - mu;
    float vs = dx*dx + dy*dy;
    #pragma unroll
    for (int o = 32; o; o >>= 1) vs += __shfl_xor(vs, o);
    const float rs = rsqrtf(vs * (1.f / D_) + 1e-5f);
    const float2 w2 = *(const float2*)(wln + lane*2);
    const float y0 = w2.x * dx * rs, y1 = w2.y * dy * rs;
    const int p = pids[bs];
    const float2 c  = *(const float2*)(cosT + (size_t)p * D_ + lane*2);
    const float2 sn = *(const float2*)(sinT + (size_t)p * D_ + lane*2);
    __hip_bfloat162 ov;
    ov.x = __float2bfloat16(y0 * c.x - y1 * sn.x);     // even: x0*c - x1*s
    ov.y = __float2bfloat16(y1 * c.y + y0 * sn.y);     // odd:  x1*c + x0*s
    *(__hip_bfloat162*)(out + (((size_t)b * NH + h) * S_ + s) * D_ + lane*2) = ov;
}

// chunk swizzle for K tile (16B chunks, 16/row): spread over 8 bank-groups per 16-lane read
static __device__ __forceinline__ int sigk_(int r) { return (r & 3) | ((r >> 1) & 4); }

// ------------------------------------------------- sliding-window GQA flash attention v3
// Swapped QK^T (in-register P^T == PV B-frag) + block-level LDS staging of K/V^T
// via global_load_lds, double-buffered with counted vmcnt + raw s_barrier.
__global__ __launch_bounds__(256) void attn_fwd(const __hip_bfloat16* __restrict__ qr,
                                                const __hip_bfloat16* __restrict__ kr,
                                                const __hip_bfloat16* __restrict__ vt,
                                                __hip_bfloat16* __restrict__ ao) {
    __shared__ __align__(16) __hip_bfloat16 Ksl[2][64*D_];    // 2 x 16KB
    __shared__ __align__(16) __hip_bfloat16 Vsl[2][D_*64];    // 2 x 16KB
    const int lane = threadIdx.x & 63, w = threadIdx.x >> 6;
    const int lq = lane & 15, lg = lane >> 4;
    const int blk = blockIdx.x;
    const int qt = blk >> 6;                     // balance: CU's blocks span qt values
    const int bh = blk & 63;
    const int h = bh & (H_-1), b = bh >> 5;
    const int g = h >> 2;                        // GQA: kv head = h/4
    const int q0 = qt*64 + w*16;
    const int q  = q0 + lq;

    const __hip_bfloat16* qbase = qr + (((size_t)b*H_ + h)*S_ + q0) * D_;
    const __hip_bfloat16* kbase = kr + ((size_t)b*KVH_ + g) * (size_t)S_ * D_;
    const __hip_bfloat16* vbase = vt + ((size_t)b*KVH_ + g) * (size_t)D_ * S_;

    // staging lane constants
    const int srK = lane >> 4, scK = lane & 15;  // K: 4 rows x 16 chunks per wave-instr
    const int srV = lane >> 3, scV = lane & 7;   // V: 8 rows x 8 chunks per wave-instr

#define STAGE(nb, k0s) do {                                                              \
    _Pragma("unroll")                                                                    \
    for (int s_ = 0; s_ < 4; ++s_) {                                                     \
        const int rK_ = s_*16 + w*4 + srK;                                               \
        const __hip_bfloat16* srcK_ = kbase + (size_t)((k0s) + rK_)*D_                   \
                                      + ((scK ^ sigk_(rK_)) * 8);                        \
        __builtin_amdgcn_global_load_lds((const GAS void*)srcK_,                         \
            (LAS void*)&Ksl[nb][(s_*16 + w*4)*D_], 16, 0, 0);                            \
    }                                                                                    \
    _Pragma("unroll")                                                                    \
    for (int s_ = 0; s_ < 4; ++s_) {                                                     \
        const int dV_ = s_*32 + w*8 + srV;                                               \
        const __hip_bfloat16* srcV_ = vbase + (size_t)dV_*S_ + (k0s)                     \
                                      + ((scV ^ (dV_ & 7)) * 8);                         \
        __builtin_amdgcn_global_load_lds((const GAS void*)srcV_,                         \
            (LAS void*)&Vsl[nb][(s_*32 + w*8)*64], 16, 0, 0);                            \
    }                                                                                    \
} while (0)

    // Q as B-operand fragment: B[k][col=q], col=lane&15, k=lg*8+j (+32*kk)
    bf16x8 qf[4];
    #pragma unroll
    for (int kk = 0; kk < 4; ++kk)
        qf[kk] = *(const bf16x8*)(qbase + lq*D_ + kk*32 + lg*8);

    f32x4 o[8] = {};                             // out^T frags: d = n*16 + lg*4 + r, col q = lq
    float m = -1e30f, l = 0.f;

    int kst = qt*64 - (WIN_ - 1); if (kst < 0) kst = 0; kst &= ~63;
    const int nt = qt + 1 - (kst >> 6);          // tiles for the whole block (uniform)
    // A-row -> key permutation: key = 8*(row>>2) + 4*f + (row&3)
    const int kldrow = 8*(lq >> 2) + (lq & 3);

    STAGE(0, kst);

    for (int t = 0; t < nt; ++t) {
        const int k0 = kst + t*64;
        const int buf = t & 1;
        if (t + 1 < nt) {
            STAGE((t + 1) & 1, k0 + 64);
            asm volatile("s_waitcnt vmcnt(8)" ::: "memory");   // tile t staged; t+1 in flight
        } else {
            asm volatile("s_waitcnt vmcnt(0)" ::: "memory");
        }
        __builtin_amdgcn_s_barrier();

        // ---- QK^T from LDS: held value (kb,f,r): key = k0+kb*32+8*lg+4f+r
        f32x4 sc[2][2] = {};
        __builtin_amdgcn_s_setprio(1);
        #pragma unroll
        for (int kb = 0; kb < 2; ++kb)
            #pragma unroll
            for (int f = 0; f < 2; ++f) {
                const int rA = kb*32 + 4*f + kldrow;
                const __hip_bfloat16* kp = &Ksl[buf][rA*D_];
                #pragma unroll
                for (int kk = 0; kk < 4; ++kk) {
                    bf16x8 ka = *(const bf16x8*)(kp + (((kk*4 + lg) ^ sigk_(rA)) * 8));
                    sc[kb][f] = __builtin_amdgcn_mfma_f32_16x16x32_bf16(ka, qf[kk], sc[kb][f], 0, 0, 0);
                }
            }
        __builtin_amdgcn_s_setprio(0);

        // ---- online softmax, log2 domain, lane-local row
        const int dqk = q - (k0 + 8*lg);         // q - key = dqk - (kb*32+4f+r)
        float pv[16];
        float mx = -INFINITY;
        #pragma unroll
        for (int kb = 0; kb < 2; ++kb)
            #pragma unroll
            for (int f = 0; f < 2; ++f)
                #pragma unroll
                for (int r = 0; r < 4; ++r) {
                    const int c = kb*32 + 4*f + r;
                    const int d = dqk - c;
                    float v = (d >= 0 && d < WIN_) ? sc[kb][f][r] * SL2E_ : -INFINITY;
                    pv[kb*8 + f*4 + r] = v;
                    mx = fmaxf(mx, v);
                }
        mx = fmaxf(mx, __shfl_xor(mx, 16));
        mx = fmaxf(mx, __shfl_xor(mx, 32));
        const float mn = fmaxf(m, mx);
        const float alpha = exp2f(m - mn);
        float ls = 0.f;
        union { bf16x8 v; __hip_bfloat16 e[8]; } pu[2];
        #pragma unroll
        for (int kb = 0; kb < 2; ++kb)
            #pragma unroll
            for (int j = 0; j < 8; ++j) {
                const float p = exp2f(pv[kb*8 + j] - mn);
                ls += p;
                pu[kb].e[j] = __float2bfloat16(p);
            }
        ls += __shfl_xor(ls, 16);
        ls += __shfl_xor(ls, 32);
        l = l * alpha + ls;
        m = mn;
        #pragma unroll
        for (int n = 0; n < 8; ++n) {
            o[n][0] *= alpha; o[n][1] *= alpha; o[n][2] *= alpha; o[n][3] *= alpha;
        }

        // ---- PV from LDS: out^T[d][q] += V^T[d][k] * P^T[k][q]; P^T regs ARE the B-frag
        __builtin_amdgcn_s_setprio(1);
        #pragma unroll
        for (int kb = 0; kb < 2; ++kb)
            #pragma unroll
            for (int n = 0; n < 8; ++n) {
                const int dR = n*16 + lq;
                bf16x8 vf8 = *(const bf16x8*)(&Vsl[buf][dR*64] + (((kb*4 + lg) ^ (dR & 7)) * 8));
                o[n] = __builtin_amdgcn_mfma_f32_16x16x32_bf16(vf8, pu[kb].v, o[n], 0, 0, 0);
            }
        __builtin_amdgcn_s_setprio(0);

        if (t + 1 < nt) __builtin_amdgcn_s_barrier();   // all reads of buf done before overwrite
    }
#undef STAGE

    const float rinv = 1.f / l;
    #pragma unroll
    for (int n = 0; n < 8; ++n) {
        union { bf16x4 v; __hip_bfloat16 e[4]; } ov;
        #pragma unroll
        for (int r = 0; r < 4; ++r) ov.e[r] = __float2bfloat16(o[n][r] * rinv);
        *(bf16x4*)(ao + ((size_t)b*S_ + q)*(H_*D_) + h*D_ + n*16 + lg*4) = ov.v;
    }
}

// ----------------------------------------------------------------- host
extern "C" void kernel_launch(void* const* d_in, const int* in_sizes, int n_in,
                              void* d_out, int out_size, void* d_ws, size_t ws_size,
                              hipStream_t stream) {
    const float* hidden = (const float*)d_in[0];
    const int*   pids   = (const int*)  d_in[1];
    const float* cosT   = (const float*)d_in[2];
    const float* sinT   = (const float*)d_in[3];
    const float* wq     = (const float*)d_in[4];
    const float* wk     = (const float*)d_in[5];
    const float* wv     = (const float*)d_in[6];
    const float* wo     = (const float*)d_in[7];
    const float* qnw    = (const float*)d_in[8];
    const float* knw    = (const float*)d_in[9];
    float* out = (float*)d_out;

    char* base = (char*)d_ws;
    size_t off = 0;
    auto take = [&](size_t bytes) -> void* {
        void* q = base + off;
        off = (off + bytes + 255) & ~(size_t)255;
        return q;
    };
    __hip_bfloat16* qfb  = (__hip_bfloat16*)take((size_t)NROW_*HID_*2);   // Q proj bf16; reused as ao
    __hip_bfloat16* kf   = (__hip_bfloat16*)take((size_t)NROW_*1024*2);   // K proj bf16
    __hip_bfloat16* hb   = (__hip_bfloat16*)take((size_t)NROW_*HID_*2);
    __hip_bfloat16* wqT  = (__hip_bfloat16*)take((size_t)HID_*HID_*2);
    __hip_bfloat16* wkvT = (__hip_bfloat16*)take((size_t)NKV_*HID_*2);    // k|v weights^T contiguous
    __hip_bfloat16* woT  = (__hip_bfloat16*)take((size_t)HID_*HID_*2);
    __hip_bfloat16* qr   = (__hip_bfloat16*)take((size_t)B_*H_*S_*D_*2);
    __hip_bfloat16* kr   = (__hip_bfloat16*)take((size_t)B_*KVH_*S_*D_*2);
    __hip_bfloat16* vt   = (__hip_bfloat16*)take((size_t)B_*KVH_*S_*D_*2);
    __hip_bfloat16* ao   = qfb;                     // alias: qfb dead after ln_rope<Q>

    if (off > ws_size) {
        fprintf(stderr, "WORKSPACE TOO SMALL: need %zu have %zu\n", off, ws_size);
        return;
    }

    // 1. merged prep: hidden convert + 4 weight transposes (1 launch)
    prep_all<<<16384 + 40960, 256, 0, stream>>>(hidden, wq, wk, wv, wo, hb, wqT, wkvT, woT);

    // 2. projections — every grid exactly 256 blocks (1 round on 256 CUs)
    gemm_t<4,1><<<(NROW_/256)*(HID_/256), 512, 0, stream>>>(hb, wqT,  qfb, nullptr, NROW_, HID_, HID_, HID_/256);
    gemm_t<2,2><<<(NROW_/256)*(NKV_/128), 512, 0, stream>>>(hb, wkvT, kf,  vt,      NROW_, NKV_, HID_, NKV_/128);

    // 3. LN + RoPE (q, k)  — V already transposed in-GEMM
    ln_rope<H_,   HID_, 0><<<(B_*S_*H_)/4,   256, 0, stream>>>(qfb, qnw, cosT, sinT, pids, qr);
    ln_rope<KVH_, 1024, 0><<<(B_*S_*KVH_)/4, 256, 0, stream>>>(kf,  knw, cosT, sinT, pids, kr);

    // 4. attention
    attn_fwd<<<B_*H_*(S_/64), 256, 0, stream>>>(qr, kr, vt, ao);

    // 5. output projection -> d_out (f32)
    gemm_t<4,0><<<(NROW_/256)*(HID_/256), 512, 0, stream>>>(ao, woT, out, nullptr, NROW_, HID_, H_*D_, HID_/256);
}

// Round 10
// 463.716 us; speedup vs baseline: 2.2187x; 1.0423x over previous
//
#include <hip/hip_runtime.h>
#include <hip/hip_bf16.h>
#include <cstdio>
#include <cstdint>

#define B_    2
#define S_    2048
#define H_    32
#define KVH_  8
#define D_    128
#define HID_  4096
#define WIN_  512
#define NROW_ (B_*S_)          // 4096 rows for projection GEMMs
#define NKV_  2048             // fused k|v output width
#define SCALE_ 0.08838834764831845f          // 128^-0.5
#define SL2E_  0.12751744932973953f          // SCALE_ * log2(e)

typedef __attribute__((ext_vector_type(8))) __bf16 bf16x8;
typedef __attribute__((ext_vector_type(4))) __bf16 bf16x4;
typedef __attribute__((ext_vector_type(4))) float  f32x4;

#define GAS __attribute__((address_space(1)))
#define LAS __attribute__((address_space(3)))

// ------------------------------------------------- merged prep: cvt hidden + 4 weight transposes
__global__ __launch_bounds__(256) void prep_all(const float* __restrict__ hidden,
                                                const float* __restrict__ wq,
                                                const float* __restrict__ wk,
                                                const float* __restrict__ wv,
                                                const float* __restrict__ wo,
                                                __hip_bfloat16* __restrict__ hb,
                                                __hip_bfloat16* __restrict__ wqT,
                                                __hip_bfloat16* __restrict__ wkvT,
                                                __hip_bfloat16* __restrict__ woT) {
    __shared__ float t[32][33];
    const int bid = blockIdx.x;
    if (bid < 16384) {
        const int i = (bid * 256 + threadIdx.x) * 4;
        float4 v = *(const float4*)(hidden + i);
        __hip_bfloat162 a, b;
        a.x = __float2bfloat16(v.x); a.y = __float2bfloat16(v.y);
        b.x = __float2bfloat16(v.z); b.y = __float2bfloat16(v.w);
        *(__hip_bfloat162*)(hb + i)     = a;
        *(__hip_bfloat162*)(hb + i + 2) = b;
        return;
    }
    const int tx = threadIdx.x & 31, ty = threadIdx.x >> 5;
    const int id = bid - 16384;
    const float* src; __hip_bfloat16* dst; int C, idx;   // R always 4096
    if (id < 16384)      { src = wq; dst = wqT;  C = 4096; idx = id; }
    else if (id < 20480) { src = wk; dst = wkvT; C = 1024; idx = id - 16384; }
    else if (id < 24576) { src = wv; dst = wkvT + (size_t)1024*HID_; C = 1024; idx = id - 20480; }
    else                 { src = wo; dst = woT;  C = 4096; idx = id - 24576; }
    const int ctiles = C >> 5;
    const int c0 = (idx % ctiles) * 32, r0 = (idx / ctiles) * 32;
    #pragma unroll
    for (int i = 0; i < 4; ++i)
        t[ty + 8*i][tx] = src[(size_t)(r0 + ty + 8*i) * C + c0 + tx];
    __syncthreads();
    #pragma unroll
    for (int i = 0; i < 4; ++i)
        dst[(size_t)(c0 + ty + 8*i) * HID_ + r0 + tx] = __float2bfloat16(t[tx][ty + 8*i]);
}

// ------------------------------------------------- GEMM 256xBN, BK=32, ring-4, 1-barrier/tile
// (unchanged from R9 — 49% MfmaUtil, hazard-audited)
template <int FN, int OMODE>
__global__ __launch_bounds__(512, 2) void gemm_t(const __hip_bfloat16* __restrict__ A,
                                                 const __hip_bfloat16* __restrict__ Bt,
                                                 void* __restrict__ Cv, void* __restrict__ C2,
                                                 int M, int N, int K, int nbx) {
    constexpr int BN   = FN * 64;
    constexpr int BLD  = BN / 128;                      // B stage loads/thread/tile (2 or 1)
    constexpr int SLOT = (256 + BN) * 32;               // elems per ring slot (A then B)
    __shared__ __align__(16) __hip_bfloat16 L[4 * SLOT];
    const int tid  = threadIdx.x;
    const int lane = tid & 63, w = tid >> 6;
    const int wm = w >> 2, wn = w & 3;                  // 2 x 4 wave grid
    const int lc = lane & 15, lg = lane >> 4;
    const int nwg = gridDim.x, cpx = nwg >> 3;
    const int bid = blockIdx.x;
    const int swz = (bid & 7) * cpx + (bid >> 3);
    const int by = swz / nbx, bx = swz - by * nbx;
    const size_t row0 = (size_t)by * 256, col0 = (size_t)bx * BN;
    const int nt = K >> 5;                              // BK = 32

    const int srow = tid >> 2;
    const int spc  = tid & 3;
    const int slx  = spc ^ ((srow >> 1) & 3);
    const __hip_bfloat16* Ab = A  + row0 * K;
    const __hip_bfloat16* Bb = Bt + col0 * K;

#define STGA(tile_) do {                                                                   \
    const int ss_ = (tile_) & 3;                                                           \
    const int kt_ = ((tile_) < nt) ? (tile_) : (nt - 1);                                   \
    _Pragma("unroll")                                                                      \
    for (int rh_ = 0; rh_ < 2; ++rh_)                                                      \
        __builtin_amdgcn_global_load_lds(                                                  \
            (const GAS void*)(Ab + (size_t)(rh_*128 + srow) * K + kt_*32 + slx*8),         \
            (LAS void*)&L[ss_*SLOT + rh_*4096 + w*512], 16, 0, 0);                         \
} while (0)

#define STGB(tile_) do {                                                                   \
    const int ss_ = (tile_) & 3;                                                           \
    const int kt_ = ((tile_) < nt) ? (tile_) : (nt - 1);                                   \
    _Pragma("unroll")                                                                      \
    for (int bh_ = 0; bh_ < BLD; ++bh_)                                                    \
        __builtin_amdgcn_global_load_lds(                                                  \
            (const GAS void*)(Bb + (size_t)(bh_*128 + srow) * K + kt_*32 + slx*8),         \
            (LAS void*)&L[ss_*SLOT + 8192 + bh_*4096 + w*512], 16, 0, 0);                  \
} while (0)

#define VMW2L() do {                                                                       \
    if constexpr (FN == 4) asm volatile("s_waitcnt vmcnt(8)" ::: "memory");                \
    else                   asm volatile("s_waitcnt vmcnt(6)" ::: "memory");                \
} while (0)

    f32x4 acc[2][4][FN] = {};
    bf16x8 afr0[4], afr1[4], bfr[FN];

    STGA(0); STGB(0); STGA(1); STGB(1); STGA(2); STGB(2);
    VMW2L();
    asm volatile("s_barrier" ::: "memory");

    for (int t = 0; t < nt; ++t) {
        const int s_ = t & 3;
        #pragma unroll
        for (int fn = 0; fn < FN; ++fn) {
            const int rB = wn*(FN*16) + fn*16 + lc;
            bfr[fn] = *(const bf16x8*)&L[s_*SLOT + 8192 + rB*32 + ((lg ^ ((rB >> 1) & 3)) * 8)];
        }
        #pragma unroll
        for (int fm = 0; fm < 4; ++fm) {
            const int rA = wm*128 + fm*16 + lc;
            afr0[fm] = *(const bf16x8*)&L[s_*SLOT + rA*32 + ((lg ^ ((rA >> 1) & 3)) * 8)];
        }
        __builtin_amdgcn_sched_barrier(0);
        #pragma unroll
        for (int fm = 0; fm < 4; ++fm) {
            const int rA = wm*128 + 64 + fm*16 + lc;
            afr1[fm] = *(const bf16x8*)&L[s_*SLOT + rA*32 + ((lg ^ ((rA >> 1) & 3)) * 8)];
        }
        STGA(t + 3);
        asm volatile("s_waitcnt lgkmcnt(4)" ::: "memory");
        __builtin_amdgcn_sched_barrier(0);
        __builtin_amdgcn_s_setprio(1);
        #pragma unroll
        for (int fm = 0; fm < 4; ++fm)
            #pragma unroll
            for (int fn = 0; fn < FN; ++fn)
                acc[0][fm][fn] = __builtin_amdgcn_mfma_f32_16x16x32_bf16(
                    afr0[fm], bfr[fn], acc[0][fm][fn], 0, 0, 0);
        __builtin_amdgcn_s_setprio(0);

        STGB(t + 3);
        asm volatile("s_waitcnt lgkmcnt(0)" ::: "memory");
        __builtin_amdgcn_sched_barrier(0);
        __builtin_amdgcn_s_setprio(1);
        #pragma unroll
        for (int fm = 0; fm < 4; ++fm)
            #pragma unroll
            for (int fn = 0; fn < FN; ++fn)
                acc[1][fm][fn] = __builtin_amdgcn_mfma_f32_16x16x32_bf16(
                    afr1[fm], bfr[fn], acc[1][fm][fn], 0, 0, 0);
        __builtin_amdgcn_s_setprio(0);
        VMW2L();
        asm volatile("s_barrier" ::: "memory");
    }
#undef STGA
#undef STGB
#undef VMW2L
    asm volatile("s_waitcnt vmcnt(0)" ::: "memory");

    if constexpr (OMODE == 0) {
        float* C = (float*)Cv;
        #pragma unroll
        for (int qm = 0; qm < 2; ++qm)
            #pragma unroll
            for (int fm = 0; fm < 4; ++fm)
                #pragma unroll
                for (int fn = 0; fn < FN; ++fn) {
                    const size_t col = col0 + wn*(FN*16) + fn*16 + lc;
                    #pragma unroll
                    for (int rr = 0; rr < 4; ++rr) {
                        const size_t row = row0 + wm*128 + qm*64 + fm*16 + lg*4 + rr;
                        C[row * N + col] = acc[qm][fm][fn][rr];
                    }
                }
    } else if constexpr (OMODE == 1) {
        __hip_bfloat16* C = (__hip_bfloat16*)Cv;
        #pragma unroll
        for (int qm = 0; qm < 2; ++qm)
            #pragma unroll
            for (int fm = 0; fm < 4; ++fm)
                #pragma unroll
                for (int fn = 0; fn < FN; ++fn) {
                    const size_t col = col0 + wn*(FN*16) + fn*16 + lc;
                    #pragma unroll
                    for (int rr = 0; rr < 4; ++rr) {
                        const size_t row = row0 + wm*128 + qm*64 + fm*16 + lg*4 + rr;
                        C[row * N + col] = __float2bfloat16(acc[qm][fm][fn][rr]);
                    }
                }
    } else {                                            // OMODE 2: KV split (FN==2, BN=128)
        if (bx < 8) {                                   // K columns -> kf bf16, LD 1024
            __hip_bfloat16* C = (__hip_bfloat16*)Cv;
            #pragma unroll
            for (int qm = 0; qm < 2; ++qm)
                #pragma unroll
                for (int fm = 0; fm < 4; ++fm)
                    #pragma unroll
                    for (int fn = 0; fn < FN; ++fn) {
                        const size_t col = col0 + wn*32 + fn*16 + lc;
                        #pragma unroll
                        for (int rr = 0; rr < 4; ++rr) {
                            const size_t row = row0 + wm*128 + qm*64 + fm*16 + lg*4 + rr;
                            C[row * 1024 + col] = __float2bfloat16(acc[qm][fm][fn][rr]);
                        }
                    }
        } else {                                        // V columns -> vt (B,KVH,D,S) via LDS
            __hip_bfloat16* lt = (__hip_bfloat16*)L;    // [128 d][264 pad]
            __syncthreads();
            #pragma unroll
            for (int qm = 0; qm < 2; ++qm)
                #pragma unroll
                for (int fm = 0; fm < 4; ++fm)
                    #pragma unroll
                    for (int fn = 0; fn < FN; ++fn) {
                        const int cl = wn*32 + fn*16 + lc;
                        #pragma unroll
                        for (int rr = 0; rr < 4; ++rr) {
                            const int rl = wm*128 + qm*64 + fm*16 + lg*4 + rr;
                            lt[cl*264 + rl] = __float2bfloat16(acc[qm][fm][fn][rr]);
                        }
                    }
            __syncthreads();
            const int bb = (int)(row0 >> 11), s0 = (int)(row0 & 2047);
            const int g  = (int)((col0 - 1024) >> 7);
            __hip_bfloat16* vto = (__hip_bfloat16*)C2 + (((size_t)bb*KVH_ + g) * D_) * (size_t)S_;
            const int d = tid >> 2, sc0 = (tid & 3) * 64;
            #pragma unroll
            for (int j = 0; j < 64; j += 8) {
                bf16x8 v = *(const bf16x8*)&lt[d*264 + sc0 + j];
                *(bf16x8*)&vto[(size_t)d*S_ + s0 + sc0 + j] = v;
            }
        }
    }
}

// ------------------------------------------------- per-head LN + interleaved RoPE (bf16 in)
// used only for K now.  in: x (B*S, LD) bf16.  out: (B, NH, S, D) bf16.
template <int NH, int LD, int XOFF>
__global__ __launch_bounds__(256) void ln_rope(const __hip_bfloat16* __restrict__ x,
                                               const float* __restrict__ wln,
                                               const float* __restrict__ cosT,
                                               const float* __restrict__ sinT,
                                               const int* __restrict__ pids,
                                               __hip_bfloat16* __restrict__ out) {
    const int lane = threadIdx.x & 63, wv = threadIdx.x >> 6;
    const int r = blockIdx.x * 4 + wv;
    const int h = r % NH;
    const int bs = r / NH;
    const int b = bs / S_, s = bs % S_;
    const __hip_bfloat162 xv2 = *(const __hip_bfloat162*)(x + (size_t)bs * LD + XOFF + h*D_ + lane*2);
    const float x0 = __bfloat162float(xv2.x), x1 = __bfloat162float(xv2.y);
    float sum = x0 + x1;
    #pragma unroll
    for (int o = 32; o; o >>= 1) sum += __shfl_xor(sum, o);
    const float mu = sum * (1.f / D_);
    const float dx = x0 - mu, dy = x1 - mu;
    float vs = dx*dx + dy*dy;
    #pragma unroll
    for (int o = 32; o; o >>= 1) vs += __shfl_xor(vs, o);
    const float rs = rsqrtf(vs * (1.f / D_) + 1e-5f);
    const float2 w2 = *(const float2*)(wln + lane*2);
    const float y0 = w2.x * dx * rs, y1 = w2.y * dy * rs;
    const int p = pids[bs];
    const float2 c  = *(const float2*)(cosT + (size_t)p * D_ + lane*2);
    const float2 sn = *(const float2*)(sinT + (size_t)p * D_ + lane*2);
    __hip_bfloat162 ov;
    ov.x = __float2bfloat16(y0 * c.x - y1 * sn.x);
    ov.y = __float2bfloat16(y1 * c.y + y0 * sn.y);
    *(__hip_bfloat162*)(out + (((size_t)b * NH + h) * S_ + s) * D_ + lane*2) = ov;
}

// chunk swizzle for K tile (16B chunks, 16/row)
static __device__ __forceinline__ int sigk_(int r) { return (r & 3) | ((r >> 1) & 4); }

// ------------------------------------------------- sliding-window GQA flash attention v4
// 8 waves / 128 q-rows per block (2 blocks/CU -> 4 waves/SIMD TLP); Q LayerNorm+RoPE fused
// in-register (reads qfb directly); swapped QK^T; K/V^T LDS-staged via global_load_lds,
// double-buffered, counted vmcnt(4) + raw s_barrier.
__global__ __launch_bounds__(512, 4) void attn_fwd(const __hip_bfloat16* __restrict__ qfb,
                                                   const __hip_bfloat16* __restrict__ kr,
                                                   const __hip_bfloat16* __restrict__ vt,
                                                   const float* __restrict__ qnw,
                                                   const float* __restrict__ cosT,
                                                   const float* __restrict__ sinT,
                                                   const int* __restrict__ pids,
                                                   __hip_bfloat16* __restrict__ ao) {
    __shared__ __align__(16) __hip_bfloat16 Ksl[2][64*D_];    // 2 x 16KB
    __shared__ __align__(16) __hip_bfloat16 Vsl[2][D_*64];    // 2 x 16KB
    const int tid = threadIdx.x;
    const int lane = tid & 63, w = tid >> 6;     // 8 waves
    const int lq = lane & 15, lg = lane >> 4;
    const int blk = blockIdx.x;
    const int qt = blk & 15;                     // interleaved qt: balanced dispatch rounds
    const int bh = blk >> 4;                     // 16 consecutive blocks share one KV head
    const int h = bh & (H_-1), b = bh >> 5;
    const int g = h >> 2;                        // GQA: kv head = h/4
    const int q0 = qt*128 + w*16;
    const int q  = q0 + lq;

    const __hip_bfloat16* kbase = kr + ((size_t)b*KVH_ + g) * (size_t)S_ * D_;
    const __hip_bfloat16* vbase = vt + ((size_t)b*KVH_ + g) * (size_t)D_ * S_;

    // staging lane constants (512 threads: 2 K-instrs + 2 V-instrs per wave per tile)
    const int srK = lane >> 4, scK = lane & 15;  // K: 4 rows x 16 chunks per wave-instr
    const int srV = lane >> 3, scV = lane & 7;   // V: 8 rows x 8 chunks per wave-instr

#define STAGE(nb, k0s) do {                                                              \
    _Pragma("unroll")                                                                    \
    for (int s_ = 0; s_ < 2; ++s_) {                                                     \
        const int rK_ = w*8 + s_*4 + srK;                                                \
        const __hip_bfloat16* srcK_ = kbase + (size_t)((k0s) + rK_)*D_                   \
                                      + ((scK ^ sigk_(rK_)) * 8);                        \
        __builtin_amdgcn_global_load_lds((const GAS void*)srcK_,                         \
            (LAS void*)&Ksl[nb][(w*8 + s_*4)*D_], 16, 0, 0);                             \
    }                                                                                    \
    _Pragma("unroll")                                                                    \
    for (int s_ = 0; s_ < 2; ++s_) {                                                     \
        const int dV_ = w*16 + s_*8 + srV;                                               \
        const __hip_bfloat16* srcV_ = vbase + (size_t)dV_*S_ + (k0s)                     \
                                      + ((scV ^ (dV_ & 7)) * 8);                         \
        __builtin_amdgcn_global_load_lds((const GAS void*)srcV_,                         \
            (LAS void*)&Vsl[nb][(w*16 + s_*8)*64], 16, 0, 0);                            \
    }                                                                                    \
} while (0)

    int kst = qt*128 - (WIN_ - 1); if (kst < 0) kst = 0; kst &= ~63;
    const int nt = qt*2 + 2 - (kst >> 6);        // tiles covering [kst, qt*128+127]

    // ---- Q load (before STAGE so its waits don't drain staging), then STAGE(0)
    union { bf16x8 v; __hip_bfloat16 e[8]; } qraw[4];
    const __hip_bfloat16* qb2 = qfb + ((size_t)(b*S_ + q)) * HID_ + h*D_;
    #pragma unroll
    for (int kk = 0; kk < 4; ++kk)
        qraw[kk].v = *(const bf16x8*)(qb2 + kk*32 + lg*8);
    const int p = pids[b*S_ + q];

    STAGE(0, kst);

    // ---- fused LayerNorm (row = 128 elems across lg-group) + interleaved RoPE, f32 math
    float sum = 0.f;
    #pragma unroll
    for (int kk = 0; kk < 4; ++kk)
        #pragma unroll
        for (int j = 0; j < 8; ++j) sum += __bfloat162float(qraw[kk].e[j]);
    sum += __shfl_xor(sum, 16); sum += __shfl_xor(sum, 32);
    const float mu = sum * (1.f / D_);
    float vsq = 0.f;
    #pragma unroll
    for (int kk = 0; kk < 4; ++kk)
        #pragma unroll
        for (int j = 0; j < 8; ++j) {
            const float dxx = __bfloat162float(qraw[kk].e[j]) - mu;
            vsq += dxx * dxx;
        }
    vsq += __shfl_xor(vsq, 16); vsq += __shfl_xor(vsq, 32);
    const float rsq = rsqrtf(vsq * (1.f / D_) + 1e-5f);

    bf16x8 qf[4];
    #pragma unroll
    for (int kk = 0; kk < 4; ++kk) {
        const int d0 = kk*32 + lg*8;
        float wl[8], cc[8], ss[8], y[8];
        *(float4*)&wl[0] = *(const float4*)(qnw + d0);
        *(float4*)&wl[4] = *(const float4*)(qnw + d0 + 4);
        *(float4*)&cc[0] = *(const float4*)(cosT + (size_t)p*D_ + d0);
        *(float4*)&cc[4] = *(const float4*)(cosT + (size_t)p*D_ + d0 + 4);
        *(float4*)&ss[0] = *(const float4*)(sinT + (size_t)p*D_ + d0);
        *(float4*)&ss[4] = *(const float4*)(sinT + (size_t)p*D_ + d0 + 4);
        #pragma unroll
        for (int j = 0; j < 8; ++j)
            y[j] = wl[j] * (__bfloat162float(qraw[kk].e[j]) - mu) * rsq;
        union { bf16x8 v; __hip_bfloat16 e[8]; } qo;
        #pragma unroll
        for (int mpair = 0; mpair < 4; ++mpair) {
            qo.e[2*mpair]   = __float2bfloat16(y[2*mpair]   * cc[2*mpair]   - y[2*mpair+1] * ss[2*mpair]);
            qo.e[2*mpair+1] = __float2bfloat16(y[2*mpair+1] * cc[2*mpair+1] + y[2*mpair]   * ss[2*mpair+1]);
        }
        qf[kk] = qo.v;
    }

    f32x4 o[8] = {};                             // out^T frags: d = n*16 + lg*4 + r, col q = lq
    float m = -1e30f, l = 0.f;
    const int kldrow = 8*(lq >> 2) + (lq & 3);   // A-row -> key permutation

    for (int t = 0; t < nt; ++t) {
        const int k0 = kst + t*64;
        const int buf = t & 1;
        if (t + 1 < nt) {
            STAGE((t + 1) & 1, k0 + 64);
            asm volatile("s_waitcnt vmcnt(4)" ::: "memory");   // tile t staged; t+1 in flight
        } else {
            asm volatile("s_waitcnt vmcnt(0)" ::: "memory");
        }
        __builtin_amdgcn_s_barrier();

        // ---- QK^T from LDS: held value (kb,f,r): key = k0+kb*32+8*lg+4f+r
        f32x4 sc[2][2] = {};
        __builtin_amdgcn_s_setprio(1);
        #pragma unroll
        for (int kb = 0; kb < 2; ++kb)
            #pragma unroll
            for (int f = 0; f < 2; ++f) {
                const int rA = kb*32 + 4*f + kldrow;
                const __hip_bfloat16* kp = &Ksl[buf][rA*D_];
                #pragma unroll
                for (int kk = 0; kk < 4; ++kk) {
                    bf16x8 ka = *(const bf16x8*)(kp + (((kk*4 + lg) ^ sigk_(rA)) * 8));
                    sc[kb][f] = __builtin_amdgcn_mfma_f32_16x16x32_bf16(ka, qf[kk], sc[kb][f], 0, 0, 0);
                }
            }
        __builtin_amdgcn_s_setprio(0);

        // ---- online softmax, log2 domain, lane-local row
        const int dqk = q - (k0 + 8*lg);
        float pv[16];
        float mx = -INFINITY;
        #pragma unroll
        for (int kb = 0; kb < 2; ++kb)
            #pragma unroll
            for (int f = 0; f < 2; ++f)
                #pragma unroll
                for (int r = 0; r < 4; ++r) {
                    const int c = kb*32 + 4*f + r;
                    const int d = dqk - c;
                    float v = (d >= 0 && d < WIN_) ? sc[kb][f][r] * SL2E_ : -INFINITY;
                    pv[kb*8 + f*4 + r] = v;
                    mx = fmaxf(mx, v);
                }
        mx = fmaxf(mx, __shfl_xor(mx, 16));
        mx = fmaxf(mx, __shfl_xor(mx, 32));
        const float mn = fmaxf(m, mx);
        const float alpha = exp2f(m - mn);
        float ls = 0.f;
        union { bf16x8 v; __hip_bfloat16 e[8]; } pu[2];
        #pragma unroll
        for (int kb = 0; kb < 2; ++kb)
            #pragma unroll
            for (int j = 0; j < 8; ++j) {
                const float pw = exp2f(pv[kb*8 + j] - mn);
                ls += pw;
                pu[kb].e[j] = __float2bfloat16(pw);
            }
        ls += __shfl_xor(ls, 16);
        ls += __shfl_xor(ls, 32);
        l = l * alpha + ls;
        m = mn;
        #pragma unroll
        for (int n = 0; n < 8; ++n) {
            o[n][0] *= alpha; o[n][1] *= alpha; o[n][2] *= alpha; o[n][3] *= alpha;
        }

        // ---- PV from LDS: out^T[d][q] += V^T[d][k] * P^T[k][q]
        __builtin_amdgcn_s_setprio(1);
        #pragma unroll
        for (int kb = 0; kb < 2; ++kb)
            #pragma unroll
            for (int n = 0; n < 8; ++n) {
                const int dR = n*16 + lq;
                bf16x8 vf8 = *(const bf16x8*)(&Vsl[buf][dR*64] + (((kb*4 + lg) ^ (dR & 7)) * 8));
                o[n] = __builtin_amdgcn_mfma_f32_16x16x32_bf16(vf8, pu[kb].v, o[n], 0, 0, 0);
            }
        __builtin_amdgcn_s_setprio(0);

        if (t + 1 < nt) __builtin_amdgcn_s_barrier();   // all reads of buf done before overwrite
    }
#undef STAGE

    const float rinv = 1.f / l;
    #pragma unroll
    for (int n = 0; n < 8; ++n) {
        union { bf16x4 v; __hip_bfloat16 e[4]; } ov;
        #pragma unroll
        for (int r = 0; r < 4; ++r) ov.e[r] = __float2bfloat16(o[n][r] * rinv);
        *(bf16x4*)(ao + ((size_t)b*S_ + q)*(H_*D_) + h*D_ + n*16 + lg*4) = ov.v;
    }
}

// ----------------------------------------------------------------- host
extern "C" void kernel_launch(void* const* d_in, const int* in_sizes, int n_in,
                              void* d_out, int out_size, void* d_ws, size_t ws_size,
                              hipStream_t stream) {
    const float* hidden = (const float*)d_in[0];
    const int*   pids   = (const int*)  d_in[1];
    const float* cosT   = (const float*)d_in[2];
    const float* sinT   = (const float*)d_in[3];
    const float* wq     = (const float*)d_in[4];
    const float* wk     = (const float*)d_in[5];
    const float* wv     = (const float*)d_in[6];
    const float* wo     = (const float*)d_in[7];
    const float* qnw    = (const float*)d_in[8];
    const float* knw    = (const float*)d_in[9];
    float* out = (float*)d_out;

    char* base = (char*)d_ws;
    size_t off = 0;
    auto take = [&](size_t bytes) -> void* {
        void* q = base + off;
        off = (off + bytes + 255) & ~(size_t)255;
        return q;
    };
    __hip_bfloat16* qfb  = (__hip_bfloat16*)take((size_t)NROW_*HID_*2);   // Q proj bf16
    __hip_bfloat16* ao   = (__hip_bfloat16*)take((size_t)NROW_*HID_*2);   // attn out bf16
    __hip_bfloat16* kf   = (__hip_bfloat16*)take((size_t)NROW_*1024*2);   // K proj bf16
    __hip_bfloat16* hb   = (__hip_bfloat16*)take((size_t)NROW_*HID_*2);
    __hip_bfloat16* wqT  = (__hip_bfloat16*)take((size_t)HID_*HID_*2);
    __hip_bfloat16* wkvT = (__hip_bfloat16*)take((size_t)NKV_*HID_*2);
    __hip_bfloat16* woT  = (__hip_bfloat16*)take((size_t)HID_*HID_*2);
    __hip_bfloat16* kr   = (__hip_bfloat16*)take((size_t)B_*KVH_*S_*D_*2);
    __hip_bfloat16* vt   = (__hip_bfloat16*)take((size_t)B_*KVH_*S_*D_*2);

    if (off > ws_size) {
        fprintf(stderr, "WORKSPACE TOO SMALL: need %zu have %zu\n", off, ws_size);
        return;
    }

    // 1. merged prep: hidden convert + 4 weight transposes (1 launch)
    prep_all<<<16384 + 40960, 256, 0, stream>>>(hidden, wq, wk, wv, wo, hb, wqT, wkvT, woT);

    // 2. projections — every grid exactly 256 blocks (1 round on 256 CUs)
    gemm_t<4,1><<<(NROW_/256)*(HID_/256), 512, 0, stream>>>(hb, wqT,  qfb, nullptr, NROW_, HID_, HID_, HID_/256);
    gemm_t<2,2><<<(NROW_/256)*(NKV_/128), 512, 0, stream>>>(hb, wkvT, kf,  vt,      NROW_, NKV_, HID_, NKV_/128);

    // 3. LN + RoPE for K only (Q is fused into attention)
    ln_rope<KVH_, 1024, 0><<<(B_*S_*KVH_)/4, 256, 0, stream>>>(kf, knw, cosT, sinT, pids, kr);

    // 4. attention (8 waves, 128 q-rows/block, fused Q LN+RoPE)
    attn_fwd<<<B_*H_*(S_/128), 512, 0, stream>>>(qfb, kr, vt, qnw, cosT, sinT, pids, ao);

    // 5. output projection -> d_out (f32)
    gemm_t<4,0><<<(NROW_/256)*(HID_/256), 512, 0, stream>>>(ao, woT, out, nullptr, NROW_, HID_, H_*D_, HID_/256);
}